// Round 2
// baseline (958.370 us; speedup 1.0000x reference)
//
#include <hip/hip_runtime.h>
#include <hip/hip_bf16.h>

// Problem sizes (fixed by reference)
#define N_NODES 50000
#define N_EDGES 800000
#define F_IN    128
#define HID     128
#define PROJ    512
#define N_CLS   32
#define N_GRAPHS 256
#define T_EMB   768
#define NB_SCAN ((N_NODES + 255) / 256)   // 196
#define DBINS   1024

typedef __attribute__((ext_vector_type(8))) short bf16x8;
typedef __attribute__((ext_vector_type(4))) float f32x4;

__device__ __forceinline__ float bf2f(unsigned short u) {
    unsigned v = ((unsigned)u) << 16;
    return __uint_as_float(v);
}
__device__ __forceinline__ unsigned short f2us(float v) {
    __hip_bfloat16 b = __float2bfloat16(v);
    union { __hip_bfloat16 b; unsigned short u; } c; c.b = b; return c.u;
}

// ---- degree histogram (int atomics over dst) ----
__global__ void k_deg(const int* __restrict__ ei, int* __restrict__ cnt, int nE) {
    int e = blockIdx.x * 256 + threadIdx.x;
    if (e < nE) atomicAdd(cnt + ei[nE + e], 1);
}

// ---- parallel scan pass 1 ----
__global__ __launch_bounds__(256) void k_scan1(const int* __restrict__ cnt,
    int* __restrict__ rowstart, float* __restrict__ dnorm, int* __restrict__ bsum)
{
    __shared__ int ps[256];
    int t = threadIdx.x;
    int i = blockIdx.x * 256 + t;
    int c = (i < N_NODES) ? cnt[i] : 0;
    if (i < N_NODES) dnorm[i] = rsqrtf((float)c + 1.0f);
    ps[t] = c;
    __syncthreads();
    for (int off = 1; off < 256; off <<= 1) {
        int v = (t >= off) ? ps[t - off] : 0;
        __syncthreads();
        ps[t] += v;
        __syncthreads();
    }
    if (i < N_NODES) rowstart[i] = ps[t] - c;
    if (t == 255) bsum[blockIdx.x] = ps[255];
}

// ---- scan pass 2 ----
__global__ __launch_bounds__(256) void k_scan2(int* __restrict__ bsum) {
    __shared__ int ps[256];
    int t = threadIdx.x;
    int v = (t < NB_SCAN) ? bsum[t] : 0;
    ps[t] = v;
    __syncthreads();
    for (int off = 1; off < 256; off <<= 1) {
        int u = (t >= off) ? ps[t - off] : 0;
        __syncthreads();
        ps[t] += u;
        __syncthreads();
    }
    if (t < NB_SCAN) bsum[t] = ps[t] - v;
}

// ---- scan pass 3 (+ degree histogram for LPT sort) ----
__global__ void k_scan3(int* __restrict__ rowstart, const int* __restrict__ bsum,
                        const int* __restrict__ cnt, int* __restrict__ dhist) {
    int i = blockIdx.x * 256 + threadIdx.x;
    if (i < N_NODES) {
        rowstart[i] += bsum[blockIdx.x];
        atomicAdd(dhist + min(cnt[i], DBINS - 1), 1);
    }
    if (i == 0) rowstart[N_NODES] = N_EDGES;
}

// ---- descending-degree exclusive offsets: doff[d] = #rows with degree > d ----
__global__ __launch_bounds__(256) void k_dscan(const int* __restrict__ dhist,
                                               int* __restrict__ doff) {
    __shared__ int part[256];
    __shared__ int binv[DBINS];
    int t = threadIdx.x;
    int base = t * 4;
    int g0 = dhist[DBINS - 1 - (base + 0)];
    int g1 = dhist[DBINS - 1 - (base + 1)];
    int g2 = dhist[DBINS - 1 - (base + 2)];
    int g3 = dhist[DBINS - 1 - (base + 3)];
    int s = g0 + g1 + g2 + g3;
    part[t] = s;
    __syncthreads();
    for (int off = 1; off < 256; off <<= 1) {
        int v = (t >= off) ? part[t - off] : 0;
        __syncthreads();
        part[t] += v;
        __syncthreads();
    }
    int run = part[t] - s;   // exclusive prefix of this thread's 4 bins
    binv[base + 0] = run; run += g0;
    binv[base + 1] = run; run += g1;
    binv[base + 2] = run; run += g2;
    binv[base + 3] = run; run += g3;
    __syncthreads();
    for (int k = t; k < DBINS; k += 256) doff[DBINS - 1 - k] = binv[k];
}

// ---- scatter rows into degree-descending permutation ----
__global__ void k_dperm(const int* __restrict__ cnt, int* __restrict__ doff,
                        int* __restrict__ rowperm) {
    int i = blockIdx.x * 256 + threadIdx.x;
    if (i < N_NODES) {
        int pos = atomicAdd(doff + min(cnt[i], DBINS - 1), 1);
        rowperm[pos] = i;
    }
}

// ---- fill CSR src lists ----
__global__ void k_fill(const int* __restrict__ ei, const int* __restrict__ rowstart,
                       int* __restrict__ cursor, int* __restrict__ srcl, int nE) {
    int e = blockIdx.x * 256 + threadIdx.x;
    if (e >= nE) return;
    int s = ei[e];
    int d = ei[nE + e];
    int pos = rowstart[d] + atomicAdd(cursor + d, 1);
    srcl[pos] = s;
}

// ---- combined prep: weight transpose+bf16 and graph boundaries ----
__global__ void k_prep(const float* __restrict__ W, unsigned short* __restrict__ Wt,
                       const int* __restrict__ batch, int* __restrict__ gstart) {
    int t = blockIdx.x * 256 + threadIdx.x;
    if (t < 4 * 128 * 128) {
        int l = t >> 14;
        int k = (t >> 7) & 127;
        int n = t & 127;
        Wt[(size_t)l * 16384 + n * 128 + k] = f2us(W[(size_t)l * 16384 + k * 128 + n]);
    } else {
        int r = t - 4 * 128 * 128;
        if (r <= N_NODES) {
            int b  = (r < N_NODES) ? batch[r] : N_GRAPHS;
            int bp = (r > 0) ? batch[r - 1] : -1;
            for (int g = bp + 1; g <= b && g <= N_GRAPHS; g++) gstart[g] = r;
        }
    }
}

// ---- GCN matmul via bf16 MFMA; direct global A-loads, BN fold in-register;
// epilogue transposed through LDS (reusing Bs) for coalesced uint4 stores.
// ph output is CHUNK-MAJOR: [4 chunks][N rows][32 feats] bf16. ----
__global__ __launch_bounds__(256) void k_gcn_mm_mfma(const void* __restrict__ inp,
    const unsigned short* __restrict__ Wt,   // [128 n][128 k] bf16 (n-major)
    const float* __restrict__ stats, const float* __restrict__ bng,
    const float* __restrict__ bnb, const float* __restrict__ dnorm,
    unsigned short* __restrict__ ph, int n)
{
    __shared__ __align__(16) unsigned short Bs[128][136];   // 34.8 KB (reused as C-staging)
    __shared__ float scs[128], shs[128];
    int t = threadIdx.x;
    int row0 = blockIdx.x * 64;

    if (stats && t < 128) {
        float inv_n = 1.0f / (float)N_NODES;
        float mu = stats[t] * inv_n;
        float var = stats[128 + t] * inv_n - mu * mu;
        float rs = rsqrtf(var + 1e-5f);
        float sc = rs * bng[t];
        scs[t] = sc;
        shs[t] = bnb[t] - mu * sc;
    }
#pragma unroll
    for (int i = 0; i < 8; i++) {
        int c = t + i * 256;
        int nn = c >> 4;
        int k8 = (c & 15) * 8;
        *(uint4*)&Bs[nn][k8] = *(const uint4*)(Wt + (size_t)nn * 128 + k8);
    }
    __syncthreads();

    int w = t >> 6, lane = t & 63;
    int m = lane & 15, quad = lane >> 4;
    int arow = row0 + w * 16 + m;        // this lane's A row
    bool rowok = arow < n;

    // load A fragments for all 4 k-chunks (16 B each, aligned)
    bf16x8 afrag[4];
    if (!stats) {
        const float* inf = (const float*)inp;
#pragma unroll
        for (int ki = 0; ki < 4; ki++) {
            int k8 = ki * 32 + quad * 8;
            float4 v0 = make_float4(0.f, 0.f, 0.f, 0.f);
            float4 v1 = make_float4(0.f, 0.f, 0.f, 0.f);
            if (rowok) {
                v0 = *(const float4*)(inf + (size_t)arow * 128 + k8);
                v1 = *(const float4*)(inf + (size_t)arow * 128 + k8 + 4);
            }
            union { unsigned short u[8]; bf16x8 v; } pk;
            pk.u[0] = f2us(v0.x); pk.u[1] = f2us(v0.y); pk.u[2] = f2us(v0.z); pk.u[3] = f2us(v0.w);
            pk.u[4] = f2us(v1.x); pk.u[5] = f2us(v1.y); pk.u[6] = f2us(v1.z); pk.u[7] = f2us(v1.w);
            afrag[ki] = pk.v;
        }
    } else {
        const unsigned short* inb = (const unsigned short*)inp;
#pragma unroll
        for (int ki = 0; ki < 4; ki++) {
            int k8 = ki * 32 + quad * 8;
            uint4 raw = make_uint4(0, 0, 0, 0);
            if (rowok) raw = *(const uint4*)(inb + (size_t)arow * 128 + k8);
            unsigned rr[4] = { raw.x, raw.y, raw.z, raw.w };
            union { unsigned short u[8]; bf16x8 v; } pk;
#pragma unroll
            for (int j = 0; j < 4; j++) {
                int f0 = k8 + 2 * j, f1 = k8 + 2 * j + 1;
                float a0 = bf2f((unsigned short)rr[j]) * scs[f0] + shs[f0];
                float a1 = bf2f((unsigned short)(rr[j] >> 16)) * scs[f1] + shs[f1];
                pk.u[2 * j] = f2us(a0);
                pk.u[2 * j + 1] = f2us(a1);
            }
            afrag[ki] = pk.v;
        }
    }

    f32x4 acc[8];
#pragma unroll
    for (int nt = 0; nt < 8; nt++) acc[nt] = (f32x4){0.f, 0.f, 0.f, 0.f};
#pragma unroll
    for (int ki = 0; ki < 4; ki++) {
#pragma unroll
        for (int nt = 0; nt < 8; nt++) {
            bf16x8 b = *(const bf16x8*)&Bs[nt * 16 + m][ki * 32 + quad * 8];
            acc[nt] = __builtin_amdgcn_mfma_f32_16x16x32_bf16(afrag[ki], b, acc[nt], 0, 0, 0);
        }
    }

    float dn[4];
#pragma unroll
    for (int reg = 0; reg < 4; reg++) {
        int gr = row0 + w * 16 + quad * 4 + reg;
        dn[reg] = (gr < n) ? dnorm[gr] : 0.f;
    }

    // ---- epilogue: transpose C through LDS (reuse Bs), store chunk-major ----
    __syncthreads();   // all waves finished reading Bs
#pragma unroll
    for (int nt = 0; nt < 8; nt++) {
#pragma unroll
        for (int reg = 0; reg < 4; reg++) {
            Bs[w * 16 + quad * 4 + reg][nt * 16 + m] = f2us(acc[nt][reg] * dn[reg]);
        }
    }
    __syncthreads();
#pragma unroll
    for (int i = 0; i < 4; i++) {
        int idx = t + i * 256;           // 0..1023
        int r = idx >> 4;                // 0..63
        int c8 = (idx & 15) * 8;         // 0..120
        int gr = row0 + r;
        int ch = c8 >> 5;                // chunk 0..3
        int off = c8 & 31;               // 0,8,16,24
        if (gr < n)
            *(uint4*)(ph + (size_t)ch * (N_NODES * 32) + (size_t)gr * 32 + off)
                = *(const uint4*)&Bs[r][c8];
    }
}

// ---- feature-chunked pair-gather v3: 4 passes x 32 feats, degree-sorted rows.
// rowperm groups equal-degree rows into each wave (lockstep, LPT block order).
// unroll-8 edge loop with software-pipelined srcl prefetch; NT loads/stores keep
// the 3.2 MB ph slice resident in each XCD's 4 MB L2. ----
__global__ __launch_bounds__(256) void k_gather_c(const unsigned long long* __restrict__ ph64,
    const int* __restrict__ srcl, const int* __restrict__ rowstart,
    const int* __restrict__ rowperm, const float* __restrict__ dnorm,
    const float* __restrict__ bias, unsigned short* __restrict__ outbb,
    float* __restrict__ stats, int n)
{
    const int EMAX = N_EDGES - 1;
    __shared__ float bsm[128], bqm[128];
    int t = threadIdx.x;
    if (t < 128) { bsm[t] = 0.f; bqm[t] = 0.f; }
    __syncthreads();

    int lane = t & 63;
    int w = t >> 6;           // wave 0..3
    int grp = lane >> 3;      // group 0..7 within wave
    int l8 = lane & 7;        // lane within group (covers 4 feats)
    int idx = blockIdx.x * 32 + w * 8 + grp;
    bool rok = idx < n;
    int r = rok ? rowperm[idx] : 0;
    int start = rowstart[r];
    int deg = rowstart[r + 1] - start;
    float dnr = dnorm[r];
    if (!rok) { deg = 0; dnr = 0.f; }
    int len = deg + 1;        // + self loop

    for (int c = 0; c < 4; c++) {
        const unsigned long long* phc = ph64 + (size_t)c * (N_NODES * 8); // 32 feats = 8 ull/row
        float4 bi4 = *(const float4*)&bias[c * 32 + l8 * 4];
        float a0 = 0.f, a1 = 0.f, a2 = 0.f, a3 = 0.f;
        int sl[8];
#pragma unroll
        for (int u = 0; u < 8; u++)
            sl[u] = __builtin_nontemporal_load(srcl + min(start + u, EMAX));
        for (int j = 0; j < len; j += 8) {
            unsigned long long uv[8];
#pragma unroll
            for (int u = 0; u < 8; u++) {
                int i = j + u;
                int s = (i < deg) ? sl[u] : r;
                uv[u] = phc[(size_t)s * 8 + l8];
            }
            // prefetch next batch's srcl while ph loads are in flight
#pragma unroll
            for (int u = 0; u < 8; u++)
                sl[u] = __builtin_nontemporal_load(srcl + min(start + j + 8 + u, EMAX));
#pragma unroll
            for (int u = 0; u < 8; u++) {
                int i = j + u;
                float wt = (i < len) ? 1.f : 0.f;
                unsigned lo = (unsigned)uv[u], hi = (unsigned)(uv[u] >> 32);
                a0 += wt * bf2f((unsigned short)lo);
                a1 += wt * bf2f((unsigned short)(lo >> 16));
                a2 += wt * bf2f((unsigned short)hi);
                a3 += wt * bf2f((unsigned short)(hi >> 16));
            }
        }
        float v0 = a0 * dnr + bi4.x;
        float v1 = a1 * dnr + bi4.y;
        float v2 = a2 * dnr + bi4.z;
        float v3 = a3 * dnr + bi4.w;
        v0 = v0 > 0.f ? v0 : 0.01f * v0;
        v1 = v1 > 0.f ? v1 : 0.01f * v1;
        v2 = v2 > 0.f ? v2 : 0.01f * v2;
        v3 = v3 > 0.f ? v3 : 0.01f * v3;
        if (rok) {
            union { ushort4 s4; unsigned long long u; } ov;
            ov.s4.x = f2us(v0); ov.s4.y = f2us(v1); ov.s4.z = f2us(v2); ov.s4.w = f2us(v3);
            __builtin_nontemporal_store(ov.u,
                (unsigned long long*)(outbb + (size_t)r * 128 + c * 32 + l8 * 4));
        } else {
            v0 = v1 = v2 = v3 = 0.f;
        }
        float q0 = v0 * v0, q1 = v1 * v1, q2 = v2 * v2, q3 = v3 * v3;
        // reduce across the 8 groups of this wave (same features at same l8)
#pragma unroll
        for (int mk = 8; mk < 64; mk <<= 1) {
            v0 += __shfl_xor(v0, mk, 64); v1 += __shfl_xor(v1, mk, 64);
            v2 += __shfl_xor(v2, mk, 64); v3 += __shfl_xor(v3, mk, 64);
            q0 += __shfl_xor(q0, mk, 64); q1 += __shfl_xor(q1, mk, 64);
            q2 += __shfl_xor(q2, mk, 64); q3 += __shfl_xor(q3, mk, 64);
        }
        if (grp == 0) {
            int f = c * 32 + l8 * 4;
            atomicAdd(&bsm[f + 0], v0); atomicAdd(&bsm[f + 1], v1);
            atomicAdd(&bsm[f + 2], v2); atomicAdd(&bsm[f + 3], v3);
            atomicAdd(&bqm[f + 0], q0); atomicAdd(&bqm[f + 1], q1);
            atomicAdd(&bqm[f + 2], q2); atomicAdd(&bqm[f + 3], q3);
        }
    }
    __syncthreads();
    if (t < 128) {
        atomicAdd(&stats[t], bsm[t]);
        atomicAdd(&stats[128 + t], bqm[t]);
    }
}

// ---- segmented mean pool (bf16 input); BN scale/shift computed in-block ----
__global__ __launch_bounds__(256) void k_pool2(const unsigned short* __restrict__ outbb,
    const int* __restrict__ gstart, const float* __restrict__ stats,
    const float* __restrict__ bng, const float* __restrict__ bnb,
    float* __restrict__ gemb)
{
    __shared__ float scs[128], shs[128];
    int g = blockIdx.x;
    int t = threadIdx.x;
    if (t < 128) {
        float inv_n = 1.0f / (float)N_NODES;
        float mu = stats[t] * inv_n;
        float var = stats[128 + t] * inv_n - mu * mu;
        float rs = rsqrtf(var + 1e-5f);
        float sc = rs * bng[t];
        scs[t] = sc;
        shs[t] = bnb[t] - mu * sc;
    }
    __syncthreads();
    int f = t & 127;
    int half = t >> 7;
    int start = gstart[g], end = gstart[g + 1];
    int cnt = end - start;
    float s0 = 0.f, s1 = 0.f, s2 = 0.f, s3 = 0.f;
    int r = start + half;
    for (; r + 6 < end; r += 8) {
        s0 += bf2f(outbb[(size_t)(r    ) * 128 + f]);
        s1 += bf2f(outbb[(size_t)(r + 2) * 128 + f]);
        s2 += bf2f(outbb[(size_t)(r + 4) * 128 + f]);
        s3 += bf2f(outbb[(size_t)(r + 6) * 128 + f]);
    }
    for (; r < end; r += 2) s0 += bf2f(outbb[(size_t)r * 128 + f]);
    float sum = (s0 + s1) + (s2 + s3);
    __shared__ float sb[256];
    sb[t] = sum;
    __syncthreads();
    if (t < 128) {
        float tot = sb[t] + sb[t + 128];
        float v = (cnt > 0) ? (tot / (float)cnt) * scs[f] + shs[f] : 0.f;
        gemb[(size_t)g * 128 + f] = v;
    }
}

// ---- fused head layer 1 for both heads ----
__global__ __launch_bounds__(256) void k_head1x(const float* __restrict__ gemb,
    const float* __restrict__ textf,
    const float* __restrict__ gW1, const float* __restrict__ gb1,
    const float* __restrict__ tW1, const float* __restrict__ tb1,
    float* __restrict__ projg, float* __restrict__ projt)
{
    __shared__ float ins[8][768];
    int bx = blockIdx.x;
    int chunk = blockIdx.y;
    int isT = bx >= 32;
    int rb = isT ? bx - 32 : bx;
    const float* in = isT ? textf : gemb;
    int K = isT ? T_EMB : HID;
    const float* W = isT ? tW1 : gW1;
    const float* b = isT ? tb1 : gb1;
    float* outp = isT ? projt : projg;

    int t = threadIdx.x;
    int tot = 8 * K;
    for (int l = t; l < tot; l += 256) {
        int r = l / K, k = l - r * K;
        ins[r][k] = in[(size_t)(rb * 8 + r) * K + k];
    }
    __syncthreads();
    int col = chunk * 128 + (t & 127);
    int rg = t >> 7;
    float acc[4] = { 0.f, 0.f, 0.f, 0.f };
    for (int k = 0; k < K; k++) {
        float w = W[(size_t)k * 512 + col];
#pragma unroll
        for (int i = 0; i < 4; i++) acc[i] += ins[rg * 4 + i][k] * w;
    }
    float bias = b[col];
#pragma unroll
    for (int i = 0; i < 4; i++) {
        int row = rb * 8 + rg * 4 + i;
        outp[(size_t)row * 512 + col] = acc[i] + bias;
    }
}

// ---- fused head2 + LayerNorm + classifier + log_softmax, both heads ----
__global__ __launch_bounds__(256) void k_head2c(
    const float* __restrict__ projg, const float* __restrict__ projt,
    const float* __restrict__ gW2, const float* __restrict__ gb2,
    const float* __restrict__ gg, const float* __restrict__ gbe,
    const float* __restrict__ gclW, const float* __restrict__ gclb,
    const float* __restrict__ tW2, const float* __restrict__ tb2,
    const float* __restrict__ tg, const float* __restrict__ tbe,
    const float* __restrict__ tclW, const float* __restrict__ tclb,
    float* __restrict__ o_gproj, float* __restrict__ o_tproj,
    float* __restrict__ o_glogp, float* __restrict__ o_tlogp)
{
    __shared__ float prow[512], grow[512], onorm[512], red[256];
    __shared__ float part[8][32];
    __shared__ float logits[32];
    __shared__ float mred, lred;
    int bx = blockIdx.x;
    int isT = bx >= N_GRAPHS;
    int row = isT ? bx - N_GRAPHS : bx;
    const float* proj = isT ? projt : projg;
    const float* W2 = isT ? tW2 : gW2;
    const float* b2 = isT ? tb2 : gb2;
    const float* g  = isT ? tg  : gg;
    const float* be = isT ? tbe : gbe;
    const float* Wc = isT ? tclW : gclW;
    const float* bc = isT ? tclb : gclb;
    float* oproj = isT ? o_tproj : o_gproj;
    float* ologp = isT ? o_tlogp : o_glogp;

    int t = threadIdx.x;
    for (int c = t; c < 512; c += 256) {
        float p = proj[(size_t)row * 512 + c];
        prow[c] = p;
        grow[c] = 0.5f * p * (1.0f + erff(p * 0.70710678118f));
    }
    __syncthreads();
    float a0 = 0.f, a1 = 0.f;
    int c0 = t, c1 = t + 256;
    for (int k = 0; k < 512; k++) {
        float gk = grow[k];
        a0 += gk * W2[(size_t)k * 512 + c0];
        a1 += gk * W2[(size_t)k * 512 + c1];
    }
    float h0 = a0 + b2[c0] + prow[c0];
    float h1 = a1 + b2[c1] + prow[c1];
    red[t] = h0 + h1;
    __syncthreads();
    for (int s = 128; s > 0; s >>= 1) { if (t < s) red[t] += red[t + s]; __syncthreads(); }
    float mu = red[0] * (1.0f / 512.0f);
    __syncthreads();
    float d0 = h0 - mu, d1 = h1 - mu;
    red[t] = d0 * d0 + d1 * d1;
    __syncthreads();
    for (int s = 128; s > 0; s >>= 1) { if (t < s) red[t] += red[t + s]; __syncthreads(); }
    float rs = rsqrtf(red[0] * (1.0f / 512.0f) + 1e-5f);
    float o0 = d0 * rs * g[c0] + be[c0];
    float o1 = d1 * rs * g[c1] + be[c1];
    onorm[c0] = o0;
    onorm[c1] = o1;
    oproj[(size_t)row * 512 + c0] = o0;
    oproj[(size_t)row * 512 + c1] = o1;
    __syncthreads();

    int c = t & 31, seg = t >> 5;
    float p = 0.f;
    for (int k = seg * 64; k < seg * 64 + 64; k++)
        p += onorm[k] * Wc[(size_t)k * 32 + c];
    part[seg][c] = p;
    __syncthreads();
    if (t < 32) {
        float l = bc[t];
#pragma unroll
        for (int s = 0; s < 8; s++) l += part[s][t];
        logits[t] = l;
    }
    __syncthreads();
    if (t == 0) {
        float m = logits[0];
        for (int i = 1; i < 32; i++) m = fmaxf(m, logits[i]);
        float sum = 0.f;
        for (int i = 0; i < 32; i++) sum += expf(logits[i] - m);
        mred = m; lred = logf(sum);
    }
    __syncthreads();
    if (t < 32) ologp[(size_t)row * 32 + t] = logits[t] - mred - lred;
}

extern "C" void kernel_launch(void* const* d_in, const int* in_sizes, int n_in,
                              void* d_out, int out_size, void* d_ws, size_t ws_size,
                              hipStream_t stream) {
    const float* x     = (const float*)d_in[0];
    const int*   ei    = (const int*)d_in[1];
    const int*   batch = (const int*)d_in[2];
    const float* textf = (const float*)d_in[3];
    const float* gcnW  = (const float*)d_in[4];
    const float* gcnb  = (const float*)d_in[5];
    const float* bng   = (const float*)d_in[6];
    const float* bnb   = (const float*)d_in[7];
    const float* gW1   = (const float*)d_in[8];
    const float* gb1   = (const float*)d_in[9];
    const float* gW2   = (const float*)d_in[10];
    const float* gb2   = (const float*)d_in[11];
    const float* gg    = (const float*)d_in[12];
    const float* gbe   = (const float*)d_in[13];
    const float* gclW  = (const float*)d_in[14];
    const float* gclb  = (const float*)d_in[15];
    const float* tW1   = (const float*)d_in[16];
    const float* tb1   = (const float*)d_in[17];
    const float* tW2   = (const float*)d_in[18];
    const float* tb2   = (const float*)d_in[19];
    const float* tg    = (const float*)d_in[20];
    const float* tbe   = (const float*)d_in[21];
    const float* tclW  = (const float*)d_in[22];
    const float* tclb  = (const float*)d_in[23];

    const int N = N_NODES, E = N_EDGES;
    const int NF = N * HID;

    float* p = (float*)d_ws;
    unsigned short* outbb = (unsigned short*)p; p += NF / 2;   // 12.8 MB bf16
    unsigned short* ph    = (unsigned short*)p; p += NF / 2;   // 12.8 MB bf16 chunk-major
    unsigned short* Wt    = (unsigned short*)p; p += 4 * 16384 / 2;
    float* dnorm = p; p += N;
    float* gemb  = p; p += N_GRAPHS * HID;
    float* projg = p; p += N_GRAPHS * PROJ;
    float* projt = p; p += N_GRAPHS * PROJ;
    // contiguous zero-init region: cnt | cursor | stats4 | dhist
    int* cnt      = (int*)p; p += N;
    int* cursor   = (int*)p; p += N;
    float* stats4 = p; p += 4 * 256;
    int* dhist    = (int*)p; p += DBINS;
    int* rowstart = (int*)p; p += N + 1;
    int* gstart   = (int*)p; p += N_GRAPHS + 1;
    int* bsum     = (int*)p; p += 256;
    int* srcl     = (int*)p; p += E;
    int* doff     = (int*)p; p += DBINS;
    int* rowperm  = (int*)p; p += N;

    float* outp = (float*)d_out;
    float* o_gproj = outp;
    float* o_tproj = outp + N_GRAPHS * PROJ;
    float* o_glogp = o_tproj + N_GRAPHS * PROJ;
    float* o_tlogp = o_glogp + N_GRAPHS * N_CLS;

    // ---- CSR build + degree-sort + prep ----
    hipMemsetAsync(cnt, 0, (size_t)(2 * N + 4 * 256 + DBINS) * sizeof(int), stream);
    k_deg<<<(E + 255) / 256, 256, 0, stream>>>(ei, cnt, E);
    k_scan1<<<NB_SCAN, 256, 0, stream>>>(cnt, rowstart, dnorm, bsum);
    k_scan2<<<1, 256, 0, stream>>>(bsum);
    k_scan3<<<NB_SCAN, 256, 0, stream>>>(rowstart, bsum, cnt, dhist);
    k_fill<<<(E + 255) / 256, 256, 0, stream>>>(ei, rowstart, cursor, srcl, E);
    k_dscan<<<1, 256, 0, stream>>>(dhist, doff);
    k_dperm<<<NB_SCAN, 256, 0, stream>>>(cnt, doff, rowperm);
    k_prep<<<(4 * 16384 + N + 1 + 255) / 256, 256, 0, stream>>>(gcnW, Wt, batch, gstart);

    // ---- 4 GCN layers (BN of layer l-1 folded into mm of layer l) ----
    for (int l = 0; l < 4; l++) {
        const void* in = (l == 0) ? (const void*)x : (const void*)outbb;
        const float* st = (l == 0) ? nullptr : stats4 + (l - 1) * 256;
        const float* bg = (l == 0) ? nullptr : bng + (size_t)(l - 1) * HID;
        const float* bb = (l == 0) ? nullptr : bnb + (size_t)(l - 1) * HID;
        k_gcn_mm_mfma<<<(N + 63) / 64, 256, 0, stream>>>(in, Wt + (size_t)l * 16384,
                                                         st, bg, bb, dnorm, ph, N);
        k_gather_c<<<(N + 31) / 32, 256, 0, stream>>>((const unsigned long long*)ph, srcl,
                                                      rowstart, rowperm, dnorm,
                                                      gcnb + (size_t)l * HID, outbb,
                                                      stats4 + l * 256, N);
    }

    // ---- segmented mean pool (layer-3 BN folded in-block) ----
    k_pool2<<<N_GRAPHS, 256, 0, stream>>>(outbb, gstart, stats4 + 3 * 256,
                                          bng + 3 * HID, bnb + 3 * HID, gemb);

    // ---- fused heads ----
    k_head1x<<<dim3(64, 4), 256, 0, stream>>>(gemb, textf, gW1, gb1, tW1, tb1, projg, projt);
    k_head2c<<<2 * N_GRAPHS, 256, 0, stream>>>(projg, projt,
                                               gW2, gb2, gg, gbe, gclW, gclb,
                                               tW2, tb2, tg, tbe, tclW, tclb,
                                               o_gproj, o_tproj, o_glogp, o_tlogp);
}

// Round 3
// 619.785 us; speedup vs baseline: 1.5463x; 1.5463x over previous
//
#include <hip/hip_runtime.h>
#include <hip/hip_bf16.h>

// Problem sizes (fixed by reference)
#define N_NODES 50000
#define N_EDGES 800000
#define F_IN    128
#define HID     128
#define PROJ    512
#define N_CLS   32
#define N_GRAPHS 256
#define T_EMB   768
#define NB_SCAN ((N_NODES + 255) / 256)   // 196
#define DBINS   1024

typedef __attribute__((ext_vector_type(8))) short bf16x8;
typedef __attribute__((ext_vector_type(4))) float f32x4;

__device__ __forceinline__ float bf2f(unsigned short u) {
    unsigned v = ((unsigned)u) << 16;
    return __uint_as_float(v);
}
__device__ __forceinline__ unsigned short f2us(float v) {
    __hip_bfloat16 b = __float2bfloat16(v);
    union { __hip_bfloat16 b; unsigned short u; } c; c.b = b; return c.u;
}

// ---- degree histogram (int atomics over dst) ----
__global__ void k_deg(const int* __restrict__ ei, int* __restrict__ cnt, int nE) {
    int e = blockIdx.x * 256 + threadIdx.x;
    if (e < nE) atomicAdd(cnt + ei[nE + e], 1);
}

// ---- parallel scan pass 1 ----
__global__ __launch_bounds__(256) void k_scan1(const int* __restrict__ cnt,
    int* __restrict__ rowstart, float* __restrict__ dnorm, int* __restrict__ bsum)
{
    __shared__ int ps[256];
    int t = threadIdx.x;
    int i = blockIdx.x * 256 + t;
    int c = (i < N_NODES) ? cnt[i] : 0;
    if (i < N_NODES) dnorm[i] = rsqrtf((float)c + 1.0f);
    ps[t] = c;
    __syncthreads();
    for (int off = 1; off < 256; off <<= 1) {
        int v = (t >= off) ? ps[t - off] : 0;
        __syncthreads();
        ps[t] += v;
        __syncthreads();
    }
    if (i < N_NODES) rowstart[i] = ps[t] - c;
    if (t == 255) bsum[blockIdx.x] = ps[255];
}

// ---- scan pass 2 ----
__global__ __launch_bounds__(256) void k_scan2(int* __restrict__ bsum) {
    __shared__ int ps[256];
    int t = threadIdx.x;
    int v = (t < NB_SCAN) ? bsum[t] : 0;
    ps[t] = v;
    __syncthreads();
    for (int off = 1; off < 256; off <<= 1) {
        int u = (t >= off) ? ps[t - off] : 0;
        __syncthreads();
        ps[t] += u;
        __syncthreads();
    }
    if (t < NB_SCAN) bsum[t] = ps[t] - v;
}

// ---- scan pass 3 (+ LDS-aggregated degree histogram for LPT sort) ----
__global__ __launch_bounds__(256) void k_scan3(int* __restrict__ rowstart,
    const int* __restrict__ bsum, const int* __restrict__ cnt,
    int* __restrict__ dhist)
{
    __shared__ int lh[DBINS];
    int t = threadIdx.x;
    for (int k = t; k < DBINS; k += 256) lh[k] = 0;
    __syncthreads();
    int i = blockIdx.x * 256 + t;
    if (i < N_NODES) {
        rowstart[i] += bsum[blockIdx.x];
        atomicAdd(&lh[min(cnt[i], DBINS - 1)], 1);
    }
    if (i == 0) rowstart[N_NODES] = N_EDGES;
    __syncthreads();
    for (int k = t; k < DBINS; k += 256) {
        int v = lh[k];
        if (v) atomicAdd(dhist + k, v);
    }
}

// ---- descending-degree exclusive offsets: doff[d] = #rows with degree > d ----
__global__ __launch_bounds__(256) void k_dscan(const int* __restrict__ dhist,
                                               int* __restrict__ doff) {
    __shared__ int part[256];
    __shared__ int binv[DBINS];
    int t = threadIdx.x;
    int base = t * 4;
    int g0 = dhist[DBINS - 1 - (base + 0)];
    int g1 = dhist[DBINS - 1 - (base + 1)];
    int g2 = dhist[DBINS - 1 - (base + 2)];
    int g3 = dhist[DBINS - 1 - (base + 3)];
    int s = g0 + g1 + g2 + g3;
    part[t] = s;
    __syncthreads();
    for (int off = 1; off < 256; off <<= 1) {
        int v = (t >= off) ? part[t - off] : 0;
        __syncthreads();
        part[t] += v;
        __syncthreads();
    }
    int run = part[t] - s;   // exclusive prefix of this thread's 4 bins
    binv[base + 0] = run; run += g0;
    binv[base + 1] = run; run += g1;
    binv[base + 2] = run; run += g2;
    binv[base + 3] = run; run += g3;
    __syncthreads();
    for (int k = t; k < DBINS; k += 256) doff[DBINS - 1 - k] = binv[k];
}

// ---- scatter rows into degree-descending permutation (two-phase, LDS ranks;
// one global atomic per non-empty bin per block -> no same-address storm) ----
__global__ __launch_bounds__(1024) void k_dperm(const int* __restrict__ cnt,
    int* __restrict__ doff, int* __restrict__ rowperm)
{
    __shared__ int lh[DBINS];
    __shared__ int lbase[DBINS];
    int t = threadIdx.x;
    if (t < DBINS) lh[t] = 0;
    __syncthreads();
    int i = blockIdx.x * 1024 + t;
    int bin = 0, lrank = 0;
    bool ok = i < N_NODES;
    if (ok) {
        bin = min(cnt[i], DBINS - 1);
        lrank = atomicAdd(&lh[bin], 1);
    }
    __syncthreads();
    if (t < DBINS) {
        int v = lh[t];
        if (v) lbase[t] = atomicAdd(doff + t, v);
    }
    __syncthreads();
    if (ok) rowperm[lbase[bin] + lrank] = i;
}

// ---- fill CSR src lists ----
__global__ void k_fill(const int* __restrict__ ei, const int* __restrict__ rowstart,
                       int* __restrict__ cursor, int* __restrict__ srcl, int nE) {
    int e = blockIdx.x * 256 + threadIdx.x;
    if (e >= nE) return;
    int s = ei[e];
    int d = ei[nE + e];
    int pos = rowstart[d] + atomicAdd(cursor + d, 1);
    srcl[pos] = s;
}

// ---- combined prep: weight transpose+bf16 and graph boundaries ----
__global__ void k_prep(const float* __restrict__ W, unsigned short* __restrict__ Wt,
                       const int* __restrict__ batch, int* __restrict__ gstart) {
    int t = blockIdx.x * 256 + threadIdx.x;
    if (t < 4 * 128 * 128) {
        int l = t >> 14;
        int k = (t >> 7) & 127;
        int n = t & 127;
        Wt[(size_t)l * 16384 + n * 128 + k] = f2us(W[(size_t)l * 16384 + k * 128 + n]);
    } else {
        int r = t - 4 * 128 * 128;
        if (r <= N_NODES) {
            int b  = (r < N_NODES) ? batch[r] : N_GRAPHS;
            int bp = (r > 0) ? batch[r - 1] : -1;
            for (int g = bp + 1; g <= b && g <= N_GRAPHS; g++) gstart[g] = r;
        }
    }
}

// ---- GCN matmul via bf16 MFMA; direct global A-loads, BN fold in-register;
// epilogue transposed through LDS (reusing Bs) for coalesced uint4 stores.
// ph output is CHUNK-MAJOR: [4 chunks][N rows][32 feats] bf16. ----
__global__ __launch_bounds__(256) void k_gcn_mm_mfma(const void* __restrict__ inp,
    const unsigned short* __restrict__ Wt,   // [128 n][128 k] bf16 (n-major)
    const float* __restrict__ stats, const float* __restrict__ bng,
    const float* __restrict__ bnb, const float* __restrict__ dnorm,
    unsigned short* __restrict__ ph, int n)
{
    __shared__ __align__(16) unsigned short Bs[128][136];   // 34.8 KB (reused as C-staging)
    __shared__ float scs[128], shs[128];
    int t = threadIdx.x;
    int row0 = blockIdx.x * 64;

    if (stats && t < 128) {
        float inv_n = 1.0f / (float)N_NODES;
        float mu = stats[t] * inv_n;
        float var = stats[128 + t] * inv_n - mu * mu;
        float rs = rsqrtf(var + 1e-5f);
        float sc = rs * bng[t];
        scs[t] = sc;
        shs[t] = bnb[t] - mu * sc;
    }
#pragma unroll
    for (int i = 0; i < 8; i++) {
        int c = t + i * 256;
        int nn = c >> 4;
        int k8 = (c & 15) * 8;
        *(uint4*)&Bs[nn][k8] = *(const uint4*)(Wt + (size_t)nn * 128 + k8);
    }
    __syncthreads();

    int w = t >> 6, lane = t & 63;
    int m = lane & 15, quad = lane >> 4;
    int arow = row0 + w * 16 + m;        // this lane's A row
    bool rowok = arow < n;

    // load A fragments for all 4 k-chunks (16 B each, aligned)
    bf16x8 afrag[4];
    if (!stats) {
        const float* inf = (const float*)inp;
#pragma unroll
        for (int ki = 0; ki < 4; ki++) {
            int k8 = ki * 32 + quad * 8;
            float4 v0 = make_float4(0.f, 0.f, 0.f, 0.f);
            float4 v1 = make_float4(0.f, 0.f, 0.f, 0.f);
            if (rowok) {
                v0 = *(const float4*)(inf + (size_t)arow * 128 + k8);
                v1 = *(const float4*)(inf + (size_t)arow * 128 + k8 + 4);
            }
            union { unsigned short u[8]; bf16x8 v; } pk;
            pk.u[0] = f2us(v0.x); pk.u[1] = f2us(v0.y); pk.u[2] = f2us(v0.z); pk.u[3] = f2us(v0.w);
            pk.u[4] = f2us(v1.x); pk.u[5] = f2us(v1.y); pk.u[6] = f2us(v1.z); pk.u[7] = f2us(v1.w);
            afrag[ki] = pk.v;
        }
    } else {
        const unsigned short* inb = (const unsigned short*)inp;
#pragma unroll
        for (int ki = 0; ki < 4; ki++) {
            int k8 = ki * 32 + quad * 8;
            uint4 raw = make_uint4(0, 0, 0, 0);
            if (rowok) raw = *(const uint4*)(inb + (size_t)arow * 128 + k8);
            unsigned rr[4] = { raw.x, raw.y, raw.z, raw.w };
            union { unsigned short u[8]; bf16x8 v; } pk;
#pragma unroll
            for (int j = 0; j < 4; j++) {
                int f0 = k8 + 2 * j, f1 = k8 + 2 * j + 1;
                float a0 = bf2f((unsigned short)rr[j]) * scs[f0] + shs[f0];
                float a1 = bf2f((unsigned short)(rr[j] >> 16)) * scs[f1] + shs[f1];
                pk.u[2 * j] = f2us(a0);
                pk.u[2 * j + 1] = f2us(a1);
            }
            afrag[ki] = pk.v;
        }
    }

    f32x4 acc[8];
#pragma unroll
    for (int nt = 0; nt < 8; nt++) acc[nt] = (f32x4){0.f, 0.f, 0.f, 0.f};
#pragma unroll
    for (int ki = 0; ki < 4; ki++) {
#pragma unroll
        for (int nt = 0; nt < 8; nt++) {
            bf16x8 b = *(const bf16x8*)&Bs[nt * 16 + m][ki * 32 + quad * 8];
            acc[nt] = __builtin_amdgcn_mfma_f32_16x16x32_bf16(afrag[ki], b, acc[nt], 0, 0, 0);
        }
    }

    float dn[4];
#pragma unroll
    for (int reg = 0; reg < 4; reg++) {
        int gr = row0 + w * 16 + quad * 4 + reg;
        dn[reg] = (gr < n) ? dnorm[gr] : 0.f;
    }

    // ---- epilogue: transpose C through LDS (reuse Bs), store chunk-major ----
    __syncthreads();   // all waves finished reading Bs
#pragma unroll
    for (int nt = 0; nt < 8; nt++) {
#pragma unroll
        for (int reg = 0; reg < 4; reg++) {
            Bs[w * 16 + quad * 4 + reg][nt * 16 + m] = f2us(acc[nt][reg] * dn[reg]);
        }
    }
    __syncthreads();
#pragma unroll
    for (int i = 0; i < 4; i++) {
        int idx = t + i * 256;           // 0..1023
        int r = idx >> 4;                // 0..63
        int c8 = (idx & 15) * 8;         // 0..120
        int gr = row0 + r;
        int ch = c8 >> 5;                // chunk 0..3
        int off = c8 & 31;               // 0,8,16,24
        if (gr < n)
            *(uint4*)(ph + (size_t)ch * (N_NODES * 32) + (size_t)gr * 32 + off)
                = *(const uint4*)&Bs[r][c8];
    }
}

// ---- feature-chunked pair-gather (round-1 body + degree-sorted rowperm):
// 4 passes x 32 feats; each pass touches a 3.2 MB ph slice (L2-resident).
// rowperm groups equal-degree rows into each wave (lockstep) in descending
// degree order (LPT schedule -> small occupancy tail). ----
__global__ __launch_bounds__(256) void k_gather_c(const unsigned long long* __restrict__ ph64,
    const int* __restrict__ srcl, const int* __restrict__ rowstart,
    const int* __restrict__ rowperm, const float* __restrict__ dnorm,
    const float* __restrict__ bias, unsigned short* __restrict__ outbb,
    float* __restrict__ stats, int n)
{
    const int EMAX = N_EDGES - 1;
    __shared__ float bsm[128], bqm[128];
    int t = threadIdx.x;
    if (t < 128) { bsm[t] = 0.f; bqm[t] = 0.f; }
    __syncthreads();

    int lane = t & 63;
    int w = t >> 6;           // wave 0..3
    int grp = lane >> 3;      // group 0..7 within wave
    int l8 = lane & 7;        // lane within group (covers 4 feats)
    int idx = blockIdx.x * 32 + w * 8 + grp;
    bool rok = idx < n;
    int r = rok ? rowperm[idx] : 0;
    int start = rowstart[r];
    int deg = rowstart[r + 1] - start;
    float dnr = dnorm[r];
    if (!rok) { deg = 0; dnr = 0.f; }
    int len = deg + 1;        // + self loop

    for (int c = 0; c < 4; c++) {
        const unsigned long long* phc = ph64 + (size_t)c * (N_NODES * 8); // 32 feats = 8 ull/row
        float4 bi4 = *(const float4*)&bias[c * 32 + l8 * 4];
        float a0 = 0.f, a1 = 0.f, a2 = 0.f, a3 = 0.f;
        for (int j = 0; j < len; j += 4) {
#pragma unroll
            for (int u = 0; u < 4; u++) {
                int i = j + u;
                int sl = srcl[min(start + i, EMAX)];
                int s = (i < deg) ? sl : r;
                float wt = (i < len) ? 1.f : 0.f;
                unsigned long long uv = phc[(size_t)s * 8 + l8];
                unsigned lo = (unsigned)uv, hi = (unsigned)(uv >> 32);
                a0 += wt * bf2f((unsigned short)lo);
                a1 += wt * bf2f((unsigned short)(lo >> 16));
                a2 += wt * bf2f((unsigned short)hi);
                a3 += wt * bf2f((unsigned short)(hi >> 16));
            }
        }
        float v0 = a0 * dnr + bi4.x;
        float v1 = a1 * dnr + bi4.y;
        float v2 = a2 * dnr + bi4.z;
        float v3 = a3 * dnr + bi4.w;
        v0 = v0 > 0.f ? v0 : 0.01f * v0;
        v1 = v1 > 0.f ? v1 : 0.01f * v1;
        v2 = v2 > 0.f ? v2 : 0.01f * v2;
        v3 = v3 > 0.f ? v3 : 0.01f * v3;
        if (rok) {
            ushort4 ov;
            ov.x = f2us(v0); ov.y = f2us(v1); ov.z = f2us(v2); ov.w = f2us(v3);
            *(ushort4*)(outbb + (size_t)r * 128 + c * 32 + l8 * 4) = ov;
        } else {
            v0 = v1 = v2 = v3 = 0.f;
        }
        float q0 = v0 * v0, q1 = v1 * v1, q2 = v2 * v2, q3 = v3 * v3;
        // reduce across the 8 groups of this wave (same features at same l8)
#pragma unroll
        for (int mk = 8; mk < 64; mk <<= 1) {
            v0 += __shfl_xor(v0, mk, 64); v1 += __shfl_xor(v1, mk, 64);
            v2 += __shfl_xor(v2, mk, 64); v3 += __shfl_xor(v3, mk, 64);
            q0 += __shfl_xor(q0, mk, 64); q1 += __shfl_xor(q1, mk, 64);
            q2 += __shfl_xor(q2, mk, 64); q3 += __shfl_xor(q3, mk, 64);
        }
        if (grp == 0) {
            int f = c * 32 + l8 * 4;
            atomicAdd(&bsm[f + 0], v0); atomicAdd(&bsm[f + 1], v1);
            atomicAdd(&bsm[f + 2], v2); atomicAdd(&bsm[f + 3], v3);
            atomicAdd(&bqm[f + 0], q0); atomicAdd(&bqm[f + 1], q1);
            atomicAdd(&bqm[f + 2], q2); atomicAdd(&bqm[f + 3], q3);
        }
    }
    __syncthreads();
    if (t < 128) {
        atomicAdd(&stats[t], bsm[t]);
        atomicAdd(&stats[128 + t], bqm[t]);
    }
}

// ---- segmented mean pool (bf16 input); BN scale/shift computed in-block ----
__global__ __launch_bounds__(256) void k_pool2(const unsigned short* __restrict__ outbb,
    const int* __restrict__ gstart, const float* __restrict__ stats,
    const float* __restrict__ bng, const float* __restrict__ bnb,
    float* __restrict__ gemb)
{
    __shared__ float scs[128], shs[128];
    int g = blockIdx.x;
    int t = threadIdx.x;
    if (t < 128) {
        float inv_n = 1.0f / (float)N_NODES;
        float mu = stats[t] * inv_n;
        float var = stats[128 + t] * inv_n - mu * mu;
        float rs = rsqrtf(var + 1e-5f);
        float sc = rs * bng[t];
        scs[t] = sc;
        shs[t] = bnb[t] - mu * sc;
    }
    __syncthreads();
    int f = t & 127;
    int half = t >> 7;
    int start = gstart[g], end = gstart[g + 1];
    int cnt = end - start;
    float s0 = 0.f, s1 = 0.f, s2 = 0.f, s3 = 0.f;
    int r = start + half;
    for (; r + 6 < end; r += 8) {
        s0 += bf2f(outbb[(size_t)(r    ) * 128 + f]);
        s1 += bf2f(outbb[(size_t)(r + 2) * 128 + f]);
        s2 += bf2f(outbb[(size_t)(r + 4) * 128 + f]);
        s3 += bf2f(outbb[(size_t)(r + 6) * 128 + f]);
    }
    for (; r < end; r += 2) s0 += bf2f(outbb[(size_t)r * 128 + f]);
    float sum = (s0 + s1) + (s2 + s3);
    __shared__ float sb[256];
    sb[t] = sum;
    __syncthreads();
    if (t < 128) {
        float tot = sb[t] + sb[t + 128];
        float v = (cnt > 0) ? (tot / (float)cnt) * scs[f] + shs[f] : 0.f;
        gemb[(size_t)g * 128 + f] = v;
    }
}

// ---- fused head layer 1 for both heads ----
__global__ __launch_bounds__(256) void k_head1x(const float* __restrict__ gemb,
    const float* __restrict__ textf,
    const float* __restrict__ gW1, const float* __restrict__ gb1,
    const float* __restrict__ tW1, const float* __restrict__ tb1,
    float* __restrict__ projg, float* __restrict__ projt)
{
    __shared__ float ins[8][768];
    int bx = blockIdx.x;
    int chunk = blockIdx.y;
    int isT = bx >= 32;
    int rb = isT ? bx - 32 : bx;
    const float* in = isT ? textf : gemb;
    int K = isT ? T_EMB : HID;
    const float* W = isT ? tW1 : gW1;
    const float* b = isT ? tb1 : gb1;
    float* outp = isT ? projt : projg;

    int t = threadIdx.x;
    int tot = 8 * K;
    for (int l = t; l < tot; l += 256) {
        int r = l / K, k = l - r * K;
        ins[r][k] = in[(size_t)(rb * 8 + r) * K + k];
    }
    __syncthreads();
    int col = chunk * 128 + (t & 127);
    int rg = t >> 7;
    float acc[4] = { 0.f, 0.f, 0.f, 0.f };
    for (int k = 0; k < K; k++) {
        float w = W[(size_t)k * 512 + col];
#pragma unroll
        for (int i = 0; i < 4; i++) acc[i] += ins[rg * 4 + i][k] * w;
    }
    float bias = b[col];
#pragma unroll
    for (int i = 0; i < 4; i++) {
        int row = rb * 8 + rg * 4 + i;
        outp[(size_t)row * 512 + col] = acc[i] + bias;
    }
}

// ---- fused head2 + LayerNorm + classifier + log_softmax, both heads ----
__global__ __launch_bounds__(256) void k_head2c(
    const float* __restrict__ projg, const float* __restrict__ projt,
    const float* __restrict__ gW2, const float* __restrict__ gb2,
    const float* __restrict__ gg, const float* __restrict__ gbe,
    const float* __restrict__ gclW, const float* __restrict__ gclb,
    const float* __restrict__ tW2, const float* __restrict__ tb2,
    const float* __restrict__ tg, const float* __restrict__ tbe,
    const float* __restrict__ tclW, const float* __restrict__ tclb,
    float* __restrict__ o_gproj, float* __restrict__ o_tproj,
    float* __restrict__ o_glogp, float* __restrict__ o_tlogp)
{
    __shared__ float prow[512], grow[512], onorm[512], red[256];
    __shared__ float part[8][32];
    __shared__ float logits[32];
    __shared__ float mred, lred;
    int bx = blockIdx.x;
    int isT = bx >= N_GRAPHS;
    int row = isT ? bx - N_GRAPHS : bx;
    const float* proj = isT ? projt : projg;
    const float* W2 = isT ? tW2 : gW2;
    const float* b2 = isT ? tb2 : gb2;
    const float* g  = isT ? tg  : gg;
    const float* be = isT ? tbe : gbe;
    const float* Wc = isT ? tclW : gclW;
    const float* bc = isT ? tclb : gclb;
    float* oproj = isT ? o_tproj : o_gproj;
    float* ologp = isT ? o_tlogp : o_glogp;

    int t = threadIdx.x;
    for (int c = t; c < 512; c += 256) {
        float p = proj[(size_t)row * 512 + c];
        prow[c] = p;
        grow[c] = 0.5f * p * (1.0f + erff(p * 0.70710678118f));
    }
    __syncthreads();
    float a0 = 0.f, a1 = 0.f;
    int c0 = t, c1 = t + 256;
    for (int k = 0; k < 512; k++) {
        float gk = grow[k];
        a0 += gk * W2[(size_t)k * 512 + c0];
        a1 += gk * W2[(size_t)k * 512 + c1];
    }
    float h0 = a0 + b2[c0] + prow[c0];
    float h1 = a1 + b2[c1] + prow[c1];
    red[t] = h0 + h1;
    __syncthreads();
    for (int s = 128; s > 0; s >>= 1) { if (t < s) red[t] += red[t + s]; __syncthreads(); }
    float mu = red[0] * (1.0f / 512.0f);
    __syncthreads();
    float d0 = h0 - mu, d1 = h1 - mu;
    red[t] = d0 * d0 + d1 * d1;
    __syncthreads();
    for (int s = 128; s > 0; s >>= 1) { if (t < s) red[t] += red[t + s]; __syncthreads(); }
    float rs = rsqrtf(red[0] * (1.0f / 512.0f) + 1e-5f);
    float o0 = d0 * rs * g[c0] + be[c0];
    float o1 = d1 * rs * g[c1] + be[c1];
    onorm[c0] = o0;
    onorm[c1] = o1;
    oproj[(size_t)row * 512 + c0] = o0;
    oproj[(size_t)row * 512 + c1] = o1;
    __syncthreads();

    int c = t & 31, seg = t >> 5;
    float p = 0.f;
    for (int k = seg * 64; k < seg * 64 + 64; k++)
        p += onorm[k] * Wc[(size_t)k * 32 + c];
    part[seg][c] = p;
    __syncthreads();
    if (t < 32) {
        float l = bc[t];
#pragma unroll
        for (int s = 0; s < 8; s++) l += part[s][t];
        logits[t] = l;
    }
    __syncthreads();
    if (t == 0) {
        float m = logits[0];
        for (int i = 1; i < 32; i++) m = fmaxf(m, logits[i]);
        float sum = 0.f;
        for (int i = 0; i < 32; i++) sum += expf(logits[i] - m);
        mred = m; lred = logf(sum);
    }
    __syncthreads();
    if (t < 32) ologp[(size_t)row * 32 + t] = logits[t] - mred - lred;
}

extern "C" void kernel_launch(void* const* d_in, const int* in_sizes, int n_in,
                              void* d_out, int out_size, void* d_ws, size_t ws_size,
                              hipStream_t stream) {
    const float* x     = (const float*)d_in[0];
    const int*   ei    = (const int*)d_in[1];
    const int*   batch = (const int*)d_in[2];
    const float* textf = (const float*)d_in[3];
    const float* gcnW  = (const float*)d_in[4];
    const float* gcnb  = (const float*)d_in[5];
    const float* bng   = (const float*)d_in[6];
    const float* bnb   = (const float*)d_in[7];
    const float* gW1   = (const float*)d_in[8];
    const float* gb1   = (const float*)d_in[9];
    const float* gW2   = (const float*)d_in[10];
    const float* gb2   = (const float*)d_in[11];
    const float* gg    = (const float*)d_in[12];
    const float* gbe   = (const float*)d_in[13];
    const float* gclW  = (const float*)d_in[14];
    const float* gclb  = (const float*)d_in[15];
    const float* tW1   = (const float*)d_in[16];
    const float* tb1   = (const float*)d_in[17];
    const float* tW2   = (const float*)d_in[18];
    const float* tb2   = (const float*)d_in[19];
    const float* tg    = (const float*)d_in[20];
    const float* tbe   = (const float*)d_in[21];
    const float* tclW  = (const float*)d_in[22];
    const float* tclb  = (const float*)d_in[23];

    const int N = N_NODES, E = N_EDGES;
    const int NF = N * HID;

    float* p = (float*)d_ws;
    unsigned short* outbb = (unsigned short*)p; p += NF / 2;   // 12.8 MB bf16
    unsigned short* ph    = (unsigned short*)p; p += NF / 2;   // 12.8 MB bf16 chunk-major
    unsigned short* Wt    = (unsigned short*)p; p += 4 * 16384 / 2;
    float* dnorm = p; p += N;
    float* gemb  = p; p += N_GRAPHS * HID;
    float* projg = p; p += N_GRAPHS * PROJ;
    float* projt = p; p += N_GRAPHS * PROJ;
    // contiguous zero-init region: cnt | cursor | stats4 | dhist
    int* cnt      = (int*)p; p += N;
    int* cursor   = (int*)p; p += N;
    float* stats4 = p; p += 4 * 256;
    int* dhist    = (int*)p; p += DBINS;
    int* rowstart = (int*)p; p += N + 1;
    int* gstart   = (int*)p; p += N_GRAPHS + 1;
    int* bsum     = (int*)p; p += 256;
    int* srcl     = (int*)p; p += E;
    int* doff     = (int*)p; p += DBINS;
    int* rowperm  = (int*)p; p += N;

    float* outp = (float*)d_out;
    float* o_gproj = outp;
    float* o_tproj = outp + N_GRAPHS * PROJ;
    float* o_glogp = o_tproj + N_GRAPHS * PROJ;
    float* o_tlogp = o_glogp + N_GRAPHS * N_CLS;

    // ---- CSR build + degree-sort + prep ----
    hipMemsetAsync(cnt, 0, (size_t)(2 * N + 4 * 256 + DBINS) * sizeof(int), stream);
    k_deg<<<(E + 255) / 256, 256, 0, stream>>>(ei, cnt, E);
    k_scan1<<<NB_SCAN, 256, 0, stream>>>(cnt, rowstart, dnorm, bsum);
    k_scan2<<<1, 256, 0, stream>>>(bsum);
    k_scan3<<<NB_SCAN, 256, 0, stream>>>(rowstart, bsum, cnt, dhist);
    k_fill<<<(E + 255) / 256, 256, 0, stream>>>(ei, rowstart, cursor, srcl, E);
    k_dscan<<<1, 256, 0, stream>>>(dhist, doff);
    k_dperm<<<(N + 1023) / 1024, 1024, 0, stream>>>(cnt, doff, rowperm);
    k_prep<<<(4 * 16384 + N + 1 + 255) / 256, 256, 0, stream>>>(gcnW, Wt, batch, gstart);

    // ---- 4 GCN layers (BN of layer l-1 folded into mm of layer l) ----
    for (int l = 0; l < 4; l++) {
        const void* in = (l == 0) ? (const void*)x : (const void*)outbb;
        const float* st = (l == 0) ? nullptr : stats4 + (l - 1) * 256;
        const float* bg = (l == 0) ? nullptr : bng + (size_t)(l - 1) * HID;
        const float* bb = (l == 0) ? nullptr : bnb + (size_t)(l - 1) * HID;
        k_gcn_mm_mfma<<<(N + 63) / 64, 256, 0, stream>>>(in, Wt + (size_t)l * 16384,
                                                         st, bg, bb, dnorm, ph, N);
        k_gather_c<<<(N + 31) / 32, 256, 0, stream>>>((const unsigned long long*)ph, srcl,
                                                      rowstart, rowperm, dnorm,
                                                      gcnb + (size_t)l * HID, outbb,
                                                      stats4 + l * 256, N);
    }

    // ---- segmented mean pool (layer-3 BN folded in-block) ----
    k_pool2<<<N_GRAPHS, 256, 0, stream>>>(outbb, gstart, stats4 + 3 * 256,
                                          bng + 3 * HID, bnb + 3 * HID, gemb);

    // ---- fused heads ----
    k_head1x<<<dim3(64, 4), 256, 0, stream>>>(gemb, textf, gW1, gb1, tW1, tb1, projg, projt);
    k_head2c<<<2 * N_GRAPHS, 256, 0, stream>>>(projg, projt,
                                               gW2, gb2, gg, gbe, gclW, gclb,
                                               tW2, tb2, tg, tbe, tclW, tclb,
                                               o_gproj, o_tproj, o_glogp, o_tlogp);
}

// Round 4
// 561.284 us; speedup vs baseline: 1.7075x; 1.1042x over previous
//
#include <hip/hip_runtime.h>
#include <hip/hip_bf16.h>

// Problem sizes (fixed by reference)
#define N_NODES 50000
#define N_EDGES 800000
#define F_IN    128
#define HID     128
#define PROJ    512
#define N_CLS   32
#define N_GRAPHS 256
#define T_EMB   768
#define NB_SCAN ((N_NODES + 255) / 256)   // 196
#define DBINS   1024
#define NBROW   ((N_NODES + 63) / 64)     // 782 row-blocks (64 rows each)

typedef __attribute__((ext_vector_type(8))) short bf16x8;
typedef __attribute__((ext_vector_type(4))) float f32x4;

__device__ __forceinline__ float bf2f(unsigned short u) {
    unsigned v = ((unsigned)u) << 16;
    return __uint_as_float(v);
}
__device__ __forceinline__ unsigned short f2us(float v) {
    __hip_bfloat16 b = __float2bfloat16(v);
    union { __hip_bfloat16 b; unsigned short u; } c; c.b = b; return c.u;
}

// ---- degree histogram (int atomics over dst) ----
__global__ void k_deg(const int* __restrict__ ei, int* __restrict__ cnt, int nE) {
    int e = blockIdx.x * 256 + threadIdx.x;
    if (e < nE) atomicAdd(cnt + ei[nE + e], 1);
}

// ---- parallel scan pass 1 ----
__global__ __launch_bounds__(256) void k_scan1(const int* __restrict__ cnt,
    int* __restrict__ rowstart, float* __restrict__ dnorm, int* __restrict__ bsum)
{
    __shared__ int ps[256];
    int t = threadIdx.x;
    int i = blockIdx.x * 256 + t;
    int c = (i < N_NODES) ? cnt[i] : 0;
    if (i < N_NODES) dnorm[i] = rsqrtf((float)c + 1.0f);
    ps[t] = c;
    __syncthreads();
    for (int off = 1; off < 256; off <<= 1) {
        int v = (t >= off) ? ps[t - off] : 0;
        __syncthreads();
        ps[t] += v;
        __syncthreads();
    }
    if (i < N_NODES) rowstart[i] = ps[t] - c;
    if (t == 255) bsum[blockIdx.x] = ps[255];
}

// ---- scan pass 2 ----
__global__ __launch_bounds__(256) void k_scan2(int* __restrict__ bsum) {
    __shared__ int ps[256];
    int t = threadIdx.x;
    int v = (t < NB_SCAN) ? bsum[t] : 0;
    ps[t] = v;
    __syncthreads();
    for (int off = 1; off < 256; off <<= 1) {
        int u = (t >= off) ? ps[t - off] : 0;
        __syncthreads();
        ps[t] += u;
        __syncthreads();
    }
    if (t < NB_SCAN) bsum[t] = ps[t] - v;
}

// ---- scan pass 3 (+ LDS-aggregated degree histogram for LPT sort) ----
__global__ __launch_bounds__(256) void k_scan3(int* __restrict__ rowstart,
    const int* __restrict__ bsum, const int* __restrict__ cnt,
    int* __restrict__ dhist)
{
    __shared__ int lh[DBINS];
    int t = threadIdx.x;
    for (int k = t; k < DBINS; k += 256) lh[k] = 0;
    __syncthreads();
    int i = blockIdx.x * 256 + t;
    if (i < N_NODES) {
        rowstart[i] += bsum[blockIdx.x];
        atomicAdd(&lh[min(cnt[i], DBINS - 1)], 1);
    }
    if (i == 0) rowstart[N_NODES] = N_EDGES;
    __syncthreads();
    for (int k = t; k < DBINS; k += 256) {
        int v = lh[k];
        if (v) atomicAdd(dhist + k, v);
    }
}

// ---- descending-degree exclusive offsets: doff[d] = #rows with degree > d ----
__global__ __launch_bounds__(256) void k_dscan(const int* __restrict__ dhist,
                                               int* __restrict__ doff) {
    __shared__ int part[256];
    __shared__ int binv[DBINS];
    int t = threadIdx.x;
    int base = t * 4;
    int g0 = dhist[DBINS - 1 - (base + 0)];
    int g1 = dhist[DBINS - 1 - (base + 1)];
    int g2 = dhist[DBINS - 1 - (base + 2)];
    int g3 = dhist[DBINS - 1 - (base + 3)];
    int s = g0 + g1 + g2 + g3;
    part[t] = s;
    __syncthreads();
    for (int off = 1; off < 256; off <<= 1) {
        int v = (t >= off) ? part[t - off] : 0;
        __syncthreads();
        part[t] += v;
        __syncthreads();
    }
    int run = part[t] - s;   // exclusive prefix of this thread's 4 bins
    binv[base + 0] = run; run += g0;
    binv[base + 1] = run; run += g1;
    binv[base + 2] = run; run += g2;
    binv[base + 3] = run; run += g3;
    __syncthreads();
    for (int k = t; k < DBINS; k += 256) doff[DBINS - 1 - k] = binv[k];
}

// ---- scatter rows into degree-descending permutation (two-phase, LDS ranks;
// one global atomic per non-empty bin per block -> no same-address storm) ----
__global__ __launch_bounds__(1024) void k_dperm(const int* __restrict__ cnt,
    int* __restrict__ doff, int* __restrict__ rowperm)
{
    __shared__ int lh[DBINS];
    __shared__ int lbase[DBINS];
    int t = threadIdx.x;
    if (t < DBINS) lh[t] = 0;
    __syncthreads();
    int i = blockIdx.x * 1024 + t;
    int bin = 0, lrank = 0;
    bool ok = i < N_NODES;
    if (ok) {
        bin = min(cnt[i], DBINS - 1);
        lrank = atomicAdd(&lh[bin], 1);
    }
    __syncthreads();
    if (t < DBINS) {
        int v = lh[t];
        if (v) lbase[t] = atomicAdd(doff + t, v);
    }
    __syncthreads();
    if (ok) rowperm[lbase[bin] + lrank] = i;
}

// ---- fill CSR src lists ----
__global__ void k_fill(const int* __restrict__ ei, const int* __restrict__ rowstart,
                       int* __restrict__ cursor, int* __restrict__ srcl, int nE) {
    int e = blockIdx.x * 256 + threadIdx.x;
    if (e >= nE) return;
    int s = ei[e];
    int d = ei[nE + e];
    int pos = rowstart[d] + atomicAdd(cursor + d, 1);
    srcl[pos] = s;
}

// ---- combined prep: weight transpose+bf16 and graph boundaries ----
__global__ void k_prep(const float* __restrict__ W, unsigned short* __restrict__ Wt,
                       const int* __restrict__ batch, int* __restrict__ gstart) {
    int t = blockIdx.x * 256 + threadIdx.x;
    if (t < 4 * 128 * 128) {
        int l = t >> 14;
        int k = (t >> 7) & 127;
        int n = t & 127;
        Wt[(size_t)l * 16384 + n * 128 + k] = f2us(W[(size_t)l * 16384 + k * 128 + n]);
    } else {
        int r = t - 4 * 128 * 128;
        if (r <= N_NODES) {
            int b  = (r < N_NODES) ? batch[r] : N_GRAPHS;
            int bp = (r > 0) ? batch[r - 1] : -1;
            for (int g = bp + 1; g <= b && g <= N_GRAPHS; g++) gstart[g] = r;
        }
    }
}

// ---- GCN matmul via bf16 MFMA; direct global A-loads, BN fold in-register;
// epilogue transposed through LDS (reusing Bs) for coalesced uint4 stores.
// ph output is CHUNK-MAJOR: [4 chunks][N rows][32 feats] bf16. ----
__global__ __launch_bounds__(256) void k_gcn_mm_mfma(const void* __restrict__ inp,
    const unsigned short* __restrict__ Wt,   // [128 n][128 k] bf16 (n-major)
    const float* __restrict__ stats, const float* __restrict__ bng,
    const float* __restrict__ bnb, const float* __restrict__ dnorm,
    unsigned short* __restrict__ ph, int n)
{
    __shared__ __align__(16) unsigned short Bs[128][136];   // 34.8 KB (reused as C-staging)
    __shared__ float scs[128], shs[128];
    int t = threadIdx.x;
    int row0 = blockIdx.x * 64;

    if (stats && t < 128) {
        float inv_n = 1.0f / (float)N_NODES;
        float mu = stats[t] * inv_n;
        float var = stats[128 + t] * inv_n - mu * mu;
        float rs = rsqrtf(var + 1e-5f);
        float sc = rs * bng[t];
        scs[t] = sc;
        shs[t] = bnb[t] - mu * sc;
    }
#pragma unroll
    for (int i = 0; i < 8; i++) {
        int c = t + i * 256;
        int nn = c >> 4;
        int k8 = (c & 15) * 8;
        *(uint4*)&Bs[nn][k8] = *(const uint4*)(Wt + (size_t)nn * 128 + k8);
    }
    __syncthreads();

    int w = t >> 6, lane = t & 63;
    int m = lane & 15, quad = lane >> 4;
    int arow = row0 + w * 16 + m;        // this lane's A row
    bool rowok = arow < n;

    // load A fragments for all 4 k-chunks (16 B each, aligned)
    bf16x8 afrag[4];
    if (!stats) {
        const float* inf = (const float*)inp;
#pragma unroll
        for (int ki = 0; ki < 4; ki++) {
            int k8 = ki * 32 + quad * 8;
            float4 v0 = make_float4(0.f, 0.f, 0.f, 0.f);
            float4 v1 = make_float4(0.f, 0.f, 0.f, 0.f);
            if (rowok) {
                v0 = *(const float4*)(inf + (size_t)arow * 128 + k8);
                v1 = *(const float4*)(inf + (size_t)arow * 128 + k8 + 4);
            }
            union { unsigned short u[8]; bf16x8 v; } pk;
            pk.u[0] = f2us(v0.x); pk.u[1] = f2us(v0.y); pk.u[2] = f2us(v0.z); pk.u[3] = f2us(v0.w);
            pk.u[4] = f2us(v1.x); pk.u[5] = f2us(v1.y); pk.u[6] = f2us(v1.z); pk.u[7] = f2us(v1.w);
            afrag[ki] = pk.v;
        }
    } else {
        const unsigned short* inb = (const unsigned short*)inp;
#pragma unroll
        for (int ki = 0; ki < 4; ki++) {
            int k8 = ki * 32 + quad * 8;
            uint4 raw = make_uint4(0, 0, 0, 0);
            if (rowok) raw = *(const uint4*)(inb + (size_t)arow * 128 + k8);
            unsigned rr[4] = { raw.x, raw.y, raw.z, raw.w };
            union { unsigned short u[8]; bf16x8 v; } pk;
#pragma unroll
            for (int j = 0; j < 4; j++) {
                int f0 = k8 + 2 * j, f1 = k8 + 2 * j + 1;
                float a0 = bf2f((unsigned short)rr[j]) * scs[f0] + shs[f0];
                float a1 = bf2f((unsigned short)(rr[j] >> 16)) * scs[f1] + shs[f1];
                pk.u[2 * j] = f2us(a0);
                pk.u[2 * j + 1] = f2us(a1);
            }
            afrag[ki] = pk.v;
        }
    }

    f32x4 acc[8];
#pragma unroll
    for (int nt = 0; nt < 8; nt++) acc[nt] = (f32x4){0.f, 0.f, 0.f, 0.f};
#pragma unroll
    for (int ki = 0; ki < 4; ki++) {
#pragma unroll
        for (int nt = 0; nt < 8; nt++) {
            bf16x8 b = *(const bf16x8*)&Bs[nt * 16 + m][ki * 32 + quad * 8];
            acc[nt] = __builtin_amdgcn_mfma_f32_16x16x32_bf16(afrag[ki], b, acc[nt], 0, 0, 0);
        }
    }

    float dn[4];
#pragma unroll
    for (int reg = 0; reg < 4; reg++) {
        int gr = row0 + w * 16 + quad * 4 + reg;
        dn[reg] = (gr < n) ? dnorm[gr] : 0.f;
    }

    // ---- epilogue: transpose C through LDS (reuse Bs), store chunk-major ----
    __syncthreads();   // all waves finished reading Bs
#pragma unroll
    for (int nt = 0; nt < 8; nt++) {
#pragma unroll
        for (int reg = 0; reg < 4; reg++) {
            Bs[w * 16 + quad * 4 + reg][nt * 16 + m] = f2us(acc[nt][reg] * dn[reg]);
        }
    }
    __syncthreads();
#pragma unroll
    for (int i = 0; i < 4; i++) {
        int idx = t + i * 256;           // 0..1023
        int r = idx >> 4;                // 0..63
        int c8 = (idx & 15) * 8;         // 0..120
        int gr = row0 + r;
        int ch = c8 >> 5;                // chunk 0..3
        int off = c8 & 31;               // 0,8,16,24
        if (gr < n)
            *(uint4*)(ph + (size_t)ch * (N_NODES * 32) + (size_t)gr * 32 + off)
                = *(const uint4*)&Bs[r][c8];
    }
}

// ---- feature-chunked pair-gather v4: one CHUNK per block (grid = NBROW x 4,
// chunk-outer so co-resident blocks share a 3.2 MB slice), 64 rows/block,
// 4-lane groups with 16-B loads -> 16 rows/wave, 64 loads in flight/wave.
// Attacks the measured miss-latency bound (round-3: 0.96 TB/s eff., occ 40%). ----
__global__ __launch_bounds__(256) void k_gather_c(const uint4* __restrict__ ph128,
    const int* __restrict__ srcl, const int* __restrict__ rowstart,
    const int* __restrict__ rowperm, const float* __restrict__ dnorm,
    const float* __restrict__ bias, unsigned short* __restrict__ outbb,
    float* __restrict__ stats, int n)
{
    const int EMAX = N_EDGES - 1;
    __shared__ float bsm[32], bqm[32];
    int t = threadIdx.x;
    if (t < 32) { bsm[t] = 0.f; bqm[t] = 0.f; }
    __syncthreads();

    int bx = blockIdx.x;
    int c = bx / NBROW;            // chunk 0..3 (outer -> co-resident blocks same slice)
    int rb = bx - c * NBROW;
    int lane = t & 63;
    int w = t >> 6;                // wave 0..3
    int grp = lane >> 2;           // group 0..15 within wave (one row each)
    int l4 = lane & 3;             // lane in group: 8 feats (16 B) each
    int idx = rb * 64 + w * 16 + grp;
    bool rok = idx < n;
    int r = rok ? rowperm[idx] : 0;
    int start = rowstart[r];
    int deg = rowstart[r + 1] - start;
    float dnr = dnorm[r];
    if (!rok) { deg = 0; dnr = 0.f; }
    int len = deg + 1;             // + self loop

    const uint4* phc = ph128 + (size_t)c * (N_NODES * 4);   // 4 uint4 per 32-feat row

    float bi[8];
#pragma unroll
    for (int k = 0; k < 8; k++) bi[k] = bias[c * 32 + l4 * 8 + k];

    float a[8];
#pragma unroll
    for (int k = 0; k < 8; k++) a[k] = 0.f;

    for (int j = 0; j < len; j += 4) {
        uint4 uv[4];
#pragma unroll
        for (int u = 0; u < 4; u++) {
            int i = j + u;
            int sl = srcl[min(start + i, EMAX)];
            int s = (i < deg) ? sl : r;
            uv[u] = phc[(size_t)s * 4 + l4];
        }
#pragma unroll
        for (int u = 0; u < 4; u++) {
            int i = j + u;
            float wt = (i < len) ? 1.f : 0.f;
            unsigned rr[4] = { uv[u].x, uv[u].y, uv[u].z, uv[u].w };
#pragma unroll
            for (int d = 0; d < 4; d++) {
                a[2 * d]     += wt * bf2f((unsigned short)rr[d]);
                a[2 * d + 1] += wt * bf2f((unsigned short)(rr[d] >> 16));
            }
        }
    }

    float v[8];
#pragma unroll
    for (int k = 0; k < 8; k++) {
        float x = a[k] * dnr + bi[k];
        v[k] = x > 0.f ? x : 0.01f * x;
    }
    if (rok) {
        union { unsigned short us[8]; uint4 u; } ov;
#pragma unroll
        for (int k = 0; k < 8; k++) ov.us[k] = f2us(v[k]);
        *(uint4*)(outbb + (size_t)r * 128 + c * 32 + l4 * 8) = ov.u;
    } else {
#pragma unroll
        for (int k = 0; k < 8; k++) v[k] = 0.f;
    }

    float q[8];
#pragma unroll
    for (int k = 0; k < 8; k++) q[k] = v[k] * v[k];
    // reduce across the 16 groups of this wave (same feature at same l4)
#pragma unroll
    for (int mk = 4; mk < 64; mk <<= 1) {
#pragma unroll
        for (int k = 0; k < 8; k++) {
            v[k] += __shfl_xor(v[k], mk, 64);
            q[k] += __shfl_xor(q[k], mk, 64);
        }
    }
    if (grp == 0) {
#pragma unroll
        for (int k = 0; k < 8; k++) {
            atomicAdd(&bsm[l4 * 8 + k], v[k]);
            atomicAdd(&bqm[l4 * 8 + k], q[k]);
        }
    }
    __syncthreads();
    if (t < 32) {
        atomicAdd(&stats[c * 32 + t], bsm[t]);
        atomicAdd(&stats[128 + c * 32 + t], bqm[t]);
    }
}

// ---- segmented mean pool (bf16 input); BN scale/shift computed in-block ----
__global__ __launch_bounds__(256) void k_pool2(const unsigned short* __restrict__ outbb,
    const int* __restrict__ gstart, const float* __restrict__ stats,
    const float* __restrict__ bng, const float* __restrict__ bnb,
    float* __restrict__ gemb)
{
    __shared__ float scs[128], shs[128];
    int g = blockIdx.x;
    int t = threadIdx.x;
    if (t < 128) {
        float inv_n = 1.0f / (float)N_NODES;
        float mu = stats[t] * inv_n;
        float var = stats[128 + t] * inv_n - mu * mu;
        float rs = rsqrtf(var + 1e-5f);
        float sc = rs * bng[t];
        scs[t] = sc;
        shs[t] = bnb[t] - mu * sc;
    }
    __syncthreads();
    int f = t & 127;
    int half = t >> 7;
    int start = gstart[g], end = gstart[g + 1];
    int cnt = end - start;
    float s0 = 0.f, s1 = 0.f, s2 = 0.f, s3 = 0.f;
    int r = start + half;
    for (; r + 6 < end; r += 8) {
        s0 += bf2f(outbb[(size_t)(r    ) * 128 + f]);
        s1 += bf2f(outbb[(size_t)(r + 2) * 128 + f]);
        s2 += bf2f(outbb[(size_t)(r + 4) * 128 + f]);
        s3 += bf2f(outbb[(size_t)(r + 6) * 128 + f]);
    }
    for (; r < end; r += 2) s0 += bf2f(outbb[(size_t)r * 128 + f]);
    float sum = (s0 + s1) + (s2 + s3);
    __shared__ float sb[256];
    sb[t] = sum;
    __syncthreads();
    if (t < 128) {
        float tot = sb[t] + sb[t + 128];
        float v = (cnt > 0) ? (tot / (float)cnt) * scs[f] + shs[f] : 0.f;
        gemb[(size_t)g * 128 + f] = v;
    }
}

// ---- fused head layer 1 for both heads ----
__global__ __launch_bounds__(256) void k_head1x(const float* __restrict__ gemb,
    const float* __restrict__ textf,
    const float* __restrict__ gW1, const float* __restrict__ gb1,
    const float* __restrict__ tW1, const float* __restrict__ tb1,
    float* __restrict__ projg, float* __restrict__ projt)
{
    __shared__ float ins[8][768];
    int bx = blockIdx.x;
    int chunk = blockIdx.y;
    int isT = bx >= 32;
    int rb = isT ? bx - 32 : bx;
    const float* in = isT ? textf : gemb;
    int K = isT ? T_EMB : HID;
    const float* W = isT ? tW1 : gW1;
    const float* b = isT ? tb1 : gb1;
    float* outp = isT ? projt : projg;

    int t = threadIdx.x;
    int tot = 8 * K;
    for (int l = t; l < tot; l += 256) {
        int r = l / K, k = l - r * K;
        ins[r][k] = in[(size_t)(rb * 8 + r) * K + k];
    }
    __syncthreads();
    int col = chunk * 128 + (t & 127);
    int rg = t >> 7;
    float acc[4] = { 0.f, 0.f, 0.f, 0.f };
    for (int k = 0; k < K; k++) {
        float w = W[(size_t)k * 512 + col];
#pragma unroll
        for (int i = 0; i < 4; i++) acc[i] += ins[rg * 4 + i][k] * w;
    }
    float bias = b[col];
#pragma unroll
    for (int i = 0; i < 4; i++) {
        int row = rb * 8 + rg * 4 + i;
        outp[(size_t)row * 512 + col] = acc[i] + bias;
    }
}

// ---- fused head2 + LayerNorm + classifier + log_softmax, both heads ----
__global__ __launch_bounds__(256) void k_head2c(
    const float* __restrict__ projg, const float* __restrict__ projt,
    const float* __restrict__ gW2, const float* __restrict__ gb2,
    const float* __restrict__ gg, const float* __restrict__ gbe,
    const float* __restrict__ gclW, const float* __restrict__ gclb,
    const float* __restrict__ tW2, const float* __restrict__ tb2,
    const float* __restrict__ tg, const float* __restrict__ tbe,
    const float* __restrict__ tclW, const float* __restrict__ tclb,
    float* __restrict__ o_gproj, float* __restrict__ o_tproj,
    float* __restrict__ o_glogp, float* __restrict__ o_tlogp)
{
    __shared__ float prow[512], grow[512], onorm[512], red[256];
    __shared__ float part[8][32];
    __shared__ float logits[32];
    __shared__ float mred, lred;
    int bx = blockIdx.x;
    int isT = bx >= N_GRAPHS;
    int row = isT ? bx - N_GRAPHS : bx;
    const float* proj = isT ? projt : projg;
    const float* W2 = isT ? tW2 : gW2;
    const float* b2 = isT ? tb2 : gb2;
    const float* g  = isT ? tg  : gg;
    const float* be = isT ? tbe : gbe;
    const float* Wc = isT ? tclW : gclW;
    const float* bc = isT ? tclb : gclb;
    float* oproj = isT ? o_tproj : o_gproj;
    float* ologp = isT ? o_tlogp : o_glogp;

    int t = threadIdx.x;
    for (int c = t; c < 512; c += 256) {
        float p = proj[(size_t)row * 512 + c];
        prow[c] = p;
        grow[c] = 0.5f * p * (1.0f + erff(p * 0.70710678118f));
    }
    __syncthreads();
    float a0 = 0.f, a1 = 0.f;
    int c0 = t, c1 = t + 256;
    for (int k = 0; k < 512; k++) {
        float gk = grow[k];
        a0 += gk * W2[(size_t)k * 512 + c0];
        a1 += gk * W2[(size_t)k * 512 + c1];
    }
    float h0 = a0 + b2[c0] + prow[c0];
    float h1 = a1 + b2[c1] + prow[c1];
    red[t] = h0 + h1;
    __syncthreads();
    for (int s = 128; s > 0; s >>= 1) { if (t < s) red[t] += red[t + s]; __syncthreads(); }
    float mu = red[0] * (1.0f / 512.0f);
    __syncthreads();
    float d0 = h0 - mu, d1 = h1 - mu;
    red[t] = d0 * d0 + d1 * d1;
    __syncthreads();
    for (int s = 128; s > 0; s >>= 1) { if (t < s) red[t] += red[t + s]; __syncthreads(); }
    float rs = rsqrtf(red[0] * (1.0f / 512.0f) + 1e-5f);
    float o0 = d0 * rs * g[c0] + be[c0];
    float o1 = d1 * rs * g[c1] + be[c1];
    onorm[c0] = o0;
    onorm[c1] = o1;
    oproj[(size_t)row * 512 + c0] = o0;
    oproj[(size_t)row * 512 + c1] = o1;
    __syncthreads();

    int c = t & 31, seg = t >> 5;
    float p = 0.f;
    for (int k = seg * 64; k < seg * 64 + 64; k++)
        p += onorm[k] * Wc[(size_t)k * 32 + c];
    part[seg][c] = p;
    __syncthreads();
    if (t < 32) {
        float l = bc[t];
#pragma unroll
        for (int s = 0; s < 8; s++) l += part[s][t];
        logits[t] = l;
    }
    __syncthreads();
    if (t == 0) {
        float m = logits[0];
        for (int i = 1; i < 32; i++) m = fmaxf(m, logits[i]);
        float sum = 0.f;
        for (int i = 0; i < 32; i++) sum += expf(logits[i] - m);
        mred = m; lred = logf(sum);
    }
    __syncthreads();
    if (t < 32) ologp[(size_t)row * 32 + t] = logits[t] - mred - lred;
}

extern "C" void kernel_launch(void* const* d_in, const int* in_sizes, int n_in,
                              void* d_out, int out_size, void* d_ws, size_t ws_size,
                              hipStream_t stream) {
    const float* x     = (const float*)d_in[0];
    const int*   ei    = (const int*)d_in[1];
    const int*   batch = (const int*)d_in[2];
    const float* textf = (const float*)d_in[3];
    const float* gcnW  = (const float*)d_in[4];
    const float* gcnb  = (const float*)d_in[5];
    const float* bng   = (const float*)d_in[6];
    const float* bnb   = (const float*)d_in[7];
    const float* gW1   = (const float*)d_in[8];
    const float* gb1   = (const float*)d_in[9];
    const float* gW2   = (const float*)d_in[10];
    const float* gb2   = (const float*)d_in[11];
    const float* gg    = (const float*)d_in[12];
    const float* gbe   = (const float*)d_in[13];
    const float* gclW  = (const float*)d_in[14];
    const float* gclb  = (const float*)d_in[15];
    const float* tW1   = (const float*)d_in[16];
    const float* tb1   = (const float*)d_in[17];
    const float* tW2   = (const float*)d_in[18];
    const float* tb2   = (const float*)d_in[19];
    const float* tg    = (const float*)d_in[20];
    const float* tbe   = (const float*)d_in[21];
    const float* tclW  = (const float*)d_in[22];
    const float* tclb  = (const float*)d_in[23];

    const int N = N_NODES, E = N_EDGES;
    const int NF = N * HID;

    float* p = (float*)d_ws;
    unsigned short* outbb = (unsigned short*)p; p += NF / 2;   // 12.8 MB bf16
    unsigned short* ph    = (unsigned short*)p; p += NF / 2;   // 12.8 MB bf16 chunk-major
    unsigned short* Wt    = (unsigned short*)p; p += 4 * 16384 / 2;
    float* dnorm = p; p += N;
    float* gemb  = p; p += N_GRAPHS * HID;
    float* projg = p; p += N_GRAPHS * PROJ;
    float* projt = p; p += N_GRAPHS * PROJ;
    // contiguous zero-init region: cnt | cursor | stats4 | dhist
    int* cnt      = (int*)p; p += N;
    int* cursor   = (int*)p; p += N;
    float* stats4 = p; p += 4 * 256;
    int* dhist    = (int*)p; p += DBINS;
    int* rowstart = (int*)p; p += N + 1;
    int* gstart   = (int*)p; p += N_GRAPHS + 1;
    int* bsum     = (int*)p; p += 256;
    int* srcl     = (int*)p; p += E;
    int* doff     = (int*)p; p += DBINS;
    int* rowperm  = (int*)p; p += N;

    float* outp = (float*)d_out;
    float* o_gproj = outp;
    float* o_tproj = outp + N_GRAPHS * PROJ;
    float* o_glogp = o_tproj + N_GRAPHS * PROJ;
    float* o_tlogp = o_glogp + N_GRAPHS * N_CLS;

    // ---- CSR build + degree-sort + prep ----
    hipMemsetAsync(cnt, 0, (size_t)(2 * N + 4 * 256 + DBINS) * sizeof(int), stream);
    k_deg<<<(E + 255) / 256, 256, 0, stream>>>(ei, cnt, E);
    k_scan1<<<NB_SCAN, 256, 0, stream>>>(cnt, rowstart, dnorm, bsum);
    k_scan2<<<1, 256, 0, stream>>>(bsum);
    k_scan3<<<NB_SCAN, 256, 0, stream>>>(rowstart, bsum, cnt, dhist);
    k_fill<<<(E + 255) / 256, 256, 0, stream>>>(ei, rowstart, cursor, srcl, E);
    k_dscan<<<1, 256, 0, stream>>>(dhist, doff);
    k_dperm<<<(N + 1023) / 1024, 1024, 0, stream>>>(cnt, doff, rowperm);
    k_prep<<<(4 * 16384 + N + 1 + 255) / 256, 256, 0, stream>>>(gcnW, Wt, batch, gstart);

    // ---- 4 GCN layers (BN of layer l-1 folded into mm of layer l) ----
    for (int l = 0; l < 4; l++) {
        const void* in = (l == 0) ? (const void*)x : (const void*)outbb;
        const float* st = (l == 0) ? nullptr : stats4 + (l - 1) * 256;
        const float* bg = (l == 0) ? nullptr : bng + (size_t)(l - 1) * HID;
        const float* bb = (l == 0) ? nullptr : bnb + (size_t)(l - 1) * HID;
        k_gcn_mm_mfma<<<(N + 63) / 64, 256, 0, stream>>>(in, Wt + (size_t)l * 16384,
                                                         st, bg, bb, dnorm, ph, N);
        k_gather_c<<<NBROW * 4, 256, 0, stream>>>((const uint4*)ph, srcl,
                                                  rowstart, rowperm, dnorm,
                                                  gcnb + (size_t)l * HID, outbb,
                                                  stats4 + l * 256, N);
    }

    // ---- segmented mean pool (layer-3 BN folded in-block) ----
    k_pool2<<<N_GRAPHS, 256, 0, stream>>>(outbb, gstart, stats4 + 3 * 256,
                                          bng + 3 * HID, bnb + 3 * HID, gemb);

    // ---- fused heads ----
    k_head1x<<<dim3(64, 4), 256, 0, stream>>>(gemb, textf, gW1, gb1, tW1, tb1, projg, projt);
    k_head2c<<<2 * N_GRAPHS, 256, 0, stream>>>(projg, projt,
                                               gW2, gb2, gg, gbe, gclW, gclb,
                                               tW2, tb2, tg, tbe, tclW, tclb,
                                               o_gproj, o_tproj, o_glogp, o_tlogp);
}

// Round 5
// 490.757 us; speedup vs baseline: 1.9528x; 1.1437x over previous
//
#include <hip/hip_runtime.h>
#include <hip/hip_bf16.h>

// Problem sizes (fixed by reference)
#define N_NODES 50000
#define N_EDGES 800000
#define F_IN    128
#define HID     128
#define PROJ    512
#define N_CLS   32
#define N_GRAPHS 256
#define T_EMB   768
#define NB_SCAN ((N_NODES + 255) / 256)   // 196
#define DBINS   1024
#define NBROW   ((N_NODES + 63) / 64)     // 782 row-blocks (64 rows each)
#define NBG2    ((NBROW + 1) / 2)         // 391 row-block pairs per chunk

typedef __attribute__((ext_vector_type(8))) short bf16x8;
typedef __attribute__((ext_vector_type(4))) float f32x4;

__device__ __forceinline__ float bf2f(unsigned short u) {
    unsigned v = ((unsigned)u) << 16;
    return __uint_as_float(v);
}
__device__ __forceinline__ unsigned short f2us(float v) {
    __hip_bfloat16 b = __float2bfloat16(v);
    union { __hip_bfloat16 b; unsigned short u; } c; c.b = b; return c.u;
}

// ---- degree histogram (int atomics over dst) ----
__global__ void k_deg(const int* __restrict__ ei, int* __restrict__ cnt, int nE) {
    int e = blockIdx.x * 256 + threadIdx.x;
    if (e < nE) atomicAdd(cnt + ei[nE + e], 1);
}

// ---- parallel scan pass 1 ----
__global__ __launch_bounds__(256) void k_scan1(const int* __restrict__ cnt,
    int* __restrict__ rowstart, float* __restrict__ dnorm, int* __restrict__ bsum)
{
    __shared__ int ps[256];
    int t = threadIdx.x;
    int i = blockIdx.x * 256 + t;
    int c = (i < N_NODES) ? cnt[i] : 0;
    if (i < N_NODES) dnorm[i] = rsqrtf((float)c + 1.0f);
    ps[t] = c;
    __syncthreads();
    for (int off = 1; off < 256; off <<= 1) {
        int v = (t >= off) ? ps[t - off] : 0;
        __syncthreads();
        ps[t] += v;
        __syncthreads();
    }
    if (i < N_NODES) rowstart[i] = ps[t] - c;
    if (t == 255) bsum[blockIdx.x] = ps[255];
}

// ---- scan pass 2 ----
__global__ __launch_bounds__(256) void k_scan2(int* __restrict__ bsum) {
    __shared__ int ps[256];
    int t = threadIdx.x;
    int v = (t < NB_SCAN) ? bsum[t] : 0;
    ps[t] = v;
    __syncthreads();
    for (int off = 1; off < 256; off <<= 1) {
        int u = (t >= off) ? ps[t - off] : 0;
        __syncthreads();
        ps[t] += u;
        __syncthreads();
    }
    if (t < NB_SCAN) bsum[t] = ps[t] - v;
}

// ---- scan pass 3 (+ LDS-aggregated degree histogram for LPT sort) ----
__global__ __launch_bounds__(256) void k_scan3(int* __restrict__ rowstart,
    const int* __restrict__ bsum, const int* __restrict__ cnt,
    int* __restrict__ dhist)
{
    __shared__ int lh[DBINS];
    int t = threadIdx.x;
    for (int k = t; k < DBINS; k += 256) lh[k] = 0;
    __syncthreads();
    int i = blockIdx.x * 256 + t;
    if (i < N_NODES) {
        rowstart[i] += bsum[blockIdx.x];
        atomicAdd(&lh[min(cnt[i], DBINS - 1)], 1);
    }
    if (i == 0) rowstart[N_NODES] = N_EDGES;
    __syncthreads();
    for (int k = t; k < DBINS; k += 256) {
        int v = lh[k];
        if (v) atomicAdd(dhist + k, v);
    }
}

// ---- descending-degree exclusive offsets: doff[d] = #rows with degree > d ----
__global__ __launch_bounds__(256) void k_dscan(const int* __restrict__ dhist,
                                               int* __restrict__ doff) {
    __shared__ int part[256];
    __shared__ int binv[DBINS];
    int t = threadIdx.x;
    int base = t * 4;
    int g0 = dhist[DBINS - 1 - (base + 0)];
    int g1 = dhist[DBINS - 1 - (base + 1)];
    int g2 = dhist[DBINS - 1 - (base + 2)];
    int g3 = dhist[DBINS - 1 - (base + 3)];
    int s = g0 + g1 + g2 + g3;
    part[t] = s;
    __syncthreads();
    for (int off = 1; off < 256; off <<= 1) {
        int v = (t >= off) ? part[t - off] : 0;
        __syncthreads();
        part[t] += v;
        __syncthreads();
    }
    int run = part[t] - s;   // exclusive prefix of this thread's 4 bins
    binv[base + 0] = run; run += g0;
    binv[base + 1] = run; run += g1;
    binv[base + 2] = run; run += g2;
    binv[base + 3] = run; run += g3;
    __syncthreads();
    for (int k = t; k < DBINS; k += 256) doff[DBINS - 1 - k] = binv[k];
}

// ---- scatter rows into degree-descending permutation (two-phase, LDS ranks;
// one global atomic per non-empty bin per block -> no same-address storm) ----
__global__ __launch_bounds__(1024) void k_dperm(const int* __restrict__ cnt,
    int* __restrict__ doff, int* __restrict__ rowperm)
{
    __shared__ int lh[DBINS];
    __shared__ int lbase[DBINS];
    int t = threadIdx.x;
    if (t < DBINS) lh[t] = 0;
    __syncthreads();
    int i = blockIdx.x * 1024 + t;
    int bin = 0, lrank = 0;
    bool ok = i < N_NODES;
    if (ok) {
        bin = min(cnt[i], DBINS - 1);
        lrank = atomicAdd(&lh[bin], 1);
    }
    __syncthreads();
    if (t < DBINS) {
        int v = lh[t];
        if (v) lbase[t] = atomicAdd(doff + t, v);
    }
    __syncthreads();
    if (ok) rowperm[lbase[bin] + lrank] = i;
}

// ---- fill CSR src lists ----
__global__ void k_fill(const int* __restrict__ ei, const int* __restrict__ rowstart,
                       int* __restrict__ cursor, int* __restrict__ srcl, int nE) {
    int e = blockIdx.x * 256 + threadIdx.x;
    if (e >= nE) return;
    int s = ei[e];
    int d = ei[nE + e];
    int pos = rowstart[d] + atomicAdd(cursor + d, 1);
    srcl[pos] = s;
}

// ---- combined prep: weight transpose+bf16 and graph boundaries ----
__global__ void k_prep(const float* __restrict__ W, unsigned short* __restrict__ Wt,
                       const int* __restrict__ batch, int* __restrict__ gstart) {
    int t = blockIdx.x * 256 + threadIdx.x;
    if (t < 4 * 128 * 128) {
        int l = t >> 14;
        int k = (t >> 7) & 127;
        int n = t & 127;
        Wt[(size_t)l * 16384 + n * 128 + k] = f2us(W[(size_t)l * 16384 + k * 128 + n]);
    } else {
        int r = t - 4 * 128 * 128;
        if (r <= N_NODES) {
            int b  = (r < N_NODES) ? batch[r] : N_GRAPHS;
            int bp = (r > 0) ? batch[r - 1] : -1;
            for (int g = bp + 1; g <= b && g <= N_GRAPHS; g++) gstart[g] = r;
        }
    }
}

// ---- GCN matmul via bf16 MFMA; direct global A-loads, BN fold in-register;
// epilogue transposed through LDS (reusing Bs) for coalesced uint4 stores.
// ph output is CHUNK-MAJOR: [4 chunks][N rows][32 feats] bf16. ----
__global__ __launch_bounds__(256) void k_gcn_mm_mfma(const void* __restrict__ inp,
    const unsigned short* __restrict__ Wt,   // [128 n][128 k] bf16 (n-major)
    const float* __restrict__ stats, const float* __restrict__ bng,
    const float* __restrict__ bnb, const float* __restrict__ dnorm,
    unsigned short* __restrict__ ph, int n)
{
    __shared__ __align__(16) unsigned short Bs[128][136];   // 34.8 KB (reused as C-staging)
    __shared__ float scs[128], shs[128];
    int t = threadIdx.x;
    int row0 = blockIdx.x * 64;

    if (stats && t < 128) {
        float inv_n = 1.0f / (float)N_NODES;
        float mu = stats[t] * inv_n;
        float var = stats[128 + t] * inv_n - mu * mu;
        float rs = rsqrtf(var + 1e-5f);
        float sc = rs * bng[t];
        scs[t] = sc;
        shs[t] = bnb[t] - mu * sc;
    }
#pragma unroll
    for (int i = 0; i < 8; i++) {
        int c = t + i * 256;
        int nn = c >> 4;
        int k8 = (c & 15) * 8;
        *(uint4*)&Bs[nn][k8] = *(const uint4*)(Wt + (size_t)nn * 128 + k8);
    }
    __syncthreads();

    int w = t >> 6, lane = t & 63;
    int m = lane & 15, quad = lane >> 4;
    int arow = row0 + w * 16 + m;        // this lane's A row
    bool rowok = arow < n;

    // load A fragments for all 4 k-chunks (16 B each, aligned)
    bf16x8 afrag[4];
    if (!stats) {
        const float* inf = (const float*)inp;
#pragma unroll
        for (int ki = 0; ki < 4; ki++) {
            int k8 = ki * 32 + quad * 8;
            float4 v0 = make_float4(0.f, 0.f, 0.f, 0.f);
            float4 v1 = make_float4(0.f, 0.f, 0.f, 0.f);
            if (rowok) {
                v0 = *(const float4*)(inf + (size_t)arow * 128 + k8);
                v1 = *(const float4*)(inf + (size_t)arow * 128 + k8 + 4);
            }
            union { unsigned short u[8]; bf16x8 v; } pk;
            pk.u[0] = f2us(v0.x); pk.u[1] = f2us(v0.y); pk.u[2] = f2us(v0.z); pk.u[3] = f2us(v0.w);
            pk.u[4] = f2us(v1.x); pk.u[5] = f2us(v1.y); pk.u[6] = f2us(v1.z); pk.u[7] = f2us(v1.w);
            afrag[ki] = pk.v;
        }
    } else {
        const unsigned short* inb = (const unsigned short*)inp;
#pragma unroll
        for (int ki = 0; ki < 4; ki++) {
            int k8 = ki * 32 + quad * 8;
            uint4 raw = make_uint4(0, 0, 0, 0);
            if (rowok) raw = *(const uint4*)(inb + (size_t)arow * 128 + k8);
            unsigned rr[4] = { raw.x, raw.y, raw.z, raw.w };
            union { unsigned short u[8]; bf16x8 v; } pk;
#pragma unroll
            for (int j = 0; j < 4; j++) {
                int f0 = k8 + 2 * j, f1 = k8 + 2 * j + 1;
                float a0 = bf2f((unsigned short)rr[j]) * scs[f0] + shs[f0];
                float a1 = bf2f((unsigned short)(rr[j] >> 16)) * scs[f1] + shs[f1];
                pk.u[2 * j] = f2us(a0);
                pk.u[2 * j + 1] = f2us(a1);
            }
            afrag[ki] = pk.v;
        }
    }

    f32x4 acc[8];
#pragma unroll
    for (int nt = 0; nt < 8; nt++) acc[nt] = (f32x4){0.f, 0.f, 0.f, 0.f};
#pragma unroll
    for (int ki = 0; ki < 4; ki++) {
#pragma unroll
        for (int nt = 0; nt < 8; nt++) {
            bf16x8 b = *(const bf16x8*)&Bs[nt * 16 + m][ki * 32 + quad * 8];
            acc[nt] = __builtin_amdgcn_mfma_f32_16x16x32_bf16(afrag[ki], b, acc[nt], 0, 0, 0);
        }
    }

    float dn[4];
#pragma unroll
    for (int reg = 0; reg < 4; reg++) {
        int gr = row0 + w * 16 + quad * 4 + reg;
        dn[reg] = (gr < n) ? dnorm[gr] : 0.f;
    }

    // ---- epilogue: transpose C through LDS (reuse Bs), store chunk-major ----
    __syncthreads();   // all waves finished reading Bs
#pragma unroll
    for (int nt = 0; nt < 8; nt++) {
#pragma unroll
        for (int reg = 0; reg < 4; reg++) {
            Bs[w * 16 + quad * 4 + reg][nt * 16 + m] = f2us(acc[nt][reg] * dn[reg]);
        }
    }
    __syncthreads();
#pragma unroll
    for (int i = 0; i < 4; i++) {
        int idx = t + i * 256;           // 0..1023
        int r = idx >> 4;                // 0..63
        int c8 = (idx & 15) * 8;         // 0..120
        int gr = row0 + r;
        int ch = c8 >> 5;                // chunk 0..3
        int off = c8 & 31;               // 0,8,16,24
        if (gr < n)
            *(uint4*)(ph + (size_t)ch * (N_NODES * 32) + (size_t)gr * 32 + off)
                = *(const uint4*)&Bs[r][c8];
    }
}

// ---- feature-chunked pair-gather v5: chunk PINNED to XCD pair via bid%8
// (XCDs {2c,2c+1} own chunk c for the whole kernel -> each XCD's 4 MB L2
// holds exactly one 3.2 MB ph slice; src-row reuse (~17 refs/row) becomes
// L2 hits instead of HBM misses; round-4 measured 131 MB fetch from
// cross-chunk thrash). 64 rows/block, 4-lane groups, 16-B loads. ----
__global__ __launch_bounds__(256) void k_gather_c(const uint4* __restrict__ ph128,
    const int* __restrict__ srcl, const int* __restrict__ rowstart,
    const int* __restrict__ rowperm, const float* __restrict__ dnorm,
    const float* __restrict__ bias, unsigned short* __restrict__ outbb,
    float* __restrict__ stats, int n)
{
    const int EMAX = N_EDGES - 1;
    __shared__ float bsm[32], bqm[32];
    int t = threadIdx.x;
    if (t < 32) { bsm[t] = 0.f; bqm[t] = 0.f; }
    __syncthreads();

    int bx = blockIdx.x;
    int xcd = bx & 7;              // empirically: workgroup -> XCD round-robin
    int c = xcd >> 1;              // chunk pinned to XCD pair
    int rb = (bx >> 3) * 2 + (xcd & 1);   // row-block within chunk (0..781)
    if (rb >= NBROW) return;
    int lane = t & 63;
    int w = t >> 6;                // wave 0..3
    int grp = lane >> 2;           // group 0..15 within wave (one row each)
    int l4 = lane & 3;             // lane in group: 8 feats (16 B) each
    int idx = rb * 64 + w * 16 + grp;
    bool rok = idx < n;
    int r = rok ? rowperm[idx] : 0;
    int start = rowstart[r];
    int deg = rowstart[r + 1] - start;
    float dnr = dnorm[r];
    if (!rok) { deg = 0; dnr = 0.f; }
    int len = deg + 1;             // + self loop

    const uint4* phc = ph128 + (size_t)c * (N_NODES * 4);   // 4 uint4 per 32-feat row

    float bi[8];
#pragma unroll
    for (int k = 0; k < 8; k++) bi[k] = bias[c * 32 + l4 * 8 + k];

    float a[8];
#pragma unroll
    for (int k = 0; k < 8; k++) a[k] = 0.f;

    for (int j = 0; j < len; j += 4) {
        uint4 uv[4];
#pragma unroll
        for (int u = 0; u < 4; u++) {
            int i = j + u;
            int sl = srcl[min(start + i, EMAX)];
            int s = (i < deg) ? sl : r;
            uv[u] = phc[(size_t)s * 4 + l4];
        }
#pragma unroll
        for (int u = 0; u < 4; u++) {
            int i = j + u;
            float wt = (i < len) ? 1.f : 0.f;
            unsigned rr[4] = { uv[u].x, uv[u].y, uv[u].z, uv[u].w };
#pragma unroll
            for (int d = 0; d < 4; d++) {
                a[2 * d]     += wt * bf2f((unsigned short)rr[d]);
                a[2 * d + 1] += wt * bf2f((unsigned short)(rr[d] >> 16));
            }
        }
    }

    float v[8];
#pragma unroll
    for (int k = 0; k < 8; k++) {
        float x = a[k] * dnr + bi[k];
        v[k] = x > 0.f ? x : 0.01f * x;
    }
    if (rok) {
        union { unsigned short us[8]; uint4 u; } ov;
#pragma unroll
        for (int k = 0; k < 8; k++) ov.us[k] = f2us(v[k]);
        *(uint4*)(outbb + (size_t)r * 128 + c * 32 + l4 * 8) = ov.u;
    } else {
#pragma unroll
        for (int k = 0; k < 8; k++) v[k] = 0.f;
    }

    float q[8];
#pragma unroll
    for (int k = 0; k < 8; k++) q[k] = v[k] * v[k];
    // reduce across the 16 groups of this wave (same feature at same l4)
#pragma unroll
    for (int mk = 4; mk < 64; mk <<= 1) {
#pragma unroll
        for (int k = 0; k < 8; k++) {
            v[k] += __shfl_xor(v[k], mk, 64);
            q[k] += __shfl_xor(q[k], mk, 64);
        }
    }
    if (grp == 0) {
#pragma unroll
        for (int k = 0; k < 8; k++) {
            atomicAdd(&bsm[l4 * 8 + k], v[k]);
            atomicAdd(&bqm[l4 * 8 + k], q[k]);
        }
    }
    __syncthreads();
    if (t < 32) {
        atomicAdd(&stats[c * 32 + t], bsm[t]);
        atomicAdd(&stats[128 + c * 32 + t], bqm[t]);
    }
}

// ---- segmented mean pool (bf16 input); BN scale/shift computed in-block ----
__global__ __launch_bounds__(256) void k_pool2(const unsigned short* __restrict__ outbb,
    const int* __restrict__ gstart, const float* __restrict__ stats,
    const float* __restrict__ bng, const float* __restrict__ bnb,
    float* __restrict__ gemb)
{
    __shared__ float scs[128], shs[128];
    int g = blockIdx.x;
    int t = threadIdx.x;
    if (t < 128) {
        float inv_n = 1.0f / (float)N_NODES;
        float mu = stats[t] * inv_n;
        float var = stats[128 + t] * inv_n - mu * mu;
        float rs = rsqrtf(var + 1e-5f);
        float sc = rs * bng[t];
        scs[t] = sc;
        shs[t] = bnb[t] - mu * sc;
    }
    __syncthreads();
    int f = t & 127;
    int half = t >> 7;
    int start = gstart[g], end = gstart[g + 1];
    int cnt = end - start;
    float s0 = 0.f, s1 = 0.f, s2 = 0.f, s3 = 0.f;
    int r = start + half;
    for (; r + 6 < end; r += 8) {
        s0 += bf2f(outbb[(size_t)(r    ) * 128 + f]);
        s1 += bf2f(outbb[(size_t)(r + 2) * 128 + f]);
        s2 += bf2f(outbb[(size_t)(r + 4) * 128 + f]);
        s3 += bf2f(outbb[(size_t)(r + 6) * 128 + f]);
    }
    for (; r < end; r += 2) s0 += bf2f(outbb[(size_t)r * 128 + f]);
    float sum = (s0 + s1) + (s2 + s3);
    __shared__ float sb[256];
    sb[t] = sum;
    __syncthreads();
    if (t < 128) {
        float tot = sb[t] + sb[t + 128];
        float v = (cnt > 0) ? (tot / (float)cnt) * scs[f] + shs[f] : 0.f;
        gemb[(size_t)g * 128 + f] = v;
    }
}

// ---- fused head layer 1 for both heads ----
__global__ __launch_bounds__(256) void k_head1x(const float* __restrict__ gemb,
    const float* __restrict__ textf,
    const float* __restrict__ gW1, const float* __restrict__ gb1,
    const float* __restrict__ tW1, const float* __restrict__ tb1,
    float* __restrict__ projg, float* __restrict__ projt)
{
    __shared__ float ins[8][768];
    int bx = blockIdx.x;
    int chunk = blockIdx.y;
    int isT = bx >= 32;
    int rb = isT ? bx - 32 : bx;
    const float* in = isT ? textf : gemb;
    int K = isT ? T_EMB : HID;
    const float* W = isT ? tW1 : gW1;
    const float* b = isT ? tb1 : gb1;
    float* outp = isT ? projt : projg;

    int t = threadIdx.x;
    int tot = 8 * K;
    for (int l = t; l < tot; l += 256) {
        int r = l / K, k = l - r * K;
        ins[r][k] = in[(size_t)(rb * 8 + r) * K + k];
    }
    __syncthreads();
    int col = chunk * 128 + (t & 127);
    int rg = t >> 7;
    float acc[4] = { 0.f, 0.f, 0.f, 0.f };
    for (int k = 0; k < K; k++) {
        float w = W[(size_t)k * 512 + col];
#pragma unroll
        for (int i = 0; i < 4; i++) acc[i] += ins[rg * 4 + i][k] * w;
    }
    float bias = b[col];
#pragma unroll
    for (int i = 0; i < 4; i++) {
        int row = rb * 8 + rg * 4 + i;
        outp[(size_t)row * 512 + col] = acc[i] + bias;
    }
}

// ---- fused head2 + LayerNorm + classifier + log_softmax, both heads ----
__global__ __launch_bounds__(256) void k_head2c(
    const float* __restrict__ projg, const float* __restrict__ projt,
    const float* __restrict__ gW2, const float* __restrict__ gb2,
    const float* __restrict__ gg, const float* __restrict__ gbe,
    const float* __restrict__ gclW, const float* __restrict__ gclb,
    const float* __restrict__ tW2, const float* __restrict__ tb2,
    const float* __restrict__ tg, const float* __restrict__ tbe,
    const float* __restrict__ tclW, const float* __restrict__ tclb,
    float* __restrict__ o_gproj, float* __restrict__ o_tproj,
    float* __restrict__ o_glogp, float* __restrict__ o_tlogp)
{
    __shared__ float prow[512], grow[512], onorm[512], red[256];
    __shared__ float part[8][32];
    __shared__ float logits[32];
    __shared__ float mred, lred;
    int bx = blockIdx.x;
    int isT = bx >= N_GRAPHS;
    int row = isT ? bx - N_GRAPHS : bx;
    const float* proj = isT ? projt : projg;
    const float* W2 = isT ? tW2 : gW2;
    const float* b2 = isT ? tb2 : gb2;
    const float* g  = isT ? tg  : gg;
    const float* be = isT ? tbe : gbe;
    const float* Wc = isT ? tclW : gclW;
    const float* bc = isT ? tclb : gclb;
    float* oproj = isT ? o_tproj : o_gproj;
    float* ologp = isT ? o_tlogp : o_glogp;

    int t = threadIdx.x;
    for (int c = t; c < 512; c += 256) {
        float p = proj[(size_t)row * 512 + c];
        prow[c] = p;
        grow[c] = 0.5f * p * (1.0f + erff(p * 0.70710678118f));
    }
    __syncthreads();
    float a0 = 0.f, a1 = 0.f;
    int c0 = t, c1 = t + 256;
    for (int k = 0; k < 512; k++) {
        float gk = grow[k];
        a0 += gk * W2[(size_t)k * 512 + c0];
        a1 += gk * W2[(size_t)k * 512 + c1];
    }
    float h0 = a0 + b2[c0] + prow[c0];
    float h1 = a1 + b2[c1] + prow[c1];
    red[t] = h0 + h1;
    __syncthreads();
    for (int s = 128; s > 0; s >>= 1) { if (t < s) red[t] += red[t + s]; __syncthreads(); }
    float mu = red[0] * (1.0f / 512.0f);
    __syncthreads();
    float d0 = h0 - mu, d1 = h1 - mu;
    red[t] = d0 * d0 + d1 * d1;
    __syncthreads();
    for (int s = 128; s > 0; s >>= 1) { if (t < s) red[t] += red[t + s]; __syncthreads(); }
    float rs = rsqrtf(red[0] * (1.0f / 512.0f) + 1e-5f);
    float o0 = d0 * rs * g[c0] + be[c0];
    float o1 = d1 * rs * g[c1] + be[c1];
    onorm[c0] = o0;
    onorm[c1] = o1;
    oproj[(size_t)row * 512 + c0] = o0;
    oproj[(size_t)row * 512 + c1] = o1;
    __syncthreads();

    int c = t & 31, seg = t >> 5;
    float p = 0.f;
    for (int k = seg * 64; k < seg * 64 + 64; k++)
        p += onorm[k] * Wc[(size_t)k * 32 + c];
    part[seg][c] = p;
    __syncthreads();
    if (t < 32) {
        float l = bc[t];
#pragma unroll
        for (int s = 0; s < 8; s++) l += part[s][t];
        logits[t] = l;
    }
    __syncthreads();
    if (t == 0) {
        float m = logits[0];
        for (int i = 1; i < 32; i++) m = fmaxf(m, logits[i]);
        float sum = 0.f;
        for (int i = 0; i < 32; i++) sum += expf(logits[i] - m);
        mred = m; lred = logf(sum);
    }
    __syncthreads();
    if (t < 32) ologp[(size_t)row * 32 + t] = logits[t] - mred - lred;
}

extern "C" void kernel_launch(void* const* d_in, const int* in_sizes, int n_in,
                              void* d_out, int out_size, void* d_ws, size_t ws_size,
                              hipStream_t stream) {
    const float* x     = (const float*)d_in[0];
    const int*   ei    = (const int*)d_in[1];
    const int*   batch = (const int*)d_in[2];
    const float* textf = (const float*)d_in[3];
    const float* gcnW  = (const float*)d_in[4];
    const float* gcnb  = (const float*)d_in[5];
    const float* bng   = (const float*)d_in[6];
    const float* bnb   = (const float*)d_in[7];
    const float* gW1   = (const float*)d_in[8];
    const float* gb1   = (const float*)d_in[9];
    const float* gW2   = (const float*)d_in[10];
    const float* gb2   = (const float*)d_in[11];
    const float* gg    = (const float*)d_in[12];
    const float* gbe   = (const float*)d_in[13];
    const float* gclW  = (const float*)d_in[14];
    const float* gclb  = (const float*)d_in[15];
    const float* tW1   = (const float*)d_in[16];
    const float* tb1   = (const float*)d_in[17];
    const float* tW2   = (const float*)d_in[18];
    const float* tb2   = (const float*)d_in[19];
    const float* tg    = (const float*)d_in[20];
    const float* tbe   = (const float*)d_in[21];
    const float* tclW  = (const float*)d_in[22];
    const float* tclb  = (const float*)d_in[23];

    const int N = N_NODES, E = N_EDGES;
    const int NF = N * HID;

    float* p = (float*)d_ws;
    unsigned short* outbb = (unsigned short*)p; p += NF / 2;   // 12.8 MB bf16
    unsigned short* ph    = (unsigned short*)p; p += NF / 2;   // 12.8 MB bf16 chunk-major
    unsigned short* Wt    = (unsigned short*)p; p += 4 * 16384 / 2;
    float* dnorm = p; p += N;
    float* gemb  = p; p += N_GRAPHS * HID;
    float* projg = p; p += N_GRAPHS * PROJ;
    float* projt = p; p += N_GRAPHS * PROJ;
    // contiguous zero-init region: cnt | cursor | stats4 | dhist
    int* cnt      = (int*)p; p += N;
    int* cursor   = (int*)p; p += N;
    float* stats4 = p; p += 4 * 256;
    int* dhist    = (int*)p; p += DBINS;
    int* rowstart = (int*)p; p += N + 1;
    int* gstart   = (int*)p; p += N_GRAPHS + 1;
    int* bsum     = (int*)p; p += 256;
    int* srcl     = (int*)p; p += E;
    int* doff     = (int*)p; p += DBINS;
    int* rowperm  = (int*)p; p += N;

    float* outp = (float*)d_out;
    float* o_gproj = outp;
    float* o_tproj = outp + N_GRAPHS * PROJ;
    float* o_glogp = o_tproj + N_GRAPHS * PROJ;
    float* o_tlogp = o_glogp + N_GRAPHS * N_CLS;

    // ---- CSR build + degree-sort + prep ----
    hipMemsetAsync(cnt, 0, (size_t)(2 * N + 4 * 256 + DBINS) * sizeof(int), stream);
    k_deg<<<(E + 255) / 256, 256, 0, stream>>>(ei, cnt, E);
    k_scan1<<<NB_SCAN, 256, 0, stream>>>(cnt, rowstart, dnorm, bsum);
    k_scan2<<<1, 256, 0, stream>>>(bsum);
    k_scan3<<<NB_SCAN, 256, 0, stream>>>(rowstart, bsum, cnt, dhist);
    k_fill<<<(E + 255) / 256, 256, 0, stream>>>(ei, rowstart, cursor, srcl, E);
    k_dscan<<<1, 256, 0, stream>>>(dhist, doff);
    k_dperm<<<(N + 1023) / 1024, 1024, 0, stream>>>(cnt, doff, rowperm);
    k_prep<<<(4 * 16384 + N + 1 + 255) / 256, 256, 0, stream>>>(gcnW, Wt, batch, gstart);

    // ---- 4 GCN layers (BN of layer l-1 folded into mm of layer l) ----
    for (int l = 0; l < 4; l++) {
        const void* in = (l == 0) ? (const void*)x : (const void*)outbb;
        const float* st = (l == 0) ? nullptr : stats4 + (l - 1) * 256;
        const float* bg = (l == 0) ? nullptr : bng + (size_t)(l - 1) * HID;
        const float* bb = (l == 0) ? nullptr : bnb + (size_t)(l - 1) * HID;
        k_gcn_mm_mfma<<<(N + 63) / 64, 256, 0, stream>>>(in, Wt + (size_t)l * 16384,
                                                         st, bg, bb, dnorm, ph, N);
        k_gather_c<<<NBG2 * 8, 256, 0, stream>>>((const uint4*)ph, srcl,
                                                 rowstart, rowperm, dnorm,
                                                 gcnb + (size_t)l * HID, outbb,
                                                 stats4 + l * 256, N);
    }

    // ---- segmented mean pool (layer-3 BN folded in-block) ----
    k_pool2<<<N_GRAPHS, 256, 0, stream>>>(outbb, gstart, stats4 + 3 * 256,
                                          bng + 3 * HID, bnb + 3 * HID, gemb);

    // ---- fused heads ----
    k_head1x<<<dim3(64, 4), 256, 0, stream>>>(gemb, textf, gW1, gb1, tW1, tb1, projg, projt);
    k_head2c<<<2 * N_GRAPHS, 256, 0, stream>>>(projg, projt,
                                               gW2, gb2, gg, gbe, gclW, gclb,
                                               tW2, tb2, tg, tbe, tclW, tclb,
                                               o_gproj, o_tproj, o_glogp, o_tlogp);
}

// Round 6
// 462.889 us; speedup vs baseline: 2.0704x; 1.0602x over previous
//
#include <hip/hip_runtime.h>
#include <hip/hip_bf16.h>

// Problem sizes (fixed by reference)
#define N_NODES 50000
#define N_EDGES 800000
#define F_IN    128
#define HID     128
#define PROJ    512
#define N_CLS   32
#define N_GRAPHS 256
#define T_EMB   768
#define NB_SCAN ((N_NODES + 255) / 256)   // 196
#define DBINS   1024
#define NBROW   ((N_NODES + 63) / 64)     // 782 row-blocks (64 rows each)
#define NBG2    ((NBROW + 1) / 2)         // 391 row-block pairs per chunk
#define SHW     6250                      // dst rows per XCD shard (8*6250 = 50000)
#define ESLICE  ((N_EDGES + 4095) / 4096) // 196 edge slices of 4096

typedef __attribute__((ext_vector_type(8))) short bf16x8;
typedef __attribute__((ext_vector_type(4))) float f32x4;

__device__ __forceinline__ float bf2f(unsigned short u) {
    unsigned v = ((unsigned)u) << 16;
    return __uint_as_float(v);
}
__device__ __forceinline__ unsigned short f2us(float v) {
    __hip_bfloat16 b = __float2bfloat16(v);
    union { __hip_bfloat16 b; unsigned short u; } c; c.b = b; return c.u;
}

// ---- degree histogram, XCD-sharded: shard s=bid&7 owns dst rows
// [s*SHW,(s+1)*SHW) -> cnt lines stay exclusive to one XCD's L2. ----
__global__ __launch_bounds__(256) void k_deg(const int* __restrict__ ei,
                                             int* __restrict__ cnt, int nE) {
    int bx = blockIdx.x;
    int s = bx & 7;
    int slice = bx >> 3;
    int lo = s * SHW, hi = lo + SHW;
    int base = slice * 4096 + threadIdx.x;
#pragma unroll 4
    for (int u = 0; u < 16; u++) {
        int e = base + u * 256;
        if (e < nE) {
            int d = ei[nE + e];
            if (d >= lo && d < hi) atomicAdd(cnt + d, 1);
        }
    }
}

// ---- parallel scan pass 1 ----
__global__ __launch_bounds__(256) void k_scan1(const int* __restrict__ cnt,
    int* __restrict__ rowstart, float* __restrict__ dnorm, int* __restrict__ bsum)
{
    __shared__ int ps[256];
    int t = threadIdx.x;
    int i = blockIdx.x * 256 + t;
    int c = (i < N_NODES) ? cnt[i] : 0;
    if (i < N_NODES) dnorm[i] = rsqrtf((float)c + 1.0f);
    ps[t] = c;
    __syncthreads();
    for (int off = 1; off < 256; off <<= 1) {
        int v = (t >= off) ? ps[t - off] : 0;
        __syncthreads();
        ps[t] += v;
        __syncthreads();
    }
    if (i < N_NODES) rowstart[i] = ps[t] - c;
    if (t == 255) bsum[blockIdx.x] = ps[255];
}

// ---- scan pass 2 ----
__global__ __launch_bounds__(256) void k_scan2(int* __restrict__ bsum) {
    __shared__ int ps[256];
    int t = threadIdx.x;
    int v = (t < NB_SCAN) ? bsum[t] : 0;
    ps[t] = v;
    __syncthreads();
    for (int off = 1; off < 256; off <<= 1) {
        int u = (t >= off) ? ps[t - off] : 0;
        __syncthreads();
        ps[t] += u;
        __syncthreads();
    }
    if (t < NB_SCAN) bsum[t] = ps[t] - v;
}

// ---- scan pass 3 (+ LDS-aggregated degree histogram for LPT sort) ----
__global__ __launch_bounds__(256) void k_scan3(int* __restrict__ rowstart,
    const int* __restrict__ bsum, const int* __restrict__ cnt,
    int* __restrict__ dhist)
{
    __shared__ int lh[DBINS];
    int t = threadIdx.x;
    for (int k = t; k < DBINS; k += 256) lh[k] = 0;
    __syncthreads();
    int i = blockIdx.x * 256 + t;
    if (i < N_NODES) {
        rowstart[i] += bsum[blockIdx.x];
        atomicAdd(&lh[min(cnt[i], DBINS - 1)], 1);
    }
    if (i == 0) rowstart[N_NODES] = N_EDGES;
    __syncthreads();
    for (int k = t; k < DBINS; k += 256) {
        int v = lh[k];
        if (v) atomicAdd(dhist + k, v);
    }
}

// ---- descending-degree exclusive offsets: doff[d] = #rows with degree > d ----
__global__ __launch_bounds__(256) void k_dscan(const int* __restrict__ dhist,
                                               int* __restrict__ doff) {
    __shared__ int part[256];
    __shared__ int binv[DBINS];
    int t = threadIdx.x;
    int base = t * 4;
    int g0 = dhist[DBINS - 1 - (base + 0)];
    int g1 = dhist[DBINS - 1 - (base + 1)];
    int g2 = dhist[DBINS - 1 - (base + 2)];
    int g3 = dhist[DBINS - 1 - (base + 3)];
    int s = g0 + g1 + g2 + g3;
    part[t] = s;
    __syncthreads();
    for (int off = 1; off < 256; off <<= 1) {
        int v = (t >= off) ? part[t - off] : 0;
        __syncthreads();
        part[t] += v;
        __syncthreads();
    }
    int run = part[t] - s;   // exclusive prefix of this thread's 4 bins
    binv[base + 0] = run; run += g0;
    binv[base + 1] = run; run += g1;
    binv[base + 2] = run; run += g2;
    binv[base + 3] = run; run += g3;
    __syncthreads();
    for (int k = t; k < DBINS; k += 256) doff[DBINS - 1 - k] = binv[k];
}

// ---- scatter rows into degree-descending permutation (two-phase, LDS ranks;
// one global atomic per non-empty bin per block -> no same-address storm) ----
__global__ __launch_bounds__(1024) void k_dperm(const int* __restrict__ cnt,
    int* __restrict__ doff, int* __restrict__ rowperm)
{
    __shared__ int lh[DBINS];
    __shared__ int lbase[DBINS];
    int t = threadIdx.x;
    if (t < DBINS) lh[t] = 0;
    __syncthreads();
    int i = blockIdx.x * 1024 + t;
    int bin = 0, lrank = 0;
    bool ok = i < N_NODES;
    if (ok) {
        bin = min(cnt[i], DBINS - 1);
        lrank = atomicAdd(&lh[bin], 1);
    }
    __syncthreads();
    if (t < DBINS) {
        int v = lh[t];
        if (v) lbase[t] = atomicAdd(doff + t, v);
    }
    __syncthreads();
    if (ok) rowperm[lbase[bin] + lrank] = i;
}

// ---- fill CSR src lists, XCD-sharded like k_deg: cursor atomics and the
// srcl write region for shard s stay local to XCD s's L2 (round-5 measured
// 55.8 MB WRITE_SIZE = cross-XCD line bounce on the unsharded version). ----
__global__ __launch_bounds__(256) void k_fill(const int* __restrict__ ei,
    const int* __restrict__ rowstart, int* __restrict__ cursor,
    int* __restrict__ srcl, int nE)
{
    int bx = blockIdx.x;
    int s = bx & 7;
    int slice = bx >> 3;
    int lo = s * SHW, hi = lo + SHW;
    int base = slice * 4096 + threadIdx.x;
#pragma unroll 4
    for (int u = 0; u < 16; u++) {
        int e = base + u * 256;
        if (e < nE) {
            int d = ei[nE + e];
            if (d >= lo && d < hi) {
                int pos = rowstart[d] + atomicAdd(cursor + d, 1);
                srcl[pos] = ei[e];
            }
        }
    }
}

// ---- combined prep: weight transpose+bf16 and graph boundaries ----
__global__ void k_prep(const float* __restrict__ W, unsigned short* __restrict__ Wt,
                       const int* __restrict__ batch, int* __restrict__ gstart) {
    int t = blockIdx.x * 256 + threadIdx.x;
    if (t < 4 * 128 * 128) {
        int l = t >> 14;
        int k = (t >> 7) & 127;
        int n = t & 127;
        Wt[(size_t)l * 16384 + n * 128 + k] = f2us(W[(size_t)l * 16384 + k * 128 + n]);
    } else {
        int r = t - 4 * 128 * 128;
        if (r <= N_NODES) {
            int b  = (r < N_NODES) ? batch[r] : N_GRAPHS;
            int bp = (r > 0) ? batch[r - 1] : -1;
            for (int g = bp + 1; g <= b && g <= N_GRAPHS; g++) gstart[g] = r;
        }
    }
}

// ---- GCN matmul via bf16 MFMA; direct global A-loads, BN fold in-register;
// epilogue transposed through LDS (reusing Bs) for coalesced uint4 stores.
// ph output is CHUNK-MAJOR: [4 chunks][N rows][32 feats] bf16. ----
__global__ __launch_bounds__(256) void k_gcn_mm_mfma(const void* __restrict__ inp,
    const unsigned short* __restrict__ Wt,   // [128 n][128 k] bf16 (n-major)
    const float* __restrict__ stats, const float* __restrict__ bng,
    const float* __restrict__ bnb, const float* __restrict__ dnorm,
    unsigned short* __restrict__ ph, int n)
{
    __shared__ __align__(16) unsigned short Bs[128][136];   // 34.8 KB (reused as C-staging)
    __shared__ float scs[128], shs[128];
    int t = threadIdx.x;
    int row0 = blockIdx.x * 64;

    if (stats && t < 128) {
        float inv_n = 1.0f / (float)N_NODES;
        float mu = stats[t] * inv_n;
        float var = stats[128 + t] * inv_n - mu * mu;
        float rs = rsqrtf(var + 1e-5f);
        float sc = rs * bng[t];
        scs[t] = sc;
        shs[t] = bnb[t] - mu * sc;
    }
#pragma unroll
    for (int i = 0; i < 8; i++) {
        int c = t + i * 256;
        int nn = c >> 4;
        int k8 = (c & 15) * 8;
        *(uint4*)&Bs[nn][k8] = *(const uint4*)(Wt + (size_t)nn * 128 + k8);
    }
    __syncthreads();

    int w = t >> 6, lane = t & 63;
    int m = lane & 15, quad = lane >> 4;
    int arow = row0 + w * 16 + m;        // this lane's A row
    bool rowok = arow < n;

    // load A fragments for all 4 k-chunks (16 B each, aligned)
    bf16x8 afrag[4];
    if (!stats) {
        const float* inf = (const float*)inp;
#pragma unroll
        for (int ki = 0; ki < 4; ki++) {
            int k8 = ki * 32 + quad * 8;
            float4 v0 = make_float4(0.f, 0.f, 0.f, 0.f);
            float4 v1 = make_float4(0.f, 0.f, 0.f, 0.f);
            if (rowok) {
                v0 = *(const float4*)(inf + (size_t)arow * 128 + k8);
                v1 = *(const float4*)(inf + (size_t)arow * 128 + k8 + 4);
            }
            union { unsigned short u[8]; bf16x8 v; } pk;
            pk.u[0] = f2us(v0.x); pk.u[1] = f2us(v0.y); pk.u[2] = f2us(v0.z); pk.u[3] = f2us(v0.w);
            pk.u[4] = f2us(v1.x); pk.u[5] = f2us(v1.y); pk.u[6] = f2us(v1.z); pk.u[7] = f2us(v1.w);
            afrag[ki] = pk.v;
        }
    } else {
        const unsigned short* inb = (const unsigned short*)inp;
#pragma unroll
        for (int ki = 0; ki < 4; ki++) {
            int k8 = ki * 32 + quad * 8;
            uint4 raw = make_uint4(0, 0, 0, 0);
            if (rowok) raw = *(const uint4*)(inb + (size_t)arow * 128 + k8);
            unsigned rr[4] = { raw.x, raw.y, raw.z, raw.w };
            union { unsigned short u[8]; bf16x8 v; } pk;
#pragma unroll
            for (int j = 0; j < 4; j++) {
                int f0 = k8 + 2 * j, f1 = k8 + 2 * j + 1;
                float a0 = bf2f((unsigned short)rr[j]) * scs[f0] + shs[f0];
                float a1 = bf2f((unsigned short)(rr[j] >> 16)) * scs[f1] + shs[f1];
                pk.u[2 * j] = f2us(a0);
                pk.u[2 * j + 1] = f2us(a1);
            }
            afrag[ki] = pk.v;
        }
    }

    f32x4 acc[8];
#pragma unroll
    for (int nt = 0; nt < 8; nt++) acc[nt] = (f32x4){0.f, 0.f, 0.f, 0.f};
#pragma unroll
    for (int ki = 0; ki < 4; ki++) {
#pragma unroll
        for (int nt = 0; nt < 8; nt++) {
            bf16x8 b = *(const bf16x8*)&Bs[nt * 16 + m][ki * 32 + quad * 8];
            acc[nt] = __builtin_amdgcn_mfma_f32_16x16x32_bf16(afrag[ki], b, acc[nt], 0, 0, 0);
        }
    }

    float dn[4];
#pragma unroll
    for (int reg = 0; reg < 4; reg++) {
        int gr = row0 + w * 16 + quad * 4 + reg;
        dn[reg] = (gr < n) ? dnorm[gr] : 0.f;
    }

    // ---- epilogue: transpose C through LDS (reuse Bs), store chunk-major ----
    __syncthreads();   // all waves finished reading Bs
#pragma unroll
    for (int nt = 0; nt < 8; nt++) {
#pragma unroll
        for (int reg = 0; reg < 4; reg++) {
            Bs[w * 16 + quad * 4 + reg][nt * 16 + m] = f2us(acc[nt][reg] * dn[reg]);
        }
    }
    __syncthreads();
#pragma unroll
    for (int i = 0; i < 4; i++) {
        int idx = t + i * 256;           // 0..1023
        int r = idx >> 4;                // 0..63
        int c8 = (idx & 15) * 8;         // 0..120
        int gr = row0 + r;
        int ch = c8 >> 5;                // chunk 0..3
        int off = c8 & 31;               // 0,8,16,24
        if (gr < n)
            *(uint4*)(ph + (size_t)ch * (N_NODES * 32) + (size_t)gr * 32 + off)
                = *(const uint4*)&Bs[r][c8];
    }
}

// ---- feature-chunked pair-gather v5: chunk PINNED to XCD pair via bid%8. ----
__global__ __launch_bounds__(256) void k_gather_c(const uint4* __restrict__ ph128,
    const int* __restrict__ srcl, const int* __restrict__ rowstart,
    const int* __restrict__ rowperm, const float* __restrict__ dnorm,
    const float* __restrict__ bias, unsigned short* __restrict__ outbb,
    float* __restrict__ stats, int n)
{
    const int EMAX = N_EDGES - 1;
    __shared__ float bsm[32], bqm[32];
    int t = threadIdx.x;
    if (t < 32) { bsm[t] = 0.f; bqm[t] = 0.f; }
    __syncthreads();

    int bx = blockIdx.x;
    int xcd = bx & 7;              // empirically: workgroup -> XCD round-robin
    int c = xcd >> 1;              // chunk pinned to XCD pair
    int rb = (bx >> 3) * 2 + (xcd & 1);   // row-block within chunk (0..781)
    if (rb >= NBROW) return;
    int lane = t & 63;
    int w = t >> 6;                // wave 0..3
    int grp = lane >> 2;           // group 0..15 within wave (one row each)
    int l4 = lane & 3;             // lane in group: 8 feats (16 B) each
    int idx = rb * 64 + w * 16 + grp;
    bool rok = idx < n;
    int r = rok ? rowperm[idx] : 0;
    int start = rowstart[r];
    int deg = rowstart[r + 1] - start;
    float dnr = dnorm[r];
    if (!rok) { deg = 0; dnr = 0.f; }
    int len = deg + 1;             // + self loop

    const uint4* phc = ph128 + (size_t)c * (N_NODES * 4);   // 4 uint4 per 32-feat row

    float bi[8];
#pragma unroll
    for (int k = 0; k < 8; k++) bi[k] = bias[c * 32 + l4 * 8 + k];

    float a[8];
#pragma unroll
    for (int k = 0; k < 8; k++) a[k] = 0.f;

    for (int j = 0; j < len; j += 4) {
        uint4 uv[4];
#pragma unroll
        for (int u = 0; u < 4; u++) {
            int i = j + u;
            int sl = srcl[min(start + i, EMAX)];
            int s = (i < deg) ? sl : r;
            uv[u] = phc[(size_t)s * 4 + l4];
        }
#pragma unroll
        for (int u = 0; u < 4; u++) {
            int i = j + u;
            float wt = (i < len) ? 1.f : 0.f;
            unsigned rr[4] = { uv[u].x, uv[u].y, uv[u].z, uv[u].w };
#pragma unroll
            for (int d = 0; d < 4; d++) {
                a[2 * d]     += wt * bf2f((unsigned short)rr[d]);
                a[2 * d + 1] += wt * bf2f((unsigned short)(rr[d] >> 16));
            }
        }
    }

    float v[8];
#pragma unroll
    for (int k = 0; k < 8; k++) {
        float x = a[k] * dnr + bi[k];
        v[k] = x > 0.f ? x : 0.01f * x;
    }
    if (rok) {
        union { unsigned short us[8]; uint4 u; } ov;
#pragma unroll
        for (int k = 0; k < 8; k++) ov.us[k] = f2us(v[k]);
        *(uint4*)(outbb + (size_t)r * 128 + c * 32 + l4 * 8) = ov.u;
    } else {
#pragma unroll
        for (int k = 0; k < 8; k++) v[k] = 0.f;
    }

    float q[8];
#pragma unroll
    for (int k = 0; k < 8; k++) q[k] = v[k] * v[k];
    // reduce across the 16 groups of this wave (same feature at same l4)
#pragma unroll
    for (int mk = 4; mk < 64; mk <<= 1) {
#pragma unroll
        for (int k = 0; k < 8; k++) {
            v[k] += __shfl_xor(v[k], mk, 64);
            q[k] += __shfl_xor(q[k], mk, 64);
        }
    }
    if (grp == 0) {
#pragma unroll
        for (int k = 0; k < 8; k++) {
            atomicAdd(&bsm[l4 * 8 + k], v[k]);
            atomicAdd(&bqm[l4 * 8 + k], q[k]);
        }
    }
    __syncthreads();
    if (t < 32) {
        atomicAdd(&stats[c * 32 + t], bsm[t]);
        atomicAdd(&stats[128 + c * 32 + t], bqm[t]);
    }
}

// ---- segmented mean pool (bf16 input); BN scale/shift computed in-block ----
__global__ __launch_bounds__(256) void k_pool2(const unsigned short* __restrict__ outbb,
    const int* __restrict__ gstart, const float* __restrict__ stats,
    const float* __restrict__ bng, const float* __restrict__ bnb,
    float* __restrict__ gemb)
{
    __shared__ float scs[128], shs[128];
    int g = blockIdx.x;
    int t = threadIdx.x;
    if (t < 128) {
        float inv_n = 1.0f / (float)N_NODES;
        float mu = stats[t] * inv_n;
        float var = stats[128 + t] * inv_n - mu * mu;
        float rs = rsqrtf(var + 1e-5f);
        float sc = rs * bng[t];
        scs[t] = sc;
        shs[t] = bnb[t] - mu * sc;
    }
    __syncthreads();
    int f = t & 127;
    int half = t >> 7;
    int start = gstart[g], end = gstart[g + 1];
    int cnt = end - start;
    float s0 = 0.f, s1 = 0.f, s2 = 0.f, s3 = 0.f;
    int r = start + half;
    for (; r + 6 < end; r += 8) {
        s0 += bf2f(outbb[(size_t)(r    ) * 128 + f]);
        s1 += bf2f(outbb[(size_t)(r + 2) * 128 + f]);
        s2 += bf2f(outbb[(size_t)(r + 4) * 128 + f]);
        s3 += bf2f(outbb[(size_t)(r + 6) * 128 + f]);
    }
    for (; r < end; r += 2) s0 += bf2f(outbb[(size_t)r * 128 + f]);
    float sum = (s0 + s1) + (s2 + s3);
    __shared__ float sb[256];
    sb[t] = sum;
    __syncthreads();
    if (t < 128) {
        float tot = sb[t] + sb[t + 128];
        float v = (cnt > 0) ? (tot / (float)cnt) * scs[f] + shs[f] : 0.f;
        gemb[(size_t)g * 128 + f] = v;
    }
}

// ---- head layer 1 v2: split-K, no bias (folded into head2c), no atomics.
// grid (64, 4, 6): bx<32 graph (K=128, kc=0 only, direct store to projg);
// bx>=32 text (K=768, 6 K-slices, each stores its partial to projt6[kc]).
// Fixes round-5: 256 blocks / 6% occupancy / 52 us latency-bound loop. ----
__global__ __launch_bounds__(256) void k_head1x(const float* __restrict__ gemb,
    const float* __restrict__ textf,
    const float* __restrict__ gW1, const float* __restrict__ tW1,
    float* __restrict__ projg, float* __restrict__ projt6)
{
    __shared__ float ins[8][128];
    int bx = blockIdx.x;
    int kc = blockIdx.z;
    int isT = bx >= 32;
    if (!isT && kc > 0) return;
    int rb = isT ? bx - 32 : bx;
    const float* in = isT ? textf : gemb;
    int K = isT ? T_EMB : HID;
    const float* W = isT ? tW1 : gW1;
    float* outp = isT ? (projt6 + (size_t)kc * (N_GRAPHS * PROJ)) : projg;
    int k0 = kc * 128;

    int t = threadIdx.x;
    {
        int r = t >> 5, k = (t & 31) * 4;   // 8 rows x 128 floats
        *(float4*)&ins[r][k] = *(const float4*)(in + (size_t)(rb * 8 + r) * K + k0 + k);
    }
    __syncthreads();
    int col = blockIdx.y * 128 + (t & 127);
    int rg = t >> 7;
    float acc[4] = { 0.f, 0.f, 0.f, 0.f };
    const float* Wp = W + (size_t)k0 * 512 + col;
#pragma unroll 8
    for (int k = 0; k < 128; k++) {
        float w = Wp[(size_t)k * 512];
#pragma unroll
        for (int i = 0; i < 4; i++) acc[i] += ins[rg * 4 + i][k] * w;
    }
#pragma unroll
    for (int i = 0; i < 4; i++) {
        int row = rb * 8 + rg * 4 + i;
        outp[(size_t)row * 512 + col] = acc[i];
    }
}

// ---- fused head2 + LayerNorm + classifier + log_softmax, both heads.
// v2: sums the 6 text split-K partials and adds b1 here. ----
__global__ __launch_bounds__(256) void k_head2c(
    const float* __restrict__ projg, const float* __restrict__ projt6,
    const float* __restrict__ gb1, const float* __restrict__ tb1,
    const float* __restrict__ gW2, const float* __restrict__ gb2,
    const float* __restrict__ gg, const float* __restrict__ gbe,
    const float* __restrict__ gclW, const float* __restrict__ gclb,
    const float* __restrict__ tW2, const float* __restrict__ tb2,
    const float* __restrict__ tg, const float* __restrict__ tbe,
    const float* __restrict__ tclW, const float* __restrict__ tclb,
    float* __restrict__ o_gproj, float* __restrict__ o_tproj,
    float* __restrict__ o_glogp, float* __restrict__ o_tlogp)
{
    __shared__ float prow[512], grow[512], onorm[512], red[256];
    __shared__ float part[8][32];
    __shared__ float logits[32];
    __shared__ float mred, lred;
    int bx = blockIdx.x;
    int isT = bx >= N_GRAPHS;
    int row = isT ? bx - N_GRAPHS : bx;
    const float* b1 = isT ? tb1 : gb1;
    const float* W2 = isT ? tW2 : gW2;
    const float* b2 = isT ? tb2 : gb2;
    const float* g  = isT ? tg  : gg;
    const float* be = isT ? tbe : gbe;
    const float* Wc = isT ? tclW : gclW;
    const float* bc = isT ? tclb : gclb;
    float* oproj = isT ? o_tproj : o_gproj;
    float* ologp = isT ? o_tlogp : o_glogp;

    int t = threadIdx.x;
    for (int c = t; c < 512; c += 256) {
        float p;
        if (isT) {
            const float* pp = projt6 + (size_t)row * 512 + c;
            p = pp[0];
#pragma unroll
            for (int s = 1; s < 6; s++) p += pp[(size_t)s * (N_GRAPHS * PROJ)];
        } else {
            p = projg[(size_t)row * 512 + c];
        }
        p += b1[c];
        prow[c] = p;
        grow[c] = 0.5f * p * (1.0f + erff(p * 0.70710678118f));
    }
    __syncthreads();
    float a0 = 0.f, a1 = 0.f;
    int c0 = t, c1 = t + 256;
    for (int k = 0; k < 512; k++) {
        float gk = grow[k];
        a0 += gk * W2[(size_t)k * 512 + c0];
        a1 += gk * W2[(size_t)k * 512 + c1];
    }
    float h0 = a0 + b2[c0] + prow[c0];
    float h1 = a1 + b2[c1] + prow[c1];
    red[t] = h0 + h1;
    __syncthreads();
    for (int s = 128; s > 0; s >>= 1) { if (t < s) red[t] += red[t + s]; __syncthreads(); }
    float mu = red[0] * (1.0f / 512.0f);
    __syncthreads();
    float d0 = h0 - mu, d1 = h1 - mu;
    red[t] = d0 * d0 + d1 * d1;
    __syncthreads();
    for (int s = 128; s > 0; s >>= 1) { if (t < s) red[t] += red[t + s]; __syncthreads(); }
    float rs = rsqrtf(red[0] * (1.0f / 512.0f) + 1e-5f);
    float o0 = d0 * rs * g[c0] + be[c0];
    float o1 = d1 * rs * g[c1] + be[c1];
    onorm[c0] = o0;
    onorm[c1] = o1;
    oproj[(size_t)row * 512 + c0] = o0;
    oproj[(size_t)row * 512 + c1] = o1;
    __syncthreads();

    int c = t & 31, seg = t >> 5;
    float p = 0.f;
    for (int k = seg * 64; k < seg * 64 + 64; k++)
        p += onorm[k] * Wc[(size_t)k * 32 + c];
    part[seg][c] = p;
    __syncthreads();
    if (t < 32) {
        float l = bc[t];
#pragma unroll
        for (int s = 0; s < 8; s++) l += part[s][t];
        logits[t] = l;
    }
    __syncthreads();
    if (t == 0) {
        float m = logits[0];
        for (int i = 1; i < 32; i++) m = fmaxf(m, logits[i]);
        float sum = 0.f;
        for (int i = 0; i < 32; i++) sum += expf(logits[i] - m);
        mred = m; lred = logf(sum);
    }
    __syncthreads();
    if (t < 32) ologp[(size_t)row * 32 + t] = logits[t] - mred - lred;
}

extern "C" void kernel_launch(void* const* d_in, const int* in_sizes, int n_in,
                              void* d_out, int out_size, void* d_ws, size_t ws_size,
                              hipStream_t stream) {
    const float* x     = (const float*)d_in[0];
    const int*   ei    = (const int*)d_in[1];
    const int*   batch = (const int*)d_in[2];
    const float* textf = (const float*)d_in[3];
    const float* gcnW  = (const float*)d_in[4];
    const float* gcnb  = (const float*)d_in[5];
    const float* bng   = (const float*)d_in[6];
    const float* bnb   = (const float*)d_in[7];
    const float* gW1   = (const float*)d_in[8];
    const float* gb1   = (const float*)d_in[9];
    const float* gW2   = (const float*)d_in[10];
    const float* gb2   = (const float*)d_in[11];
    const float* gg    = (const float*)d_in[12];
    const float* gbe   = (const float*)d_in[13];
    const float* gclW  = (const float*)d_in[14];
    const float* gclb  = (const float*)d_in[15];
    const float* tW1   = (const float*)d_in[16];
    const float* tb1   = (const float*)d_in[17];
    const float* tW2   = (const float*)d_in[18];
    const float* tb2   = (const float*)d_in[19];
    const float* tg    = (const float*)d_in[20];
    const float* tbe   = (const float*)d_in[21];
    const float* tclW  = (const float*)d_in[22];
    const float* tclb  = (const float*)d_in[23];

    const int N = N_NODES, E = N_EDGES;
    const int NF = N * HID;

    float* p = (float*)d_ws;
    unsigned short* outbb = (unsigned short*)p; p += NF / 2;   // 12.8 MB bf16
    unsigned short* ph    = (unsigned short*)p; p += NF / 2;   // 12.8 MB bf16 chunk-major
    unsigned short* Wt    = (unsigned short*)p; p += 4 * 16384 / 2;
    float* dnorm  = p; p += N;
    float* gemb   = p; p += N_GRAPHS * HID;
    float* projg  = p; p += N_GRAPHS * PROJ;
    float* projt6 = p; p += 6 * N_GRAPHS * PROJ;               // split-K partials (3 MB)
    // contiguous zero-init region: cnt | cursor | stats4 | dhist
    int* cnt      = (int*)p; p += N;
    int* cursor   = (int*)p; p += N;
    float* stats4 = p; p += 4 * 256;
    int* dhist    = (int*)p; p += DBINS;
    int* rowstart = (int*)p; p += N + 1;
    int* gstart   = (int*)p; p += N_GRAPHS + 1;
    int* bsum     = (int*)p; p += 256;
    int* srcl     = (int*)p; p += E;
    int* doff     = (int*)p; p += DBINS;
    int* rowperm  = (int*)p; p += N;

    float* outp = (float*)d_out;
    float* o_gproj = outp;
    float* o_tproj = outp + N_GRAPHS * PROJ;
    float* o_glogp = o_tproj + N_GRAPHS * PROJ;
    float* o_tlogp = o_glogp + N_GRAPHS * N_CLS;

    // ---- CSR build + degree-sort + prep ----
    hipMemsetAsync(cnt, 0, (size_t)(2 * N + 4 * 256 + DBINS) * sizeof(int), stream);
    k_deg<<<ESLICE * 8, 256, 0, stream>>>(ei, cnt, E);
    k_scan1<<<NB_SCAN, 256, 0, stream>>>(cnt, rowstart, dnorm, bsum);
    k_scan2<<<1, 256, 0, stream>>>(bsum);
    k_scan3<<<NB_SCAN, 256, 0, stream>>>(rowstart, bsum, cnt, dhist);
    k_fill<<<ESLICE * 8, 256, 0, stream>>>(ei, rowstart, cursor, srcl, E);
    k_dscan<<<1, 256, 0, stream>>>(dhist, doff);
    k_dperm<<<(N + 1023) / 1024, 1024, 0, stream>>>(cnt, doff, rowperm);
    k_prep<<<(4 * 16384 + N + 1 + 255) / 256, 256, 0, stream>>>(gcnW, Wt, batch, gstart);

    // ---- 4 GCN layers (BN of layer l-1 folded into mm of layer l) ----
    for (int l = 0; l < 4; l++) {
        const void* in = (l == 0) ? (const void*)x : (const void*)outbb;
        const float* st = (l == 0) ? nullptr : stats4 + (l - 1) * 256;
        const float* bg = (l == 0) ? nullptr : bng + (size_t)(l - 1) * HID;
        const float* bb = (l == 0) ? nullptr : bnb + (size_t)(l - 1) * HID;
        k_gcn_mm_mfma<<<(N + 63) / 64, 256, 0, stream>>>(in, Wt + (size_t)l * 16384,
                                                         st, bg, bb, dnorm, ph, N);
        k_gather_c<<<NBG2 * 8, 256, 0, stream>>>((const uint4*)ph, srcl,
                                                 rowstart, rowperm, dnorm,
                                                 gcnb + (size_t)l * HID, outbb,
                                                 stats4 + l * 256, N);
    }

    // ---- segmented mean pool (layer-3 BN folded in-block) ----
    k_pool2<<<N_GRAPHS, 256, 0, stream>>>(outbb, gstart, stats4 + 3 * 256,
                                          bng + 3 * HID, bnb + 3 * HID, gemb);

    // ---- fused heads ----
    k_head1x<<<dim3(64, 4, 6), 256, 0, stream>>>(gemb, textf, gW1, tW1, projg, projt6);
    k_head2c<<<2 * N_GRAPHS, 256, 0, stream>>>(projg, projt6, gb1, tb1,
                                               gW2, gb2, gg, gbe, gclW, gclb,
                                               tW2, tb2, tg, tbe, tclW, tclb,
                                               o_gproj, o_tproj, o_glogp, o_tlogp);
}

// Round 7
// 457.744 us; speedup vs baseline: 2.0937x; 1.0112x over previous
//
#include <hip/hip_runtime.h>
#include <hip/hip_bf16.h>

// Problem sizes (fixed by reference)
#define N_NODES 50000
#define N_EDGES 800000
#define F_IN    128
#define HID     128
#define PROJ    512
#define N_CLS   32
#define N_GRAPHS 256
#define T_EMB   768
#define NB_SCAN ((N_NODES + 255) / 256)   // 196
#define DBINS   1024
#define NBROW   ((N_NODES + 63) / 64)     // 782 row-blocks (64 rows each)
#define NBG2    ((NBROW + 1) / 2)         // 391 row-block pairs per chunk
#define SHW     6250                      // dst rows per XCD shard (8*6250 = 50000)
#define ESLICE  ((N_EDGES + 4095) / 4096) // 196 edge slices of 4096

typedef __attribute__((ext_vector_type(8))) short bf16x8;
typedef __attribute__((ext_vector_type(4))) float f32x4;

__device__ __forceinline__ float bf2f(unsigned short u) {
    unsigned v = ((unsigned)u) << 16;
    return __uint_as_float(v);
}
__device__ __forceinline__ unsigned short f2us(float v) {
    __hip_bfloat16 b = __float2bfloat16(v);
    union { __hip_bfloat16 b; unsigned short u; } c; c.b = b; return c.u;
}

// ---- degree histogram, XCD-sharded: shard s=bid&7 owns dst rows
// [s*SHW,(s+1)*SHW) -> cnt lines stay exclusive to one XCD's L2. ----
__global__ __launch_bounds__(256) void k_deg(const int* __restrict__ ei,
                                             int* __restrict__ cnt, int nE) {
    int bx = blockIdx.x;
    int s = bx & 7;
    int slice = bx >> 3;
    int lo = s * SHW, hi = lo + SHW;
    int base = slice * 4096 + threadIdx.x;
#pragma unroll 4
    for (int u = 0; u < 16; u++) {
        int e = base + u * 256;
        if (e < nE) {
            int d = ei[nE + e];
            if (d >= lo && d < hi) atomicAdd(cnt + d, 1);
        }
    }
}

// ---- parallel scan pass 1 ----
__global__ __launch_bounds__(256) void k_scan1(const int* __restrict__ cnt,
    int* __restrict__ rowstart, float* __restrict__ dnorm, int* __restrict__ bsum)
{
    __shared__ int ps[256];
    int t = threadIdx.x;
    int i = blockIdx.x * 256 + t;
    int c = (i < N_NODES) ? cnt[i] : 0;
    if (i < N_NODES) dnorm[i] = rsqrtf((float)c + 1.0f);
    ps[t] = c;
    __syncthreads();
    for (int off = 1; off < 256; off <<= 1) {
        int v = (t >= off) ? ps[t - off] : 0;
        __syncthreads();
        ps[t] += v;
        __syncthreads();
    }
    if (i < N_NODES) rowstart[i] = ps[t] - c;
    if (t == 255) bsum[blockIdx.x] = ps[255];
}

// ---- scan pass 2 ----
__global__ __launch_bounds__(256) void k_scan2(int* __restrict__ bsum) {
    __shared__ int ps[256];
    int t = threadIdx.x;
    int v = (t < NB_SCAN) ? bsum[t] : 0;
    ps[t] = v;
    __syncthreads();
    for (int off = 1; off < 256; off <<= 1) {
        int u = (t >= off) ? ps[t - off] : 0;
        __syncthreads();
        ps[t] += u;
        __syncthreads();
    }
    if (t < NB_SCAN) bsum[t] = ps[t] - v;
}

// ---- scan pass 3 (+ LDS-aggregated degree histogram for LPT sort) ----
__global__ __launch_bounds__(256) void k_scan3(int* __restrict__ rowstart,
    const int* __restrict__ bsum, const int* __restrict__ cnt,
    int* __restrict__ dhist)
{
    __shared__ int lh[DBINS];
    int t = threadIdx.x;
    for (int k = t; k < DBINS; k += 256) lh[k] = 0;
    __syncthreads();
    int i = blockIdx.x * 256 + t;
    if (i < N_NODES) {
        rowstart[i] += bsum[blockIdx.x];
        atomicAdd(&lh[min(cnt[i], DBINS - 1)], 1);
    }
    if (i == 0) rowstart[N_NODES] = N_EDGES;
    __syncthreads();
    for (int k = t; k < DBINS; k += 256) {
        int v = lh[k];
        if (v) atomicAdd(dhist + k, v);
    }
}

// ---- descending-degree exclusive offsets: doff[d] = #rows with degree > d ----
__global__ __launch_bounds__(256) void k_dscan(const int* __restrict__ dhist,
                                               int* __restrict__ doff) {
    __shared__ int part[256];
    __shared__ int binv[DBINS];
    int t = threadIdx.x;
    int base = t * 4;
    int g0 = dhist[DBINS - 1 - (base + 0)];
    int g1 = dhist[DBINS - 1 - (base + 1)];
    int g2 = dhist[DBINS - 1 - (base + 2)];
    int g3 = dhist[DBINS - 1 - (base + 3)];
    int s = g0 + g1 + g2 + g3;
    part[t] = s;
    __syncthreads();
    for (int off = 1; off < 256; off <<= 1) {
        int v = (t >= off) ? part[t - off] : 0;
        __syncthreads();
        part[t] += v;
        __syncthreads();
    }
    int run = part[t] - s;   // exclusive prefix of this thread's 4 bins
    binv[base + 0] = run; run += g0;
    binv[base + 1] = run; run += g1;
    binv[base + 2] = run; run += g2;
    binv[base + 3] = run; run += g3;
    __syncthreads();
    for (int k = t; k < DBINS; k += 256) doff[DBINS - 1 - k] = binv[k];
}

// ---- scatter rows into degree-descending permutation (two-phase, LDS ranks;
// one global atomic per non-empty bin per block -> no same-address storm) ----
__global__ __launch_bounds__(1024) void k_dperm(const int* __restrict__ cnt,
    int* __restrict__ doff, int* __restrict__ rowperm)
{
    __shared__ int lh[DBINS];
    __shared__ int lbase[DBINS];
    int t = threadIdx.x;
    if (t < DBINS) lh[t] = 0;
    __syncthreads();
    int i = blockIdx.x * 1024 + t;
    int bin = 0, lrank = 0;
    bool ok = i < N_NODES;
    if (ok) {
        bin = min(cnt[i], DBINS - 1);
        lrank = atomicAdd(&lh[bin], 1);
    }
    __syncthreads();
    if (t < DBINS) {
        int v = lh[t];
        if (v) lbase[t] = atomicAdd(doff + t, v);
    }
    __syncthreads();
    if (ok) rowperm[lbase[bin] + lrank] = i;
}

// ---- fill CSR src lists, XCD-sharded like k_deg ----
__global__ __launch_bounds__(256) void k_fill(const int* __restrict__ ei,
    const int* __restrict__ rowstart, int* __restrict__ cursor,
    int* __restrict__ srcl, int nE)
{
    int bx = blockIdx.x;
    int s = bx & 7;
    int slice = bx >> 3;
    int lo = s * SHW, hi = lo + SHW;
    int base = slice * 4096 + threadIdx.x;
#pragma unroll 4
    for (int u = 0; u < 16; u++) {
        int e = base + u * 256;
        if (e < nE) {
            int d = ei[nE + e];
            if (d >= lo && d < hi) {
                int pos = rowstart[d] + atomicAdd(cursor + d, 1);
                srcl[pos] = ei[e];
            }
        }
    }
}

// ---- combined prep: weight transpose+bf16 and graph boundaries ----
__global__ void k_prep(const float* __restrict__ W, unsigned short* __restrict__ Wt,
                       const int* __restrict__ batch, int* __restrict__ gstart) {
    int t = blockIdx.x * 256 + threadIdx.x;
    if (t < 4 * 128 * 128) {
        int l = t >> 14;
        int k = (t >> 7) & 127;
        int n = t & 127;
        Wt[(size_t)l * 16384 + n * 128 + k] = f2us(W[(size_t)l * 16384 + k * 128 + n]);
    } else {
        int r = t - 4 * 128 * 128;
        if (r <= N_NODES) {
            int b  = (r < N_NODES) ? batch[r] : N_GRAPHS;
            int bp = (r > 0) ? batch[r - 1] : -1;
            for (int g = bp + 1; g <= b && g <= N_GRAPHS; g++) gstart[g] = r;
        }
    }
}

// ---- GCN matmul via bf16 MFMA; ph output CHUNK-MAJOR [4][N][32] bf16. ----
__global__ __launch_bounds__(256) void k_gcn_mm_mfma(const void* __restrict__ inp,
    const unsigned short* __restrict__ Wt,   // [128 n][128 k] bf16 (n-major)
    const float* __restrict__ stats, const float* __restrict__ bng,
    const float* __restrict__ bnb, const float* __restrict__ dnorm,
    unsigned short* __restrict__ ph, int n)
{
    __shared__ __align__(16) unsigned short Bs[128][136];   // 34.8 KB (reused as C-staging)
    __shared__ float scs[128], shs[128];
    int t = threadIdx.x;
    int row0 = blockIdx.x * 64;

    if (stats && t < 128) {
        float inv_n = 1.0f / (float)N_NODES;
        float mu = stats[t] * inv_n;
        float var = stats[128 + t] * inv_n - mu * mu;
        float rs = rsqrtf(var + 1e-5f);
        float sc = rs * bng[t];
        scs[t] = sc;
        shs[t] = bnb[t] - mu * sc;
    }
#pragma unroll
    for (int i = 0; i < 8; i++) {
        int c = t + i * 256;
        int nn = c >> 4;
        int k8 = (c & 15) * 8;
        *(uint4*)&Bs[nn][k8] = *(const uint4*)(Wt + (size_t)nn * 128 + k8);
    }
    __syncthreads();

    int w = t >> 6, lane = t & 63;
    int m = lane & 15, quad = lane >> 4;
    int arow = row0 + w * 16 + m;        // this lane's A row
    bool rowok = arow < n;

    // load A fragments for all 4 k-chunks (16 B each, aligned)
    bf16x8 afrag[4];
    if (!stats) {
        const float* inf = (const float*)inp;
#pragma unroll
        for (int ki = 0; ki < 4; ki++) {
            int k8 = ki * 32 + quad * 8;
            float4 v0 = make_float4(0.f, 0.f, 0.f, 0.f);
            float4 v1 = make_float4(0.f, 0.f, 0.f, 0.f);
            if (rowok) {
                v0 = *(const float4*)(inf + (size_t)arow * 128 + k8);
                v1 = *(const float4*)(inf + (size_t)arow * 128 + k8 + 4);
            }
            union { unsigned short u[8]; bf16x8 v; } pk;
            pk.u[0] = f2us(v0.x); pk.u[1] = f2us(v0.y); pk.u[2] = f2us(v0.z); pk.u[3] = f2us(v0.w);
            pk.u[4] = f2us(v1.x); pk.u[5] = f2us(v1.y); pk.u[6] = f2us(v1.z); pk.u[7] = f2us(v1.w);
            afrag[ki] = pk.v;
        }
    } else {
        const unsigned short* inb = (const unsigned short*)inp;
#pragma unroll
        for (int ki = 0; ki < 4; ki++) {
            int k8 = ki * 32 + quad * 8;
            uint4 raw = make_uint4(0, 0, 0, 0);
            if (rowok) raw = *(const uint4*)(inb + (size_t)arow * 128 + k8);
            unsigned rr[4] = { raw.x, raw.y, raw.z, raw.w };
            union { unsigned short u[8]; bf16x8 v; } pk;
#pragma unroll
            for (int j = 0; j < 4; j++) {
                int f0 = k8 + 2 * j, f1 = k8 + 2 * j + 1;
                float a0 = bf2f((unsigned short)rr[j]) * scs[f0] + shs[f0];
                float a1 = bf2f((unsigned short)(rr[j] >> 16)) * scs[f1] + shs[f1];
                pk.u[2 * j] = f2us(a0);
                pk.u[2 * j + 1] = f2us(a1);
            }
            afrag[ki] = pk.v;
        }
    }

    f32x4 acc[8];
#pragma unroll
    for (int nt = 0; nt < 8; nt++) acc[nt] = (f32x4){0.f, 0.f, 0.f, 0.f};
#pragma unroll
    for (int ki = 0; ki < 4; ki++) {
#pragma unroll
        for (int nt = 0; nt < 8; nt++) {
            bf16x8 b = *(const bf16x8*)&Bs[nt * 16 + m][ki * 32 + quad * 8];
            acc[nt] = __builtin_amdgcn_mfma_f32_16x16x32_bf16(afrag[ki], b, acc[nt], 0, 0, 0);
        }
    }

    float dn[4];
#pragma unroll
    for (int reg = 0; reg < 4; reg++) {
        int gr = row0 + w * 16 + quad * 4 + reg;
        dn[reg] = (gr < n) ? dnorm[gr] : 0.f;
    }

    // ---- epilogue: transpose C through LDS (reuse Bs), store chunk-major ----
    __syncthreads();   // all waves finished reading Bs
#pragma unroll
    for (int nt = 0; nt < 8; nt++) {
#pragma unroll
        for (int reg = 0; reg < 4; reg++) {
            Bs[w * 16 + quad * 4 + reg][nt * 16 + m] = f2us(acc[nt][reg] * dn[reg]);
        }
    }
    __syncthreads();
#pragma unroll
    for (int i = 0; i < 4; i++) {
        int idx = t + i * 256;           // 0..1023
        int r = idx >> 4;                // 0..63
        int c8 = (idx & 15) * 8;         // 0..120
        int gr = row0 + r;
        int ch = c8 >> 5;                // chunk 0..3
        int off = c8 & 31;               // 0,8,16,24
        if (gr < n)
            *(uint4*)(ph + (size_t)ch * (N_NODES * 32) + (size_t)gr * 32 + off)
                = *(const uint4*)&Bs[r][c8];
    }
}

// ---- feature-chunked pair-gather v5: chunk PINNED to XCD pair via bid%8. ----
__global__ __launch_bounds__(256) void k_gather_c(const uint4* __restrict__ ph128,
    const int* __restrict__ srcl, const int* __restrict__ rowstart,
    const int* __restrict__ rowperm, const float* __restrict__ dnorm,
    const float* __restrict__ bias, unsigned short* __restrict__ outbb,
    float* __restrict__ stats, int n)
{
    const int EMAX = N_EDGES - 1;
    __shared__ float bsm[32], bqm[32];
    int t = threadIdx.x;
    if (t < 32) { bsm[t] = 0.f; bqm[t] = 0.f; }
    __syncthreads();

    int bx = blockIdx.x;
    int xcd = bx & 7;              // empirically: workgroup -> XCD round-robin
    int c = xcd >> 1;              // chunk pinned to XCD pair
    int rb = (bx >> 3) * 2 + (xcd & 1);   // row-block within chunk (0..781)
    if (rb >= NBROW) return;
    int lane = t & 63;
    int w = t >> 6;                // wave 0..3
    int grp = lane >> 2;           // group 0..15 within wave (one row each)
    int l4 = lane & 3;             // lane in group: 8 feats (16 B) each
    int idx = rb * 64 + w * 16 + grp;
    bool rok = idx < n;
    int r = rok ? rowperm[idx] : 0;
    int start = rowstart[r];
    int deg = rowstart[r + 1] - start;
    float dnr = dnorm[r];
    if (!rok) { deg = 0; dnr = 0.f; }
    int len = deg + 1;             // + self loop

    const uint4* phc = ph128 + (size_t)c * (N_NODES * 4);   // 4 uint4 per 32-feat row

    float bi[8];
#pragma unroll
    for (int k = 0; k < 8; k++) bi[k] = bias[c * 32 + l4 * 8 + k];

    float a[8];
#pragma unroll
    for (int k = 0; k < 8; k++) a[k] = 0.f;

    for (int j = 0; j < len; j += 4) {
        uint4 uv[4];
#pragma unroll
        for (int u = 0; u < 4; u++) {
            int i = j + u;
            int sl = srcl[min(start + i, EMAX)];
            int s = (i < deg) ? sl : r;
            uv[u] = phc[(size_t)s * 4 + l4];
        }
#pragma unroll
        for (int u = 0; u < 4; u++) {
            int i = j + u;
            float wt = (i < len) ? 1.f : 0.f;
            unsigned rr[4] = { uv[u].x, uv[u].y, uv[u].z, uv[u].w };
#pragma unroll
            for (int d = 0; d < 4; d++) {
                a[2 * d]     += wt * bf2f((unsigned short)rr[d]);
                a[2 * d + 1] += wt * bf2f((unsigned short)(rr[d] >> 16));
            }
        }
    }

    float v[8];
#pragma unroll
    for (int k = 0; k < 8; k++) {
        float x = a[k] * dnr + bi[k];
        v[k] = x > 0.f ? x : 0.01f * x;
    }
    if (rok) {
        union { unsigned short us[8]; uint4 u; } ov;
#pragma unroll
        for (int k = 0; k < 8; k++) ov.us[k] = f2us(v[k]);
        *(uint4*)(outbb + (size_t)r * 128 + c * 32 + l4 * 8) = ov.u;
    } else {
#pragma unroll
        for (int k = 0; k < 8; k++) v[k] = 0.f;
    }

    float q[8];
#pragma unroll
    for (int k = 0; k < 8; k++) q[k] = v[k] * v[k];
    // reduce across the 16 groups of this wave (same feature at same l4)
#pragma unroll
    for (int mk = 4; mk < 64; mk <<= 1) {
#pragma unroll
        for (int k = 0; k < 8; k++) {
            v[k] += __shfl_xor(v[k], mk, 64);
            q[k] += __shfl_xor(q[k], mk, 64);
        }
    }
    if (grp == 0) {
#pragma unroll
        for (int k = 0; k < 8; k++) {
            atomicAdd(&bsm[l4 * 8 + k], v[k]);
            atomicAdd(&bqm[l4 * 8 + k], q[k]);
        }
    }
    __syncthreads();
    if (t < 32) {
        atomicAdd(&stats[c * 32 + t], bsm[t]);
        atomicAdd(&stats[128 + c * 32 + t], bqm[t]);
    }
}

// ---- segmented mean pool (bf16 input); BN scale/shift computed in-block ----
__global__ __launch_bounds__(256) void k_pool2(const unsigned short* __restrict__ outbb,
    const int* __restrict__ gstart, const float* __restrict__ stats,
    const float* __restrict__ bng, const float* __restrict__ bnb,
    float* __restrict__ gemb)
{
    __shared__ float scs[128], shs[128];
    int g = blockIdx.x;
    int t = threadIdx.x;
    if (t < 128) {
        float inv_n = 1.0f / (float)N_NODES;
        float mu = stats[t] * inv_n;
        float var = stats[128 + t] * inv_n - mu * mu;
        float rs = rsqrtf(var + 1e-5f);
        float sc = rs * bng[t];
        scs[t] = sc;
        shs[t] = bnb[t] - mu * sc;
    }
    __syncthreads();
    int f = t & 127;
    int half = t >> 7;
    int start = gstart[g], end = gstart[g + 1];
    int cnt = end - start;
    float s0 = 0.f, s1 = 0.f, s2 = 0.f, s3 = 0.f;
    int r = start + half;
    for (; r + 6 < end; r += 8) {
        s0 += bf2f(outbb[(size_t)(r    ) * 128 + f]);
        s1 += bf2f(outbb[(size_t)(r + 2) * 128 + f]);
        s2 += bf2f(outbb[(size_t)(r + 4) * 128 + f]);
        s3 += bf2f(outbb[(size_t)(r + 6) * 128 + f]);
    }
    for (; r < end; r += 2) s0 += bf2f(outbb[(size_t)r * 128 + f]);
    float sum = (s0 + s1) + (s2 + s3);
    __shared__ float sb[256];
    sb[t] = sum;
    __syncthreads();
    if (t < 128) {
        float tot = sb[t] + sb[t + 128];
        float v = (cnt > 0) ? (tot / (float)cnt) * scs[f] + shs[f] : 0.f;
        gemb[(size_t)g * 128 + f] = v;
    }
}

// ---- head layer 1 v2: split-K, no bias (folded downstream), no atomics. ----
__global__ __launch_bounds__(256) void k_head1x(const float* __restrict__ gemb,
    const float* __restrict__ textf,
    const float* __restrict__ gW1, const float* __restrict__ tW1,
    float* __restrict__ projg, float* __restrict__ projt6)
{
    __shared__ float ins[8][128];
    int bx = blockIdx.x;
    int kc = blockIdx.z;
    int isT = bx >= 32;
    if (!isT && kc > 0) return;
    int rb = isT ? bx - 32 : bx;
    const float* in = isT ? textf : gemb;
    int K = isT ? T_EMB : HID;
    const float* W = isT ? tW1 : gW1;
    float* outp = isT ? (projt6 + (size_t)kc * (N_GRAPHS * PROJ)) : projg;
    int k0 = kc * 128;

    int t = threadIdx.x;
    {
        int r = t >> 5, k = (t & 31) * 4;   // 8 rows x 128 floats
        *(float4*)&ins[r][k] = *(const float4*)(in + (size_t)(rb * 8 + r) * K + k0 + k);
    }
    __syncthreads();
    int col = blockIdx.y * 128 + (t & 127);
    int rg = t >> 7;
    float acc[4] = { 0.f, 0.f, 0.f, 0.f };
    const float* Wp = W + (size_t)k0 * 512 + col;
#pragma unroll 8
    for (int k = 0; k < 128; k++) {
        float w = Wp[(size_t)k * 512];
#pragma unroll
        for (int i = 0; i < 4; i++) acc[i] += ins[rg * 4 + i][k] * w;
    }
#pragma unroll
    for (int i = 0; i < 4; i++) {
        int row = rb * 8 + rg * 4 + i;
        outp[(size_t)row * 512 + col] = acc[i];
    }
}

// ---- hprep: materialize prow = proj + b1 (summing text split-K partials
// once) and grow = gelu(prow) for all 512 rows. ----
__global__ __launch_bounds__(256) void k_hprep(const float* __restrict__ projg,
    const float* __restrict__ projt6, const float* __restrict__ gb1,
    const float* __restrict__ tb1, float* __restrict__ prow_buf,
    float* __restrict__ grow_buf)
{
    int idx = (blockIdx.x * 256 + threadIdx.x) * 4;   // 512*512 total floats
    int row = idx >> 9;
    int c = idx & 511;
    int isT = row >= N_GRAPHS;
    int lrow = row & (N_GRAPHS - 1);
    const float* b1 = isT ? tb1 : gb1;
    float4 p;
    if (isT) {
        const float* pp = projt6 + (size_t)lrow * 512 + c;
        p = *(const float4*)pp;
#pragma unroll
        for (int s = 1; s < 6; s++) {
            float4 q = *(const float4*)(pp + (size_t)s * (N_GRAPHS * PROJ));
            p.x += q.x; p.y += q.y; p.z += q.z; p.w += q.w;
        }
    } else {
        p = *(const float4*)(projg + (size_t)lrow * 512 + c);
    }
    float4 b = *(const float4*)(b1 + c);
    p.x += b.x; p.y += b.y; p.z += b.z; p.w += b.w;
    *(float4*)(prow_buf + (size_t)row * 512 + c) = p;
    float4 g;
    g.x = 0.5f * p.x * (1.0f + erff(p.x * 0.70710678118f));
    g.y = 0.5f * p.y * (1.0f + erff(p.y * 0.70710678118f));
    g.z = 0.5f * p.z * (1.0f + erff(p.z * 0.70710678118f));
    g.w = 0.5f * p.w * (1.0f + erff(p.w * 0.70710678118f));
    *(float4*)(grow_buf + (size_t)row * 512 + c) = g;
}

// ---- head2a: split-K GEMM h2 = grow @ W2 (per-head W2), partials to h2p.
// grid (64 rowblk, 4 colchunk, 4 kchunk) = 1024 blocks (~4/CU) — fixes
// round-6: 512-block head2c at 19% occupancy / 45 us. ----
__global__ __launch_bounds__(256) void k_head2a(const float* __restrict__ grow_buf,
    const float* __restrict__ gW2, const float* __restrict__ tW2,
    float* __restrict__ h2p)
{
    __shared__ float gs[8][128];
    int rb = blockIdx.x;      // 0..63 (8 rows each; rb>=32 -> text head)
    int cc = blockIdx.y;      // 0..3
    int kc = blockIdx.z;      // 0..3
    int isT = rb >= 32;
    const float* W2 = isT ? tW2 : gW2;
    int t = threadIdx.x;
    {
        int r = t >> 5, k4 = (t & 31) * 4;
        *(float4*)&gs[r][k4] =
            *(const float4*)(grow_buf + (size_t)(rb * 8 + r) * 512 + kc * 128 + k4);
    }
    __syncthreads();
    int col = cc * 128 + (t & 127);
    int rg = t >> 7;
    float acc[4] = { 0.f, 0.f, 0.f, 0.f };
    const float* Wp = W2 + (size_t)(kc * 128) * 512 + col;
#pragma unroll 8
    for (int k = 0; k < 128; k++) {
        float w = Wp[(size_t)k * 512];
#pragma unroll
        for (int i = 0; i < 4; i++) acc[i] += gs[rg * 4 + i][k] * w;
    }
#pragma unroll
    for (int i = 0; i < 4; i++) {
        int row = rb * 8 + rg * 4 + i;
        h2p[(size_t)kc * (512 * 512) + (size_t)row * 512 + col] = acc[i];
    }
}

// ---- head2b: sum split-K partials + b2 + residual -> LayerNorm -> oproj,
// classifier + log_softmax. One block per row (cheap now, no 512-deep loop). ----
__global__ __launch_bounds__(256) void k_head2b(const float* __restrict__ h2p,
    const float* __restrict__ prow_buf,
    const float* __restrict__ gb2, const float* __restrict__ gg,
    const float* __restrict__ gbe, const float* __restrict__ gclW,
    const float* __restrict__ gclb,
    const float* __restrict__ tb2, const float* __restrict__ tg,
    const float* __restrict__ tbe, const float* __restrict__ tclW,
    const float* __restrict__ tclb,
    float* __restrict__ o_gproj, float* __restrict__ o_tproj,
    float* __restrict__ o_glogp, float* __restrict__ o_tlogp)
{
    __shared__ float onorm[512], red[256];
    __shared__ float part[8][32];
    __shared__ float logits[32];
    __shared__ float mred, lred;
    int bx = blockIdx.x;              // global row 0..511
    int isT = bx >= N_GRAPHS;
    int row = bx & (N_GRAPHS - 1);
    const float* b2 = isT ? tb2 : gb2;
    const float* g  = isT ? tg  : gg;
    const float* be = isT ? tbe : gbe;
    const float* Wc = isT ? tclW : gclW;
    const float* bc = isT ? tclb : gclb;
    float* oproj = isT ? o_tproj : o_gproj;
    float* ologp = isT ? o_tlogp : o_glogp;

    int t = threadIdx.x;
    int c0 = t, c1 = t + 256;
    size_t base = (size_t)bx * 512;
    float h0 = prow_buf[base + c0] + b2[c0];
    float h1 = prow_buf[base + c1] + b2[c1];
#pragma unroll
    for (int kc = 0; kc < 4; kc++) {
        h0 += h2p[(size_t)kc * (512 * 512) + base + c0];
        h1 += h2p[(size_t)kc * (512 * 512) + base + c1];
    }
    red[t] = h0 + h1;
    __syncthreads();
    for (int s = 128; s > 0; s >>= 1) { if (t < s) red[t] += red[t + s]; __syncthreads(); }
    float mu = red[0] * (1.0f / 512.0f);
    __syncthreads();
    float d0 = h0 - mu, d1 = h1 - mu;
    red[t] = d0 * d0 + d1 * d1;
    __syncthreads();
    for (int s = 128; s > 0; s >>= 1) { if (t < s) red[t] += red[t + s]; __syncthreads(); }
    float rs = rsqrtf(red[0] * (1.0f / 512.0f) + 1e-5f);
    float o0 = d0 * rs * g[c0] + be[c0];
    float o1 = d1 * rs * g[c1] + be[c1];
    onorm[c0] = o0;
    onorm[c1] = o1;
    oproj[(size_t)row * 512 + c0] = o0;
    oproj[(size_t)row * 512 + c1] = o1;
    __syncthreads();

    int c = t & 31, seg = t >> 5;
    float p = 0.f;
    for (int k = seg * 64; k < seg * 64 + 64; k++)
        p += onorm[k] * Wc[(size_t)k * 32 + c];
    part[seg][c] = p;
    __syncthreads();
    if (t < 32) {
        float l = bc[t];
#pragma unroll
        for (int s = 0; s < 8; s++) l += part[s][t];
        logits[t] = l;
    }
    __syncthreads();
    if (t == 0) {
        float m = logits[0];
        for (int i = 1; i < 32; i++) m = fmaxf(m, logits[i]);
        float sum = 0.f;
        for (int i = 0; i < 32; i++) sum += expf(logits[i] - m);
        mred = m; lred = logf(sum);
    }
    __syncthreads();
    if (t < 32) ologp[(size_t)row * 32 + t] = logits[t] - mred - lred;
}

extern "C" void kernel_launch(void* const* d_in, const int* in_sizes, int n_in,
                              void* d_out, int out_size, void* d_ws, size_t ws_size,
                              hipStream_t stream) {
    const float* x     = (const float*)d_in[0];
    const int*   ei    = (const int*)d_in[1];
    const int*   batch = (const int*)d_in[2];
    const float* textf = (const float*)d_in[3];
    const float* gcnW  = (const float*)d_in[4];
    const float* gcnb  = (const float*)d_in[5];
    const float* bng   = (const float*)d_in[6];
    const float* bnb   = (const float*)d_in[7];
    const float* gW1   = (const float*)d_in[8];
    const float* gb1   = (const float*)d_in[9];
    const float* gW2   = (const float*)d_in[10];
    const float* gb2   = (const float*)d_in[11];
    const float* gg    = (const float*)d_in[12];
    const float* gbe   = (const float*)d_in[13];
    const float* gclW  = (const float*)d_in[14];
    const float* gclb  = (const float*)d_in[15];
    const float* tW1   = (const float*)d_in[16];
    const float* tb1   = (const float*)d_in[17];
    const float* tW2   = (const float*)d_in[18];
    const float* tb2   = (const float*)d_in[19];
    const float* tg    = (const float*)d_in[20];
    const float* tbe   = (const float*)d_in[21];
    const float* tclW  = (const float*)d_in[22];
    const float* tclb  = (const float*)d_in[23];

    const int N = N_NODES, E = N_EDGES;
    const int NF = N * HID;

    float* p = (float*)d_ws;
    unsigned short* outbb = (unsigned short*)p; p += NF / 2;   // 12.8 MB bf16
    unsigned short* ph    = (unsigned short*)p; p += NF / 2;   // 12.8 MB bf16 chunk-major
    unsigned short* Wt    = (unsigned short*)p; p += 4 * 16384 / 2;
    float* dnorm    = p; p += N;
    float* gemb     = p; p += N_GRAPHS * HID;
    float* projg    = p; p += N_GRAPHS * PROJ;
    float* projt6   = p; p += 6 * N_GRAPHS * PROJ;             // split-K partials (3 MB)
    float* prow_buf = p; p += 512 * PROJ;                      // 1 MB
    float* grow_buf = p; p += 512 * PROJ;                      // 1 MB
    float* h2p      = p; p += 4 * 512 * PROJ;                  // 4 MB split-K partials
    // contiguous zero-init region: cnt | cursor | stats4 | dhist
    int* cnt      = (int*)p; p += N;
    int* cursor   = (int*)p; p += N;
    float* stats4 = p; p += 4 * 256;
    int* dhist    = (int*)p; p += DBINS;
    int* rowstart = (int*)p; p += N + 1;
    int* gstart   = (int*)p; p += N_GRAPHS + 1;
    int* bsum     = (int*)p; p += 256;
    int* srcl     = (int*)p; p += E;
    int* doff     = (int*)p; p += DBINS;
    int* rowperm  = (int*)p; p += N;

    float* outp = (float*)d_out;
    float* o_gproj = outp;
    float* o_tproj = outp + N_GRAPHS * PROJ;
    float* o_glogp = o_tproj + N_GRAPHS * PROJ;
    float* o_tlogp = o_glogp + N_GRAPHS * N_CLS;

    // ---- CSR build + degree-sort + prep ----
    hipMemsetAsync(cnt, 0, (size_t)(2 * N + 4 * 256 + DBINS) * sizeof(int), stream);
    k_deg<<<ESLICE * 8, 256, 0, stream>>>(ei, cnt, E);
    k_scan1<<<NB_SCAN, 256, 0, stream>>>(cnt, rowstart, dnorm, bsum);
    k_scan2<<<1, 256, 0, stream>>>(bsum);
    k_scan3<<<NB_SCAN, 256, 0, stream>>>(rowstart, bsum, cnt, dhist);
    k_fill<<<ESLICE * 8, 256, 0, stream>>>(ei, rowstart, cursor, srcl, E);
    k_dscan<<<1, 256, 0, stream>>>(dhist, doff);
    k_dperm<<<(N + 1023) / 1024, 1024, 0, stream>>>(cnt, doff, rowperm);
    k_prep<<<(4 * 16384 + N + 1 + 255) / 256, 256, 0, stream>>>(gcnW, Wt, batch, gstart);

    // ---- 4 GCN layers (BN of layer l-1 folded into mm of layer l) ----
    for (int l = 0; l < 4; l++) {
        const void* in = (l == 0) ? (const void*)x : (const void*)outbb;
        const float* st = (l == 0) ? nullptr : stats4 + (l - 1) * 256;
        const float* bg = (l == 0) ? nullptr : bng + (size_t)(l - 1) * HID;
        const float* bb = (l == 0) ? nullptr : bnb + (size_t)(l - 1) * HID;
        k_gcn_mm_mfma<<<(N + 63) / 64, 256, 0, stream>>>(in, Wt + (size_t)l * 16384,
                                                         st, bg, bb, dnorm, ph, N);
        k_gather_c<<<NBG2 * 8, 256, 0, stream>>>((const uint4*)ph, srcl,
                                                 rowstart, rowperm, dnorm,
                                                 gcnb + (size_t)l * HID, outbb,
                                                 stats4 + l * 256, N);
    }

    // ---- segmented mean pool (layer-3 BN folded in-block) ----
    k_pool2<<<N_GRAPHS, 256, 0, stream>>>(outbb, gstart, stats4 + 3 * 256,
                                          bng + 3 * HID, bnb + 3 * HID, gemb);

    // ---- fused heads ----
    k_head1x<<<dim3(64, 4, 6), 256, 0, stream>>>(gemb, textf, gW1, tW1, projg, projt6);
    k_hprep<<<256, 256, 0, stream>>>(projg, projt6, gb1, tb1, prow_buf, grow_buf);
    k_head2a<<<dim3(64, 4, 4), 256, 0, stream>>>(grow_buf, gW2, tW2, h2p);
    k_head2b<<<512, 256, 0, stream>>>(h2p, prow_buf,
                                      gb2, gg, gbe, gclW, gclb,
                                      tb2, tg, tbe, tclW, tclb,
                                      o_gproj, o_tproj, o_glogp, o_tlogp);
}

// Round 8
// 446.951 us; speedup vs baseline: 2.1442x; 1.0241x over previous
//
#include <hip/hip_runtime.h>
#include <hip/hip_bf16.h>

// Problem sizes (fixed by reference)
#define N_NODES 50000
#define N_EDGES 800000
#define F_IN    128
#define HID     128
#define PROJ    512
#define N_CLS   32
#define N_GRAPHS 256
#define T_EMB   768
#define NB_SCAN ((N_NODES + 255) / 256)   // 196
#define DBINS   1024
#define NBROW   ((N_NODES + 63) / 64)     // 782 row-blocks (64 rows each)
#define NBG2    ((NBROW + 1) / 2)         // 391 row-block pairs per chunk
#define SHW     6250                      // dst rows per XCD shard (8*6250 = 50000)
#define ECAP    131072                    // per-shard edge capacity (mean 100k, sigma ~300)
#define NBF     98                        // blocks per shard for degb/fillb

typedef __attribute__((ext_vector_type(8))) short bf16x8;
typedef __attribute__((ext_vector_type(4))) float f32x4;

__device__ __forceinline__ float bf2f(unsigned short u) {
    unsigned v = ((unsigned)u) << 16;
    return __uint_as_float(v);
}
__device__ __forceinline__ unsigned short f2us(float v) {
    __hip_bfloat16 b = __float2bfloat16(v);
    union { __hip_bfloat16 b; unsigned short u; } c; c.b = b; return c.u;
}

// ---- edge pre-binning: one pass over ei, scatter packed (dst<<16|src) into
// 8 per-XCD-shard segments. LDS counters -> one global cursor atomic per
// block per shard (no same-address storm). Replaces 8x full-ei rescans. ----
__global__ __launch_bounds__(256) void k_bin(const int* __restrict__ ei,
    unsigned* __restrict__ ebuf, int* __restrict__ ecur, int nE)
{
    __shared__ int lcnt[8], lbase[8], lcur[8];
    int t = threadIdx.x;
    if (t < 8) { lcnt[t] = 0; lcur[t] = 0; }
    __syncthreads();
    int base = blockIdx.x * 1024 + t;
    int dd[4], ss[4], sh[4];
    bool ok[4];
#pragma unroll
    for (int u = 0; u < 4; u++) {
        int e = base + u * 256;
        ok[u] = e < nE;
        int d = ok[u] ? ei[nE + e] : 0;
        int s = ok[u] ? ei[e] : 0;
        dd[u] = d; ss[u] = s;
        sh[u] = d / SHW;
        if (ok[u]) atomicAdd(&lcnt[sh[u]], 1);
    }
    __syncthreads();
    if (t < 8) lbase[t] = atomicAdd(ecur + t, lcnt[t]);
    __syncthreads();
#pragma unroll
    for (int u = 0; u < 4; u++) {
        if (ok[u]) {
            int rank = atomicAdd(&lcur[sh[u]], 1);
            ebuf[(size_t)sh[u] * ECAP + lbase[sh[u]] + rank] =
                ((unsigned)dd[u] << 16) | (unsigned)ss[u];
        }
    }
}

// ---- degree histogram over binned edges; shard s pinned to XCD s via bid&7
// -> cnt atomics XCD-local; reads only the shard's ~100k records. ----
__global__ __launch_bounds__(256) void k_degb(const unsigned* __restrict__ ebuf,
    const int* __restrict__ ecur, int* __restrict__ cnt)
{
    int s = blockIdx.x & 7;
    int bs = blockIdx.x >> 3;
    int ecnt = ecur[s];
    const unsigned* eb = ebuf + (size_t)s * ECAP;
    for (int i = bs * 256 + threadIdx.x; i < ecnt; i += NBF * 256)
        atomicAdd(cnt + (eb[i] >> 16), 1);
}

// ---- parallel scan pass 1 ----
__global__ __launch_bounds__(256) void k_scan1(const int* __restrict__ cnt,
    int* __restrict__ rowstart, float* __restrict__ dnorm, int* __restrict__ bsum)
{
    __shared__ int ps[256];
    int t = threadIdx.x;
    int i = blockIdx.x * 256 + t;
    int c = (i < N_NODES) ? cnt[i] : 0;
    if (i < N_NODES) dnorm[i] = rsqrtf((float)c + 1.0f);
    ps[t] = c;
    __syncthreads();
    for (int off = 1; off < 256; off <<= 1) {
        int v = (t >= off) ? ps[t - off] : 0;
        __syncthreads();
        ps[t] += v;
        __syncthreads();
    }
    if (i < N_NODES) rowstart[i] = ps[t] - c;
    if (t == 255) bsum[blockIdx.x] = ps[255];
}

// ---- scan pass 2 ----
__global__ __launch_bounds__(256) void k_scan2(int* __restrict__ bsum) {
    __shared__ int ps[256];
    int t = threadIdx.x;
    int v = (t < NB_SCAN) ? bsum[t] : 0;
    ps[t] = v;
    __syncthreads();
    for (int off = 1; off < 256; off <<= 1) {
        int u = (t >= off) ? ps[t - off] : 0;
        __syncthreads();
        ps[t] += u;
        __syncthreads();
    }
    if (t < NB_SCAN) bsum[t] = ps[t] - v;
}

// ---- scan pass 3 (+ LDS-aggregated degree histogram for LPT sort) ----
__global__ __launch_bounds__(256) void k_scan3(int* __restrict__ rowstart,
    const int* __restrict__ bsum, const int* __restrict__ cnt,
    int* __restrict__ dhist)
{
    __shared__ int lh[DBINS];
    int t = threadIdx.x;
    for (int k = t; k < DBINS; k += 256) lh[k] = 0;
    __syncthreads();
    int i = blockIdx.x * 256 + t;
    if (i < N_NODES) {
        rowstart[i] += bsum[blockIdx.x];
        atomicAdd(&lh[min(cnt[i], DBINS - 1)], 1);
    }
    if (i == 0) rowstart[N_NODES] = N_EDGES;
    __syncthreads();
    for (int k = t; k < DBINS; k += 256) {
        int v = lh[k];
        if (v) atomicAdd(dhist + k, v);
    }
}

// ---- fill CSR src lists (uint16) over binned edges, XCD-local atomics ----
__global__ __launch_bounds__(256) void k_fillb(const unsigned* __restrict__ ebuf,
    const int* __restrict__ ecur, const int* __restrict__ rowstart,
    int* __restrict__ cursor, unsigned short* __restrict__ srcl16)
{
    int s = blockIdx.x & 7;
    int bs = blockIdx.x >> 3;
    int ecnt = ecur[s];
    const unsigned* eb = ebuf + (size_t)s * ECAP;
    for (int i = bs * 256 + threadIdx.x; i < ecnt; i += NBF * 256) {
        unsigned pk = eb[i];
        int d = pk >> 16;
        int pos = rowstart[d] + atomicAdd(cursor + d, 1);
        srcl16[pos] = (unsigned short)(pk & 0xffffu);
    }
}

// ---- descending-degree exclusive offsets: doff[d] = #rows with degree > d ----
__global__ __launch_bounds__(256) void k_dscan(const int* __restrict__ dhist,
                                               int* __restrict__ doff) {
    __shared__ int part[256];
    __shared__ int binv[DBINS];
    int t = threadIdx.x;
    int base = t * 4;
    int g0 = dhist[DBINS - 1 - (base + 0)];
    int g1 = dhist[DBINS - 1 - (base + 1)];
    int g2 = dhist[DBINS - 1 - (base + 2)];
    int g3 = dhist[DBINS - 1 - (base + 3)];
    int s = g0 + g1 + g2 + g3;
    part[t] = s;
    __syncthreads();
    for (int off = 1; off < 256; off <<= 1) {
        int v = (t >= off) ? part[t - off] : 0;
        __syncthreads();
        part[t] += v;
        __syncthreads();
    }
    int run = part[t] - s;   // exclusive prefix of this thread's 4 bins
    binv[base + 0] = run; run += g0;
    binv[base + 1] = run; run += g1;
    binv[base + 2] = run; run += g2;
    binv[base + 3] = run; run += g3;
    __syncthreads();
    for (int k = t; k < DBINS; k += 256) doff[DBINS - 1 - k] = binv[k];
}

// ---- degree-descending permutation + packed per-row meta {r,start,deg,dnorm}
// so the gather reads ONE sequential int4 instead of 4 random scalars. ----
__global__ __launch_bounds__(1024) void k_dperm(const int* __restrict__ cnt,
    int* __restrict__ doff, const int* __restrict__ rowstart,
    const float* __restrict__ dnorm, int4* __restrict__ meta)
{
    __shared__ int lh[DBINS];
    __shared__ int lbase[DBINS];
    int t = threadIdx.x;
    if (t < DBINS) lh[t] = 0;
    __syncthreads();
    int i = blockIdx.x * 1024 + t;
    int bin = 0, lrank = 0, c = 0;
    bool ok = i < N_NODES;
    if (ok) {
        c = cnt[i];
        bin = min(c, DBINS - 1);
        lrank = atomicAdd(&lh[bin], 1);
    }
    __syncthreads();
    if (t < DBINS) {
        int v = lh[t];
        if (v) lbase[t] = atomicAdd(doff + t, v);
    }
    __syncthreads();
    if (ok) {
        int pos = lbase[bin] + lrank;
        int4 mv;
        mv.x = i;
        mv.y = rowstart[i];
        mv.z = c;
        mv.w = __float_as_int(dnorm[i]);
        meta[pos] = mv;
    }
}

// ---- combined prep: weight transpose+bf16 and graph boundaries ----
__global__ void k_prep(const float* __restrict__ W, unsigned short* __restrict__ Wt,
                       const int* __restrict__ batch, int* __restrict__ gstart) {
    int t = blockIdx.x * 256 + threadIdx.x;
    if (t < 4 * 128 * 128) {
        int l = t >> 14;
        int k = (t >> 7) & 127;
        int n = t & 127;
        Wt[(size_t)l * 16384 + n * 128 + k] = f2us(W[(size_t)l * 16384 + k * 128 + n]);
    } else {
        int r = t - 4 * 128 * 128;
        if (r <= N_NODES) {
            int b  = (r < N_NODES) ? batch[r] : N_GRAPHS;
            int bp = (r > 0) ? batch[r - 1] : -1;
            for (int g = bp + 1; g <= b && g <= N_GRAPHS; g++) gstart[g] = r;
        }
    }
}

// ---- GCN matmul via bf16 MFMA; ph output CHUNK-MAJOR [4][N][32] bf16. ----
__global__ __launch_bounds__(256) void k_gcn_mm_mfma(const void* __restrict__ inp,
    const unsigned short* __restrict__ Wt,   // [128 n][128 k] bf16 (n-major)
    const float* __restrict__ stats, const float* __restrict__ bng,
    const float* __restrict__ bnb, const float* __restrict__ dnorm,
    unsigned short* __restrict__ ph, int n)
{
    __shared__ __align__(16) unsigned short Bs[128][136];   // 34.8 KB (reused as C-staging)
    __shared__ float scs[128], shs[128];
    int t = threadIdx.x;
    int row0 = blockIdx.x * 64;

    if (stats && t < 128) {
        float inv_n = 1.0f / (float)N_NODES;
        float mu = stats[t] * inv_n;
        float var = stats[128 + t] * inv_n - mu * mu;
        float rs = rsqrtf(var + 1e-5f);
        float sc = rs * bng[t];
        scs[t] = sc;
        shs[t] = bnb[t] - mu * sc;
    }
#pragma unroll
    for (int i = 0; i < 8; i++) {
        int c = t + i * 256;
        int nn = c >> 4;
        int k8 = (c & 15) * 8;
        *(uint4*)&Bs[nn][k8] = *(const uint4*)(Wt + (size_t)nn * 128 + k8);
    }
    __syncthreads();

    int w = t >> 6, lane = t & 63;
    int m = lane & 15, quad = lane >> 4;
    int arow = row0 + w * 16 + m;        // this lane's A row
    bool rowok = arow < n;

    // load A fragments for all 4 k-chunks (16 B each, aligned)
    bf16x8 afrag[4];
    if (!stats) {
        const float* inf = (const float*)inp;
#pragma unroll
        for (int ki = 0; ki < 4; ki++) {
            int k8 = ki * 32 + quad * 8;
            float4 v0 = make_float4(0.f, 0.f, 0.f, 0.f);
            float4 v1 = make_float4(0.f, 0.f, 0.f, 0.f);
            if (rowok) {
                v0 = *(const float4*)(inf + (size_t)arow * 128 + k8);
                v1 = *(const float4*)(inf + (size_t)arow * 128 + k8 + 4);
            }
            union { unsigned short u[8]; bf16x8 v; } pk;
            pk.u[0] = f2us(v0.x); pk.u[1] = f2us(v0.y); pk.u[2] = f2us(v0.z); pk.u[3] = f2us(v0.w);
            pk.u[4] = f2us(v1.x); pk.u[5] = f2us(v1.y); pk.u[6] = f2us(v1.z); pk.u[7] = f2us(v1.w);
            afrag[ki] = pk.v;
        }
    } else {
        const unsigned short* inb = (const unsigned short*)inp;
#pragma unroll
        for (int ki = 0; ki < 4; ki++) {
            int k8 = ki * 32 + quad * 8;
            uint4 raw = make_uint4(0, 0, 0, 0);
            if (rowok) raw = *(const uint4*)(inb + (size_t)arow * 128 + k8);
            unsigned rr[4] = { raw.x, raw.y, raw.z, raw.w };
            union { unsigned short u[8]; bf16x8 v; } pk;
#pragma unroll
            for (int j = 0; j < 4; j++) {
                int f0 = k8 + 2 * j, f1 = k8 + 2 * j + 1;
                float a0 = bf2f((unsigned short)rr[j]) * scs[f0] + shs[f0];
                float a1 = bf2f((unsigned short)(rr[j] >> 16)) * scs[f1] + shs[f1];
                pk.u[2 * j] = f2us(a0);
                pk.u[2 * j + 1] = f2us(a1);
            }
            afrag[ki] = pk.v;
        }
    }

    f32x4 acc[8];
#pragma unroll
    for (int nt = 0; nt < 8; nt++) acc[nt] = (f32x4){0.f, 0.f, 0.f, 0.f};
#pragma unroll
    for (int ki = 0; ki < 4; ki++) {
#pragma unroll
        for (int nt = 0; nt < 8; nt++) {
            bf16x8 b = *(const bf16x8*)&Bs[nt * 16 + m][ki * 32 + quad * 8];
            acc[nt] = __builtin_amdgcn_mfma_f32_16x16x32_bf16(afrag[ki], b, acc[nt], 0, 0, 0);
        }
    }

    float dn[4];
#pragma unroll
    for (int reg = 0; reg < 4; reg++) {
        int gr = row0 + w * 16 + quad * 4 + reg;
        dn[reg] = (gr < n) ? dnorm[gr] : 0.f;
    }

    // ---- epilogue: transpose C through LDS (reuse Bs), store chunk-major ----
    __syncthreads();   // all waves finished reading Bs
#pragma unroll
    for (int nt = 0; nt < 8; nt++) {
#pragma unroll
        for (int reg = 0; reg < 4; reg++) {
            Bs[w * 16 + quad * 4 + reg][nt * 16 + m] = f2us(acc[nt][reg] * dn[reg]);
        }
    }
    __syncthreads();
#pragma unroll
    for (int i = 0; i < 4; i++) {
        int idx = t + i * 256;           // 0..1023
        int r = idx >> 4;                // 0..63
        int c8 = (idx & 15) * 8;         // 0..120
        int gr = row0 + r;
        int ch = c8 >> 5;                // chunk 0..3
        int off = c8 & 31;               // 0,8,16,24
        if (gr < n)
            *(uint4*)(ph + (size_t)ch * (N_NODES * 32) + (size_t)gr * 32 + off)
                = *(const uint4*)&Bs[r][c8];
    }
}

// ---- gather v6: chunk pinned to XCD pair (bid&7), packed meta (1 sequential
// int4/row replaces 4 random scalar reads), uint16 srcl (half stream),
// unroll-8 edge chain for deeper MLP. ----
__global__ __launch_bounds__(256) void k_gather_c(const uint4* __restrict__ ph128,
    const unsigned short* __restrict__ srcl16, const int4* __restrict__ meta,
    const float* __restrict__ bias, unsigned short* __restrict__ outbb,
    float* __restrict__ stats, int n)
{
    const int EMAX = N_EDGES - 1;
    __shared__ float bsm[32], bqm[32];
    int t = threadIdx.x;
    if (t < 32) { bsm[t] = 0.f; bqm[t] = 0.f; }
    __syncthreads();

    int bx = blockIdx.x;
    int xcd = bx & 7;              // empirically: workgroup -> XCD round-robin
    int c = xcd >> 1;              // chunk pinned to XCD pair
    int rb = (bx >> 3) * 2 + (xcd & 1);   // row-block within chunk (0..781)
    int lane = t & 63;
    int w = t >> 6;                // wave 0..3
    int grp = lane >> 2;           // group 0..15 within wave (one row each)
    int l4 = lane & 3;             // lane in group: 8 feats (16 B) each
    int idx = rb * 64 + w * 16 + grp;
    bool rok = idx < n;
    int4 mv = rok ? meta[idx] : make_int4(0, 0, 0, 0);
    int r = mv.x, start = mv.y, deg = mv.z;
    float dnr = rok ? __int_as_float(mv.w) : 0.f;
    int len = deg + 1;             // + self loop

    const uint4* phc = ph128 + (size_t)c * (N_NODES * 4);   // 4 uint4 per 32-feat row

    float bi[8];
#pragma unroll
    for (int k = 0; k < 8; k++) bi[k] = bias[c * 32 + l4 * 8 + k];

    float a[8];
#pragma unroll
    for (int k = 0; k < 8; k++) a[k] = 0.f;

    for (int j = 0; j < len; j += 8) {
        int sl[8];
#pragma unroll
        for (int u = 0; u < 8; u++)
            sl[u] = srcl16[min(start + j + u, EMAX)];
        uint4 uv[8];
#pragma unroll
        for (int u = 0; u < 8; u++) {
            int i = j + u;
            int s = (i < deg) ? sl[u] : r;
            uv[u] = phc[(size_t)s * 4 + l4];
        }
#pragma unroll
        for (int u = 0; u < 8; u++) {
            int i = j + u;
            float wt = (i < len) ? 1.f : 0.f;
            unsigned rr[4] = { uv[u].x, uv[u].y, uv[u].z, uv[u].w };
#pragma unroll
            for (int d = 0; d < 4; d++) {
                a[2 * d]     += wt * bf2f((unsigned short)rr[d]);
                a[2 * d + 1] += wt * bf2f((unsigned short)(rr[d] >> 16));
            }
        }
    }

    float v[8];
#pragma unroll
    for (int k = 0; k < 8; k++) {
        float x = a[k] * dnr + bi[k];
        v[k] = x > 0.f ? x : 0.01f * x;
    }
    if (rok) {
        union { unsigned short us[8]; uint4 u; } ov;
#pragma unroll
        for (int k = 0; k < 8; k++) ov.us[k] = f2us(v[k]);
        *(uint4*)(outbb + (size_t)r * 128 + c * 32 + l4 * 8) = ov.u;
    } else {
#pragma unroll
        for (int k = 0; k < 8; k++) v[k] = 0.f;
    }

    float q[8];
#pragma unroll
    for (int k = 0; k < 8; k++) q[k] = v[k] * v[k];
    // reduce across the 16 groups of this wave (same feature at same l4)
#pragma unroll
    for (int mk = 4; mk < 64; mk <<= 1) {
#pragma unroll
        for (int k = 0; k < 8; k++) {
            v[k] += __shfl_xor(v[k], mk, 64);
            q[k] += __shfl_xor(q[k], mk, 64);
        }
    }
    if (grp == 0) {
#pragma unroll
        for (int k = 0; k < 8; k++) {
            atomicAdd(&bsm[l4 * 8 + k], v[k]);
            atomicAdd(&bqm[l4 * 8 + k], q[k]);
        }
    }
    __syncthreads();
    if (t < 32) {
        atomicAdd(&stats[c * 32 + t], bsm[t]);
        atomicAdd(&stats[128 + c * 32 + t], bqm[t]);
    }
}

// ---- segmented mean pool (bf16 input); BN scale/shift computed in-block ----
__global__ __launch_bounds__(256) void k_pool2(const unsigned short* __restrict__ outbb,
    const int* __restrict__ gstart, const float* __restrict__ stats,
    const float* __restrict__ bng, const float* __restrict__ bnb,
    float* __restrict__ gemb)
{
    __shared__ float scs[128], shs[128];
    int g = blockIdx.x;
    int t = threadIdx.x;
    if (t < 128) {
        float inv_n = 1.0f / (float)N_NODES;
        float mu = stats[t] * inv_n;
        float var = stats[128 + t] * inv_n - mu * mu;
        float rs = rsqrtf(var + 1e-5f);
        float sc = rs * bng[t];
        scs[t] = sc;
        shs[t] = bnb[t] - mu * sc;
    }
    __syncthreads();
    int f = t & 127;
    int half = t >> 7;
    int start = gstart[g], end = gstart[g + 1];
    int cnt = end - start;
    float s0 = 0.f, s1 = 0.f, s2 = 0.f, s3 = 0.f;
    int r = start + half;
    for (; r + 6 < end; r += 8) {
        s0 += bf2f(outbb[(size_t)(r    ) * 128 + f]);
        s1 += bf2f(outbb[(size_t)(r + 2) * 128 + f]);
        s2 += bf2f(outbb[(size_t)(r + 4) * 128 + f]);
        s3 += bf2f(outbb[(size_t)(r + 6) * 128 + f]);
    }
    for (; r < end; r += 2) s0 += bf2f(outbb[(size_t)r * 128 + f]);
    float sum = (s0 + s1) + (s2 + s3);
    __shared__ float sb[256];
    sb[t] = sum;
    __syncthreads();
    if (t < 128) {
        float tot = sb[t] + sb[t + 128];
        float v = (cnt > 0) ? (tot / (float)cnt) * scs[f] + shs[f] : 0.f;
        gemb[(size_t)g * 128 + f] = v;
    }
}

// ---- head layer 1 v2: split-K, no bias (folded downstream), no atomics. ----
__global__ __launch_bounds__(256) void k_head1x(const float* __restrict__ gemb,
    const float* __restrict__ textf,
    const float* __restrict__ gW1, const float* __restrict__ tW1,
    float* __restrict__ projg, float* __restrict__ projt6)
{
    __shared__ float ins[8][128];
    int bx = blockIdx.x;
    int kc = blockIdx.z;
    int isT = bx >= 32;
    if (!isT && kc > 0) return;
    int rb = isT ? bx - 32 : bx;
    const float* in = isT ? textf : gemb;
    int K = isT ? T_EMB : HID;
    const float* W = isT ? tW1 : gW1;
    float* outp = isT ? (projt6 + (size_t)kc * (N_GRAPHS * PROJ)) : projg;
    int k0 = kc * 128;

    int t = threadIdx.x;
    {
        int r = t >> 5, k = (t & 31) * 4;   // 8 rows x 128 floats
        *(float4*)&ins[r][k] = *(const float4*)(in + (size_t)(rb * 8 + r) * K + k0 + k);
    }
    __syncthreads();
    int col = blockIdx.y * 128 + (t & 127);
    int rg = t >> 7;
    float acc[4] = { 0.f, 0.f, 0.f, 0.f };
    const float* Wp = W + (size_t)k0 * 512 + col;
#pragma unroll 8
    for (int k = 0; k < 128; k++) {
        float w = Wp[(size_t)k * 512];
#pragma unroll
        for (int i = 0; i < 4; i++) acc[i] += ins[rg * 4 + i][k] * w;
    }
#pragma unroll
    for (int i = 0; i < 4; i++) {
        int row = rb * 8 + rg * 4 + i;
        outp[(size_t)row * 512 + col] = acc[i];
    }
}

// ---- hprep: materialize prow = proj + b1 (summing text split-K partials
// once) and grow = gelu(prow) for all 512 rows. ----
__global__ __launch_bounds__(256) void k_hprep(const float* __restrict__ projg,
    const float* __restrict__ projt6, const float* __restrict__ gb1,
    const float* __restrict__ tb1, float* __restrict__ prow_buf,
    float* __restrict__ grow_buf)
{
    int idx = (blockIdx.x * 256 + threadIdx.x) * 4;   // 512*512 total floats
    int row = idx >> 9;
    int c = idx & 511;
    int isT = row >= N_GRAPHS;
    int lrow = row & (N_GRAPHS - 1);
    const float* b1 = isT ? tb1 : gb1;
    float4 p;
    if (isT) {
        const float* pp = projt6 + (size_t)lrow * 512 + c;
        p = *(const float4*)pp;
#pragma unroll
        for (int s = 1; s < 6; s++) {
            float4 q = *(const float4*)(pp + (size_t)s * (N_GRAPHS * PROJ));
            p.x += q.x; p.y += q.y; p.z += q.z; p.w += q.w;
        }
    } else {
        p = *(const float4*)(projg + (size_t)lrow * 512 + c);
    }
    float4 b = *(const float4*)(b1 + c);
    p.x += b.x; p.y += b.y; p.z += b.z; p.w += b.w;
    *(float4*)(prow_buf + (size_t)row * 512 + c) = p;
    float4 g;
    g.x = 0.5f * p.x * (1.0f + erff(p.x * 0.70710678118f));
    g.y = 0.5f * p.y * (1.0f + erff(p.y * 0.70710678118f));
    g.z = 0.5f * p.z * (1.0f + erff(p.z * 0.70710678118f));
    g.w = 0.5f * p.w * (1.0f + erff(p.w * 0.70710678118f));
    *(float4*)(grow_buf + (size_t)row * 512 + c) = g;
}

// ---- head2a: split-K GEMM h2 = grow @ W2 (per-head W2), partials to h2p. ----
__global__ __launch_bounds__(256) void k_head2a(const float* __restrict__ grow_buf,
    const float* __restrict__ gW2, const float* __restrict__ tW2,
    float* __restrict__ h2p)
{
    __shared__ float gs[8][128];
    int rb = blockIdx.x;      // 0..63 (8 rows each; rb>=32 -> text head)
    int cc = blockIdx.y;      // 0..3
    int kc = blockIdx.z;      // 0..3
    int isT = rb >= 32;
    const float* W2 = isT ? tW2 : gW2;
    int t = threadIdx.x;
    {
        int r = t >> 5, k4 = (t & 31) * 4;
        *(float4*)&gs[r][k4] =
            *(const float4*)(grow_buf + (size_t)(rb * 8 + r) * 512 + kc * 128 + k4);
    }
    __syncthreads();
    int col = cc * 128 + (t & 127);
    int rg = t >> 7;
    float acc[4] = { 0.f, 0.f, 0.f, 0.f };
    const float* Wp = W2 + (size_t)(kc * 128) * 512 + col;
#pragma unroll 8
    for (int k = 0; k < 128; k++) {
        float w = Wp[(size_t)k * 512];
#pragma unroll
        for (int i = 0; i < 4; i++) acc[i] += gs[rg * 4 + i][k] * w;
    }
#pragma unroll
    for (int i = 0; i < 4; i++) {
        int row = rb * 8 + rg * 4 + i;
        h2p[(size_t)kc * (512 * 512) + (size_t)row * 512 + col] = acc[i];
    }
}

// ---- head2b: sum split-K partials + b2 + residual -> LayerNorm -> oproj,
// classifier + log_softmax. ----
__global__ __launch_bounds__(256) void k_head2b(const float* __restrict__ h2p,
    const float* __restrict__ prow_buf,
    const float* __restrict__ gb2, const float* __restrict__ gg,
    const float* __restrict__ gbe, const float* __restrict__ gclW,
    const float* __restrict__ gclb,
    const float* __restrict__ tb2, const float* __restrict__ tg,
    const float* __restrict__ tbe, const float* __restrict__ tclW,
    const float* __restrict__ tclb,
    float* __restrict__ o_gproj, float* __restrict__ o_tproj,
    float* __restrict__ o_glogp, float* __restrict__ o_tlogp)
{
    __shared__ float onorm[512], red[256];
    __shared__ float part[8][32];
    __shared__ float logits[32];
    __shared__ float mred, lred;
    int bx = blockIdx.x;              // global row 0..511
    int isT = bx >= N_GRAPHS;
    int row = bx & (N_GRAPHS - 1);
    const float* b2 = isT ? tb2 : gb2;
    const float* g  = isT ? tg  : gg;
    const float* be = isT ? tbe : gbe;
    const float* Wc = isT ? tclW : gclW;
    const float* bc = isT ? tclb : gclb;
    float* oproj = isT ? o_tproj : o_gproj;
    float* ologp = isT ? o_tlogp : o_glogp;

    int t = threadIdx.x;
    int c0 = t, c1 = t + 256;
    size_t base = (size_t)bx * 512;
    float h0 = prow_buf[base + c0] + b2[c0];
    float h1 = prow_buf[base + c1] + b2[c1];
#pragma unroll
    for (int kc = 0; kc < 4; kc++) {
        h0 += h2p[(size_t)kc * (512 * 512) + base + c0];
        h1 += h2p[(size_t)kc * (512 * 512) + base + c1];
    }
    red[t] = h0 + h1;
    __syncthreads();
    for (int s = 128; s > 0; s >>= 1) { if (t < s) red[t] += red[t + s]; __syncthreads(); }
    float mu = red[0] * (1.0f / 512.0f);
    __syncthreads();
    float d0 = h0 - mu, d1 = h1 - mu;
    red[t] = d0 * d0 + d1 * d1;
    __syncthreads();
    for (int s = 128; s > 0; s >>= 1) { if (t < s) red[t] += red[t + s]; __syncthreads(); }
    float rs = rsqrtf(red[0] * (1.0f / 512.0f) + 1e-5f);
    float o0 = d0 * rs * g[c0] + be[c0];
    float o1 = d1 * rs * g[c1] + be[c1];
    onorm[c0] = o0;
    onorm[c1] = o1;
    oproj[(size_t)row * 512 + c0] = o0;
    oproj[(size_t)row * 512 + c1] = o1;
    __syncthreads();

    int c = t & 31, seg = t >> 5;
    float p = 0.f;
    for (int k = seg * 64; k < seg * 64 + 64; k++)
        p += onorm[k] * Wc[(size_t)k * 32 + c];
    part[seg][c] = p;
    __syncthreads();
    if (t < 32) {
        float l = bc[t];
#pragma unroll
        for (int s = 0; s < 8; s++) l += part[s][t];
        logits[t] = l;
    }
    __syncthreads();
    if (t == 0) {
        float m = logits[0];
        for (int i = 1; i < 32; i++) m = fmaxf(m, logits[i]);
        float sum = 0.f;
        for (int i = 0; i < 32; i++) sum += expf(logits[i] - m);
        mred = m; lred = logf(sum);
    }
    __syncthreads();
    if (t < 32) ologp[(size_t)row * 32 + t] = logits[t] - mred - lred;
}

extern "C" void kernel_launch(void* const* d_in, const int* in_sizes, int n_in,
                              void* d_out, int out_size, void* d_ws, size_t ws_size,
                              hipStream_t stream) {
    const float* x     = (const float*)d_in[0];
    const int*   ei    = (const int*)d_in[1];
    const int*   batch = (const int*)d_in[2];
    const float* textf = (const float*)d_in[3];
    const float* gcnW  = (const float*)d_in[4];
    const float* gcnb  = (const float*)d_in[5];
    const float* bng   = (const float*)d_in[6];
    const float* bnb   = (const float*)d_in[7];
    const float* gW1   = (const float*)d_in[8];
    const float* gb1   = (const float*)d_in[9];
    const float* gW2   = (const float*)d_in[10];
    const float* gb2   = (const float*)d_in[11];
    const float* gg    = (const float*)d_in[12];
    const float* gbe   = (const float*)d_in[13];
    const float* gclW  = (const float*)d_in[14];
    const float* gclb  = (const float*)d_in[15];
    const float* tW1   = (const float*)d_in[16];
    const float* tb1   = (const float*)d_in[17];
    const float* tW2   = (const float*)d_in[18];
    const float* tb2   = (const float*)d_in[19];
    const float* tg    = (const float*)d_in[20];
    const float* tbe   = (const float*)d_in[21];
    const float* tclW  = (const float*)d_in[22];
    const float* tclb  = (const float*)d_in[23];

    const int N = N_NODES, E = N_EDGES;
    const int NF = N * HID;

    float* p = (float*)d_ws;
    unsigned short* outbb = (unsigned short*)p; p += NF / 2;   // 12.8 MB bf16
    unsigned short* ph    = (unsigned short*)p; p += NF / 2;   // 12.8 MB bf16 chunk-major
    unsigned short* Wt    = (unsigned short*)p; p += 4 * 16384 / 2;
    float* dnorm    = p; p += N;
    float* gemb     = p; p += N_GRAPHS * HID;
    float* projg    = p; p += N_GRAPHS * PROJ;
    float* projt6   = p; p += 6 * N_GRAPHS * PROJ;             // split-K partials (3 MB)
    float* prow_buf = p; p += 512 * PROJ;                      // 1 MB
    float* grow_buf = p; p += 512 * PROJ;                      // 1 MB
    float* h2p      = p; p += 4 * 512 * PROJ;                  // 4 MB split-K partials
    // contiguous zero-init region: cnt | cursor | stats4 | dhist | ecur
    int* cnt      = (int*)p; p += N;
    int* cursor   = (int*)p; p += N;
    float* stats4 = p; p += 4 * 256;
    int* dhist    = (int*)p; p += DBINS;
    int* ecur     = (int*)p; p += 8;
    int* rowstart = (int*)p; p += N + 1;
    int* gstart   = (int*)p; p += N_GRAPHS + 1;
    int* bsum     = (int*)p; p += 256;
    unsigned short* srcl16 = (unsigned short*)p; p += E / 2;   // 1.6 MB
    unsigned* ebuf = (unsigned*)p; p += 8 * ECAP;              // 4 MB binned edges
    int* doff     = (int*)p; p += DBINS;
    int4* meta    = (int4*)p; p += 4 * N;                      // 0.8 MB packed row meta

    float* outp = (float*)d_out;
    float* o_gproj = outp;
    float* o_tproj = outp + N_GRAPHS * PROJ;
    float* o_glogp = o_tproj + N_GRAPHS * PROJ;
    float* o_tlogp = o_glogp + N_GRAPHS * N_CLS;

    // ---- CSR build (binned) + degree-sort + prep ----
    hipMemsetAsync(cnt, 0, (size_t)(2 * N + 4 * 256 + DBINS + 8) * sizeof(int), stream);
    k_bin<<<(E + 1023) / 1024, 256, 0, stream>>>(ei, ebuf, ecur, E);
    k_degb<<<NBF * 8, 256, 0, stream>>>(ebuf, ecur, cnt);
    k_scan1<<<NB_SCAN, 256, 0, stream>>>(cnt, rowstart, dnorm, bsum);
    k_scan2<<<1, 256, 0, stream>>>(bsum);
    k_scan3<<<NB_SCAN, 256, 0, stream>>>(rowstart, bsum, cnt, dhist);
    k_fillb<<<NBF * 8, 256, 0, stream>>>(ebuf, ecur, rowstart, cursor, srcl16);
    k_dscan<<<1, 256, 0, stream>>>(dhist, doff);
    k_dperm<<<(N + 1023) / 1024, 1024, 0, stream>>>(cnt, doff, rowstart, dnorm, meta);
    k_prep<<<(4 * 16384 + N + 1 + 255) / 256, 256, 0, stream>>>(gcnW, Wt, batch, gstart);

    // ---- 4 GCN layers (BN of layer l-1 folded into mm of layer l) ----
    for (int l = 0; l < 4; l++) {
        const void* in = (l == 0) ? (const void*)x : (const void*)outbb;
        const float* st = (l == 0) ? nullptr : stats4 + (l - 1) * 256;
        const float* bg = (l == 0) ? nullptr : bng + (size_t)(l - 1) * HID;
        const float* bb = (l == 0) ? nullptr : bnb + (size_t)(l - 1) * HID;
        k_gcn_mm_mfma<<<(N + 63) / 64, 256, 0, stream>>>(in, Wt + (size_t)l * 16384,
                                                         st, bg, bb, dnorm, ph, N);
        k_gather_c<<<NBG2 * 8, 256, 0, stream>>>((const uint4*)ph, srcl16, meta,
                                                 gcnb + (size_t)l * HID, outbb,
                                                 stats4 + l * 256, N);
    }

    // ---- segmented mean pool (layer-3 BN folded in-block) ----
    k_pool2<<<N_GRAPHS, 256, 0, stream>>>(outbb, gstart, stats4 + 3 * 256,
                                          bng + 3 * HID, bnb + 3 * HID, gemb);

    // ---- fused heads ----
    k_head1x<<<dim3(64, 4, 6), 256, 0, stream>>>(gemb, textf, gW1, tW1, projg, projt6);
    k_hprep<<<256, 256, 0, stream>>>(projg, projt6, gb1, tb1, prow_buf, grow_buf);
    k_head2a<<<dim3(64, 4, 4), 256, 0, stream>>>(grow_buf, gW2, tW2, h2p);
    k_head2b<<<512, 256, 0, stream>>>(h2p, prow_buf,
                                      gb2, gg, gbe, gclW, gclb,
                                      tb2, tg, tbe, tclW, tclb,
                                      o_gproj, o_tproj, o_glogp, o_tlogp);
}

// Round 9
// 443.319 us; speedup vs baseline: 2.1618x; 1.0082x over previous
//
#include <hip/hip_runtime.h>
#include <hip/hip_bf16.h>

// Problem sizes (fixed by reference)
#define N_NODES 50000
#define N_EDGES 800000
#define F_IN    128
#define HID     128
#define PROJ    512
#define N_CLS   32
#define N_GRAPHS 256
#define T_EMB   768
#define NB_SCAN ((N_NODES + 255) / 256)   // 196
#define DBINS   1024
#define NBROW32 ((N_NODES + 31) / 32)     // 1563.. (32-row blocks); use 1564 via pairs
#define SHW     6250                      // dst rows per XCD shard (8*6250 = 50000)
#define ECAP    131072                    // per-shard edge capacity
#define NBF     98                        // blocks per shard for degb/fillb

typedef __attribute__((ext_vector_type(8))) short bf16x8;
typedef __attribute__((ext_vector_type(4))) float f32x4;

__device__ __forceinline__ float bf2f(unsigned short u) {
    unsigned v = ((unsigned)u) << 16;
    return __uint_as_float(v);
}
__device__ __forceinline__ unsigned short f2us(float v) {
    __hip_bfloat16 b = __float2bfloat16(v);
    union { __hip_bfloat16 b; unsigned short u; } c; c.b = b; return c.u;
}

// ---- edge pre-binning: one pass over ei, scatter packed (dst<<16|src) into
// 8 per-XCD-shard segments. ----
__global__ __launch_bounds__(256) void k_bin(const int* __restrict__ ei,
    unsigned* __restrict__ ebuf, int* __restrict__ ecur, int nE)
{
    __shared__ int lcnt[8], lbase[8], lcur[8];
    int t = threadIdx.x;
    if (t < 8) { lcnt[t] = 0; lcur[t] = 0; }
    __syncthreads();
    int base = blockIdx.x * 1024 + t;
    int dd[4], ss[4], sh[4];
    bool ok[4];
#pragma unroll
    for (int u = 0; u < 4; u++) {
        int e = base + u * 256;
        ok[u] = e < nE;
        int d = ok[u] ? ei[nE + e] : 0;
        int s = ok[u] ? ei[e] : 0;
        dd[u] = d; ss[u] = s;
        sh[u] = d / SHW;
        if (ok[u]) atomicAdd(&lcnt[sh[u]], 1);
    }
    __syncthreads();
    if (t < 8) lbase[t] = atomicAdd(ecur + t, lcnt[t]);
    __syncthreads();
#pragma unroll
    for (int u = 0; u < 4; u++) {
        if (ok[u]) {
            int rank = atomicAdd(&lcur[sh[u]], 1);
            ebuf[(size_t)sh[u] * ECAP + lbase[sh[u]] + rank] =
                ((unsigned)dd[u] << 16) | (unsigned)ss[u];
        }
    }
}

// ---- degree histogram over binned edges; shard s pinned to XCD s ----
__global__ __launch_bounds__(256) void k_degb(const unsigned* __restrict__ ebuf,
    const int* __restrict__ ecur, int* __restrict__ cnt)
{
    int s = blockIdx.x & 7;
    int bs = blockIdx.x >> 3;
    int ecnt = ecur[s];
    const unsigned* eb = ebuf + (size_t)s * ECAP;
    for (int i = bs * 256 + threadIdx.x; i < ecnt; i += NBF * 256)
        atomicAdd(cnt + (eb[i] >> 16), 1);
}

// ---- parallel scan pass 1 ----
__global__ __launch_bounds__(256) void k_scan1(const int* __restrict__ cnt,
    int* __restrict__ rowstart, float* __restrict__ dnorm, int* __restrict__ bsum)
{
    __shared__ int ps[256];
    int t = threadIdx.x;
    int i = blockIdx.x * 256 + t;
    int c = (i < N_NODES) ? cnt[i] : 0;
    if (i < N_NODES) dnorm[i] = rsqrtf((float)c + 1.0f);
    ps[t] = c;
    __syncthreads();
    for (int off = 1; off < 256; off <<= 1) {
        int v = (t >= off) ? ps[t - off] : 0;
        __syncthreads();
        ps[t] += v;
        __syncthreads();
    }
    if (i < N_NODES) rowstart[i] = ps[t] - c;
    if (t == 255) bsum[blockIdx.x] = ps[255];
}

// ---- scan pass 2 ----
__global__ __launch_bounds__(256) void k_scan2(int* __restrict__ bsum) {
    __shared__ int ps[256];
    int t = threadIdx.x;
    int v = (t < NB_SCAN) ? bsum[t] : 0;
    ps[t] = v;
    __syncthreads();
    for (int off = 1; off < 256; off <<= 1) {
        int u = (t >= off) ? ps[t - off] : 0;
        __syncthreads();
        ps[t] += u;
        __syncthreads();
    }
    if (t < NB_SCAN) bsum[t] = ps[t] - v;
}

// ---- scan pass 3 (+ LDS-aggregated degree histogram for LPT sort) ----
__global__ __launch_bounds__(256) void k_scan3(int* __restrict__ rowstart,
    const int* __restrict__ bsum, const int* __restrict__ cnt,
    int* __restrict__ dhist)
{
    __shared__ int lh[DBINS];
    int t = threadIdx.x;
    for (int k = t; k < DBINS; k += 256) lh[k] = 0;
    __syncthreads();
    int i = blockIdx.x * 256 + t;
    if (i < N_NODES) {
        rowstart[i] += bsum[blockIdx.x];
        atomicAdd(&lh[min(cnt[i], DBINS - 1)], 1);
    }
    if (i == 0) rowstart[N_NODES] = N_EDGES;
    __syncthreads();
    for (int k = t; k < DBINS; k += 256) {
        int v = lh[k];
        if (v) atomicAdd(dhist + k, v);
    }
}

// ---- fill CSR src lists (uint16) over binned edges, XCD-local atomics ----
__global__ __launch_bounds__(256) void k_fillb(const unsigned* __restrict__ ebuf,
    const int* __restrict__ ecur, const int* __restrict__ rowstart,
    int* __restrict__ cursor, unsigned short* __restrict__ srcl16)
{
    int s = blockIdx.x & 7;
    int bs = blockIdx.x >> 3;
    int ecnt = ecur[s];
    const unsigned* eb = ebuf + (size_t)s * ECAP;
    for (int i = bs * 256 + threadIdx.x; i < ecnt; i += NBF * 256) {
        unsigned pk = eb[i];
        int d = pk >> 16;
        int pos = rowstart[d] + atomicAdd(cursor + d, 1);
        srcl16[pos] = (unsigned short)(pk & 0xffffu);
    }
}

// ---- descending-degree exclusive offsets ----
__global__ __launch_bounds__(256) void k_dscan(const int* __restrict__ dhist,
                                               int* __restrict__ doff) {
    __shared__ int part[256];
    __shared__ int binv[DBINS];
    int t = threadIdx.x;
    int base = t * 4;
    int g0 = dhist[DBINS - 1 - (base + 0)];
    int g1 = dhist[DBINS - 1 - (base + 1)];
    int g2 = dhist[DBINS - 1 - (base + 2)];
    int g3 = dhist[DBINS - 1 - (base + 3)];
    int s = g0 + g1 + g2 + g3;
    part[t] = s;
    __syncthreads();
    for (int off = 1; off < 256; off <<= 1) {
        int v = (t >= off) ? part[t - off] : 0;
        __syncthreads();
        part[t] += v;
        __syncthreads();
    }
    int run = part[t] - s;   // exclusive prefix of this thread's 4 bins
    binv[base + 0] = run; run += g0;
    binv[base + 1] = run; run += g1;
    binv[base + 2] = run; run += g2;
    binv[base + 3] = run; run += g3;
    __syncthreads();
    for (int k = t; k < DBINS; k += 256) doff[DBINS - 1 - k] = binv[k];
}

// ---- degree-descending permutation + packed per-row meta {r,start,deg,dnorm} ----
__global__ __launch_bounds__(1024) void k_dperm(const int* __restrict__ cnt,
    int* __restrict__ doff, const int* __restrict__ rowstart,
    const float* __restrict__ dnorm, int4* __restrict__ meta)
{
    __shared__ int lh[DBINS];
    __shared__ int lbase[DBINS];
    int t = threadIdx.x;
    if (t < DBINS) lh[t] = 0;
    __syncthreads();
    int i = blockIdx.x * 1024 + t;
    int bin = 0, lrank = 0, c = 0;
    bool ok = i < N_NODES;
    if (ok) {
        c = cnt[i];
        bin = min(c, DBINS - 1);
        lrank = atomicAdd(&lh[bin], 1);
    }
    __syncthreads();
    if (t < DBINS) {
        int v = lh[t];
        if (v) lbase[t] = atomicAdd(doff + t, v);
    }
    __syncthreads();
    if (ok) {
        int pos = lbase[bin] + lrank;
        int4 mv;
        mv.x = i;
        mv.y = rowstart[i];
        mv.z = c;
        mv.w = __float_as_int(dnorm[i]);
        meta[pos] = mv;
    }
}

// ---- combined prep: weight transpose+bf16 and graph boundaries ----
__global__ void k_prep(const float* __restrict__ W, unsigned short* __restrict__ Wt,
                       const int* __restrict__ batch, int* __restrict__ gstart) {
    int t = blockIdx.x * 256 + threadIdx.x;
    if (t < 4 * 128 * 128) {
        int l = t >> 14;
        int k = (t >> 7) & 127;
        int n = t & 127;
        Wt[(size_t)l * 16384 + n * 128 + k] = f2us(W[(size_t)l * 16384 + k * 128 + n]);
    } else {
        int r = t - 4 * 128 * 128;
        if (r <= N_NODES) {
            int b  = (r < N_NODES) ? batch[r] : N_GRAPHS;
            int bp = (r > 0) ? batch[r - 1] : -1;
            for (int g = bp + 1; g <= b && g <= N_GRAPHS; g++) gstart[g] = r;
        }
    }
}

// ---- GCN matmul via bf16 MFMA; ph output CHUNK-MAJOR [4][N][32] bf16.
// stats is now 2x256 (parity copies) - BN fold sums the two copies. ----
__global__ __launch_bounds__(256) void k_gcn_mm_mfma(const void* __restrict__ inp,
    const unsigned short* __restrict__ Wt,   // [128 n][128 k] bf16 (n-major)
    const float* __restrict__ stats, const float* __restrict__ bng,
    const float* __restrict__ bnb, const float* __restrict__ dnorm,
    unsigned short* __restrict__ ph, int n)
{
    __shared__ __align__(16) unsigned short Bs[128][136];   // 34.8 KB (reused as C-staging)
    __shared__ float scs[128], shs[128];
    int t = threadIdx.x;
    int row0 = blockIdx.x * 64;

    if (stats && t < 128) {
        float inv_n = 1.0f / (float)N_NODES;
        float mu = (stats[t] + stats[256 + t]) * inv_n;
        float var = (stats[128 + t] + stats[384 + t]) * inv_n - mu * mu;
        float rs = rsqrtf(var + 1e-5f);
        float sc = rs * bng[t];
        scs[t] = sc;
        shs[t] = bnb[t] - mu * sc;
    }
#pragma unroll
    for (int i = 0; i < 8; i++) {
        int c = t + i * 256;
        int nn = c >> 4;
        int k8 = (c & 15) * 8;
        *(uint4*)&Bs[nn][k8] = *(const uint4*)(Wt + (size_t)nn * 128 + k8);
    }
    __syncthreads();

    int w = t >> 6, lane = t & 63;
    int m = lane & 15, quad = lane >> 4;
    int arow = row0 + w * 16 + m;        // this lane's A row
    bool rowok = arow < n;

    // load A fragments for all 4 k-chunks (16 B each, aligned)
    bf16x8 afrag[4];
    if (!stats) {
        const float* inf = (const float*)inp;
#pragma unroll
        for (int ki = 0; ki < 4; ki++) {
            int k8 = ki * 32 + quad * 8;
            float4 v0 = make_float4(0.f, 0.f, 0.f, 0.f);
            float4 v1 = make_float4(0.f, 0.f, 0.f, 0.f);
            if (rowok) {
                v0 = *(const float4*)(inf + (size_t)arow * 128 + k8);
                v1 = *(const float4*)(inf + (size_t)arow * 128 + k8 + 4);
            }
            union { unsigned short u[8]; bf16x8 v; } pk;
            pk.u[0] = f2us(v0.x); pk.u[1] = f2us(v0.y); pk.u[2] = f2us(v0.z); pk.u[3] = f2us(v0.w);
            pk.u[4] = f2us(v1.x); pk.u[5] = f2us(v1.y); pk.u[6] = f2us(v1.z); pk.u[7] = f2us(v1.w);
            afrag[ki] = pk.v;
        }
    } else {
        const unsigned short* inb = (const unsigned short*)inp;
#pragma unroll
        for (int ki = 0; ki < 4; ki++) {
            int k8 = ki * 32 + quad * 8;
            uint4 raw = make_uint4(0, 0, 0, 0);
            if (rowok) raw = *(const uint4*)(inb + (size_t)arow * 128 + k8);
            unsigned rr[4] = { raw.x, raw.y, raw.z, raw.w };
            union { unsigned short u[8]; bf16x8 v; } pk;
#pragma unroll
            for (int j = 0; j < 4; j++) {
                int f0 = k8 + 2 * j, f1 = k8 + 2 * j + 1;
                float a0 = bf2f((unsigned short)rr[j]) * scs[f0] + shs[f0];
                float a1 = bf2f((unsigned short)(rr[j] >> 16)) * scs[f1] + shs[f1];
                pk.u[2 * j] = f2us(a0);
                pk.u[2 * j + 1] = f2us(a1);
            }
            afrag[ki] = pk.v;
        }
    }

    f32x4 acc[8];
#pragma unroll
    for (int nt = 0; nt < 8; nt++) acc[nt] = (f32x4){0.f, 0.f, 0.f, 0.f};
#pragma unroll
    for (int ki = 0; ki < 4; ki++) {
#pragma unroll
        for (int nt = 0; nt < 8; nt++) {
            bf16x8 b = *(const bf16x8*)&Bs[nt * 16 + m][ki * 32 + quad * 8];
            acc[nt] = __builtin_amdgcn_mfma_f32_16x16x32_bf16(afrag[ki], b, acc[nt], 0, 0, 0);
        }
    }

    float dn[4];
#pragma unroll
    for (int reg = 0; reg < 4; reg++) {
        int gr = row0 + w * 16 + quad * 4 + reg;
        dn[reg] = (gr < n) ? dnorm[gr] : 0.f;
    }

    // ---- epilogue: transpose C through LDS (reuse Bs), store chunk-major ----
    __syncthreads();   // all waves finished reading Bs
#pragma unroll
    for (int nt = 0; nt < 8; nt++) {
#pragma unroll
        for (int reg = 0; reg < 4; reg++) {
            Bs[w * 16 + quad * 4 + reg][nt * 16 + m] = f2us(acc[nt][reg] * dn[reg]);
        }
    }
    __syncthreads();
#pragma unroll
    for (int i = 0; i < 4; i++) {
        int idx = t + i * 256;           // 0..1023
        int r = idx >> 4;                // 0..63
        int c8 = (idx & 15) * 8;         // 0..120
        int gr = row0 + r;
        int ch = c8 >> 5;                // chunk 0..3
        int off = c8 & 31;               // 0,8,16,24
        if (gr < n)
            *(uint4*)(ph + (size_t)ch * (N_NODES * 32) + (size_t)gr * 32 + off)
                = *(const uint4*)&Bs[r][c8];
    }
}

// ---- gather v7: 128-thread blocks (32 rows, 2 waves) -> 2x grid (6256
// blocks, ~24/CU) to raise residency (round-7: 57% occupancy, latency-bound).
// Chunk still pinned to XCD pair via bid&7. Stats split into 2 parity copies
// (indexed xcd&1) to keep same-address atomic count flat vs round 8. ----
__global__ __launch_bounds__(128) void k_gather_c(const uint4* __restrict__ ph128,
    const unsigned short* __restrict__ srcl16, const int4* __restrict__ meta,
    const float* __restrict__ bias, unsigned short* __restrict__ outbb,
    float* __restrict__ stats, int n)
{
    const int EMAX = N_EDGES - 1;
    __shared__ float bsm[32], bqm[32];
    int t = threadIdx.x;
    if (t < 32) { bsm[t] = 0.f; bqm[t] = 0.f; }
    __syncthreads();

    int bx = blockIdx.x;
    int xcd = bx & 7;              // empirically: workgroup -> XCD round-robin
    int c = xcd >> 1;              // chunk pinned to XCD pair
    int sub = xcd & 1;             // stats parity copy
    int rb32 = (bx >> 3) * 2 + sub;       // 32-row block within chunk (0..1563)
    int lane = t & 63;
    int w = t >> 6;                // wave 0..1
    int grp = lane >> 2;           // group 0..15 within wave (one row each)
    int l4 = lane & 3;             // lane in group: 8 feats (16 B) each
    int idx = rb32 * 32 + w * 16 + grp;
    bool rok = idx < n;
    int4 mv = rok ? meta[idx] : make_int4(0, 0, 0, 0);
    int r = mv.x, start = mv.y, deg = mv.z;
    float dnr = rok ? __int_as_float(mv.w) : 0.f;
    int len = deg + 1;             // + self loop

    const uint4* phc = ph128 + (size_t)c * (N_NODES * 4);   // 4 uint4 per 32-feat row

    float bi[8];
#pragma unroll
    for (int k = 0; k < 8; k++) bi[k] = bias[c * 32 + l4 * 8 + k];

    float a[8];
#pragma unroll
    for (int k = 0; k < 8; k++) a[k] = 0.f;

    for (int j = 0; j < len; j += 8) {
        int sl[8];
#pragma unroll
        for (int u = 0; u < 8; u++)
            sl[u] = srcl16[min(start + j + u, EMAX)];
        uint4 uv[8];
#pragma unroll
        for (int u = 0; u < 8; u++) {
            int i = j + u;
            int s = (i < deg) ? sl[u] : r;
            uv[u] = phc[(size_t)s * 4 + l4];
        }
#pragma unroll
        for (int u = 0; u < 8; u++) {
            int i = j + u;
            float wt = (i < len) ? 1.f : 0.f;
            unsigned rr[4] = { uv[u].x, uv[u].y, uv[u].z, uv[u].w };
#pragma unroll
            for (int d = 0; d < 4; d++) {
                a[2 * d]     += wt * bf2f((unsigned short)rr[d]);
                a[2 * d + 1] += wt * bf2f((unsigned short)(rr[d] >> 16));
            }
        }
    }

    float v[8];
#pragma unroll
    for (int k = 0; k < 8; k++) {
        float x = a[k] * dnr + bi[k];
        v[k] = x > 0.f ? x : 0.01f * x;
    }
    if (rok) {
        union { unsigned short us[8]; uint4 u; } ov;
#pragma unroll
        for (int k = 0; k < 8; k++) ov.us[k] = f2us(v[k]);
        *(uint4*)(outbb + (size_t)r * 128 + c * 32 + l4 * 8) = ov.u;
    } else {
#pragma unroll
        for (int k = 0; k < 8; k++) v[k] = 0.f;
    }

    float q[8];
#pragma unroll
    for (int k = 0; k < 8; k++) q[k] = v[k] * v[k];
    // reduce across the 16 groups of this wave (same feature at same l4)
#pragma unroll
    for (int mk = 4; mk < 64; mk <<= 1) {
#pragma unroll
        for (int k = 0; k < 8; k++) {
            v[k] += __shfl_xor(v[k], mk, 64);
            q[k] += __shfl_xor(q[k], mk, 64);
        }
    }
    if (grp == 0) {
#pragma unroll
        for (int k = 0; k < 8; k++) {
            atomicAdd(&bsm[l4 * 8 + k], v[k]);
            atomicAdd(&bqm[l4 * 8 + k], q[k]);
        }
    }
    __syncthreads();
    if (t < 32) {
        atomicAdd(&stats[sub * 256 + c * 32 + t], bsm[t]);
        atomicAdd(&stats[sub * 256 + 128 + c * 32 + t], bqm[t]);
    }
}

// ---- segmented mean pool (bf16 input); BN from 2 parity stat copies ----
__global__ __launch_bounds__(256) void k_pool2(const unsigned short* __restrict__ outbb,
    const int* __restrict__ gstart, const float* __restrict__ stats,
    const float* __restrict__ bng, const float* __restrict__ bnb,
    float* __restrict__ gemb)
{
    __shared__ float scs[128], shs[128];
    int g = blockIdx.x;
    int t = threadIdx.x;
    if (t < 128) {
        float inv_n = 1.0f / (float)N_NODES;
        float mu = (stats[t] + stats[256 + t]) * inv_n;
        float var = (stats[128 + t] + stats[384 + t]) * inv_n - mu * mu;
        float rs = rsqrtf(var + 1e-5f);
        float sc = rs * bng[t];
        scs[t] = sc;
        shs[t] = bnb[t] - mu * sc;
    }
    __syncthreads();
    int f = t & 127;
    int half = t >> 7;
    int start = gstart[g], end = gstart[g + 1];
    int cnt = end - start;
    float s0 = 0.f, s1 = 0.f, s2 = 0.f, s3 = 0.f;
    int r = start + half;
    for (; r + 6 < end; r += 8) {
        s0 += bf2f(outbb[(size_t)(r    ) * 128 + f]);
        s1 += bf2f(outbb[(size_t)(r + 2) * 128 + f]);
        s2 += bf2f(outbb[(size_t)(r + 4) * 128 + f]);
        s3 += bf2f(outbb[(size_t)(r + 6) * 128 + f]);
    }
    for (; r < end; r += 2) s0 += bf2f(outbb[(size_t)r * 128 + f]);
    float sum = (s0 + s1) + (s2 + s3);
    __shared__ float sb[256];
    sb[t] = sum;
    __syncthreads();
    if (t < 128) {
        float tot = sb[t] + sb[t + 128];
        float v = (cnt > 0) ? (tot / (float)cnt) * scs[f] + shs[f] : 0.f;
        gemb[(size_t)g * 128 + f] = v;
    }
}

// ---- head layer 1 v2: split-K, no bias (folded downstream), no atomics. ----
__global__ __launch_bounds__(256) void k_head1x(const float* __restrict__ gemb,
    const float* __restrict__ textf,
    const float* __restrict__ gW1, const float* __restrict__ tW1,
    float* __restrict__ projg, float* __restrict__ projt6)
{
    __shared__ float ins[8][128];
    int bx = blockIdx.x;
    int kc = blockIdx.z;
    int isT = bx >= 32;
    if (!isT && kc > 0) return;
    int rb = isT ? bx - 32 : bx;
    const float* in = isT ? textf : gemb;
    int K = isT ? T_EMB : HID;
    const float* W = isT ? tW1 : gW1;
    float* outp = isT ? (projt6 + (size_t)kc * (N_GRAPHS * PROJ)) : projg;
    int k0 = kc * 128;

    int t = threadIdx.x;
    {
        int r = t >> 5, k = (t & 31) * 4;   // 8 rows x 128 floats
        *(float4*)&ins[r][k] = *(const float4*)(in + (size_t)(rb * 8 + r) * K + k0 + k);
    }
    __syncthreads();
    int col = blockIdx.y * 128 + (t & 127);
    int rg = t >> 7;
    float acc[4] = { 0.f, 0.f, 0.f, 0.f };
    const float* Wp = W + (size_t)k0 * 512 + col;
#pragma unroll 8
    for (int k = 0; k < 128; k++) {
        float w = Wp[(size_t)k * 512];
#pragma unroll
        for (int i = 0; i < 4; i++) acc[i] += ins[rg * 4 + i][k] * w;
    }
#pragma unroll
    for (int i = 0; i < 4; i++) {
        int row = rb * 8 + rg * 4 + i;
        outp[(size_t)row * 512 + col] = acc[i];
    }
}

// ---- hprep: materialize prow = proj + b1 and grow = gelu(prow). ----
__global__ __launch_bounds__(256) void k_hprep(const float* __restrict__ projg,
    const float* __restrict__ projt6, const float* __restrict__ gb1,
    const float* __restrict__ tb1, float* __restrict__ prow_buf,
    float* __restrict__ grow_buf)
{
    int idx = (blockIdx.x * 256 + threadIdx.x) * 4;   // 512*512 total floats
    int row = idx >> 9;
    int c = idx & 511;
    int isT = row >= N_GRAPHS;
    int lrow = row & (N_GRAPHS - 1);
    const float* b1 = isT ? tb1 : gb1;
    float4 p;
    if (isT) {
        const float* pp = projt6 + (size_t)lrow * 512 + c;
        p = *(const float4*)pp;
#pragma unroll
        for (int s = 1; s < 6; s++) {
            float4 q = *(const float4*)(pp + (size_t)s * (N_GRAPHS * PROJ));
            p.x += q.x; p.y += q.y; p.z += q.z; p.w += q.w;
        }
    } else {
        p = *(const float4*)(projg + (size_t)lrow * 512 + c);
    }
    float4 b = *(const float4*)(b1 + c);
    p.x += b.x; p.y += b.y; p.z += b.z; p.w += b.w;
    *(float4*)(prow_buf + (size_t)row * 512 + c) = p;
    float4 g;
    g.x = 0.5f * p.x * (1.0f + erff(p.x * 0.70710678118f));
    g.y = 0.5f * p.y * (1.0f + erff(p.y * 0.70710678118f));
    g.z = 0.5f * p.z * (1.0f + erff(p.z * 0.70710678118f));
    g.w = 0.5f * p.w * (1.0f + erff(p.w * 0.70710678118f));
    *(float4*)(grow_buf + (size_t)row * 512 + c) = g;
}

// ---- head2a: split-K GEMM h2 = grow @ W2 (per-head W2), partials to h2p. ----
__global__ __launch_bounds__(256) void k_head2a(const float* __restrict__ grow_buf,
    const float* __restrict__ gW2, const float* __restrict__ tW2,
    float* __restrict__ h2p)
{
    __shared__ float gs[8][128];
    int rb = blockIdx.x;      // 0..63 (8 rows each; rb>=32 -> text head)
    int cc = blockIdx.y;      // 0..3
    int kc = blockIdx.z;      // 0..3
    int isT = rb >= 32;
    const float* W2 = isT ? tW2 : gW2;
    int t = threadIdx.x;
    {
        int r = t >> 5, k4 = (t & 31) * 4;
        *(float4*)&gs[r][k4] =
            *(const float4*)(grow_buf + (size_t)(rb * 8 + r) * 512 + kc * 128 + k4);
    }
    __syncthreads();
    int col = cc * 128 + (t & 127);
    int rg = t >> 7;
    float acc[4] = { 0.f, 0.f, 0.f, 0.f };
    const float* Wp = W2 + (size_t)(kc * 128) * 512 + col;
#pragma unroll 8
    for (int k = 0; k < 128; k++) {
        float w = Wp[(size_t)k * 512];
#pragma unroll
        for (int i = 0; i < 4; i++) acc[i] += gs[rg * 4 + i][k] * w;
    }
#pragma unroll
    for (int i = 0; i < 4; i++) {
        int row = rb * 8 + rg * 4 + i;
        h2p[(size_t)kc * (512 * 512) + (size_t)row * 512 + col] = acc[i];
    }
}

// ---- head2b: sum split-K partials + b2 + residual -> LayerNorm -> oproj,
// classifier + log_softmax. ----
__global__ __launch_bounds__(256) void k_head2b(const float* __restrict__ h2p,
    const float* __restrict__ prow_buf,
    const float* __restrict__ gb2, const float* __restrict__ gg,
    const float* __restrict__ gbe, const float* __restrict__ gclW,
    const float* __restrict__ gclb,
    const float* __restrict__ tb2, const float* __restrict__ tg,
    const float* __restrict__ tbe, const float* __restrict__ tclW,
    const float* __restrict__ tclb,
    float* __restrict__ o_gproj, float* __restrict__ o_tproj,
    float* __restrict__ o_glogp, float* __restrict__ o_tlogp)
{
    __shared__ float onorm[512], red[256];
    __shared__ float part[8][32];
    __shared__ float logits[32];
    __shared__ float mred, lred;
    int bx = blockIdx.x;              // global row 0..511
    int isT = bx >= N_GRAPHS;
    int row = bx & (N_GRAPHS - 1);
    const float* b2 = isT ? tb2 : gb2;
    const float* g  = isT ? tg  : gg;
    const float* be = isT ? tbe : gbe;
    const float* Wc = isT ? tclW : gclW;
    const float* bc = isT ? tclb : gclb;
    float* oproj = isT ? o_tproj : o_gproj;
    float* ologp = isT ? o_tlogp : o_glogp;

    int t = threadIdx.x;
    int c0 = t, c1 = t + 256;
    size_t base = (size_t)bx * 512;
    float h0 = prow_buf[base + c0] + b2[c0];
    float h1 = prow_buf[base + c1] + b2[c1];
#pragma unroll
    for (int kc = 0; kc < 4; kc++) {
        h0 += h2p[(size_t)kc * (512 * 512) + base + c0];
        h1 += h2p[(size_t)kc * (512 * 512) + base + c1];
    }
    red[t] = h0 + h1;
    __syncthreads();
    for (int s = 128; s > 0; s >>= 1) { if (t < s) red[t] += red[t + s]; __syncthreads(); }
    float mu = red[0] * (1.0f / 512.0f);
    __syncthreads();
    float d0 = h0 - mu, d1 = h1 - mu;
    red[t] = d0 * d0 + d1 * d1;
    __syncthreads();
    for (int s = 128; s > 0; s >>= 1) { if (t < s) red[t] += red[t + s]; __syncthreads(); }
    float rs = rsqrtf(red[0] * (1.0f / 512.0f) + 1e-5f);
    float o0 = d0 * rs * g[c0] + be[c0];
    float o1 = d1 * rs * g[c1] + be[c1];
    onorm[c0] = o0;
    onorm[c1] = o1;
    oproj[(size_t)row * 512 + c0] = o0;
    oproj[(size_t)row * 512 + c1] = o1;
    __syncthreads();

    int c = t & 31, seg = t >> 5;
    float p = 0.f;
    for (int k = seg * 64; k < seg * 64 + 64; k++)
        p += onorm[k] * Wc[(size_t)k * 32 + c];
    part[seg][c] = p;
    __syncthreads();
    if (t < 32) {
        float l = bc[t];
#pragma unroll
        for (int s = 0; s < 8; s++) l += part[s][t];
        logits[t] = l;
    }
    __syncthreads();
    if (t == 0) {
        float m = logits[0];
        for (int i = 1; i < 32; i++) m = fmaxf(m, logits[i]);
        float sum = 0.f;
        for (int i = 0; i < 32; i++) sum += expf(logits[i] - m);
        mred = m; lred = logf(sum);
    }
    __syncthreads();
    if (t < 32) ologp[(size_t)row * 32 + t] = logits[t] - mred - lred;
}

extern "C" void kernel_launch(void* const* d_in, const int* in_sizes, int n_in,
                              void* d_out, int out_size, void* d_ws, size_t ws_size,
                              hipStream_t stream) {
    const float* x     = (const float*)d_in[0];
    const int*   ei    = (const int*)d_in[1];
    const int*   batch = (const int*)d_in[2];
    const float* textf = (const float*)d_in[3];
    const float* gcnW  = (const float*)d_in[4];
    const float* gcnb  = (const float*)d_in[5];
    const float* bng   = (const float*)d_in[6];
    const float* bnb   = (const float*)d_in[7];
    const float* gW1   = (const float*)d_in[8];
    const float* gb1   = (const float*)d_in[9];
    const float* gW2   = (const float*)d_in[10];
    const float* gb2   = (const float*)d_in[11];
    const float* gg    = (const float*)d_in[12];
    const float* gbe   = (const float*)d_in[13];
    const float* gclW  = (const float*)d_in[14];
    const float* gclb  = (const float*)d_in[15];
    const float* tW1   = (const float*)d_in[16];
    const float* tb1   = (const float*)d_in[17];
    const float* tW2   = (const float*)d_in[18];
    const float* tb2   = (const float*)d_in[19];
    const float* tg    = (const float*)d_in[20];
    const float* tbe   = (const float*)d_in[21];
    const float* tclW  = (const float*)d_in[22];
    const float* tclb  = (const float*)d_in[23];

    const int N = N_NODES, E = N_EDGES;
    const int NF = N * HID;

    float* p = (float*)d_ws;
    unsigned short* outbb = (unsigned short*)p; p += NF / 2;   // 12.8 MB bf16
    unsigned short* ph    = (unsigned short*)p; p += NF / 2;   // 12.8 MB bf16 chunk-major
    unsigned short* Wt    = (unsigned short*)p; p += 4 * 16384 / 2;
    float* dnorm    = p; p += N;
    float* gemb     = p; p += N_GRAPHS * HID;
    float* projg    = p; p += N_GRAPHS * PROJ;
    float* projt6   = p; p += 6 * N_GRAPHS * PROJ;             // split-K partials (3 MB)
    float* prow_buf = p; p += 512 * PROJ;                      // 1 MB
    float* grow_buf = p; p += 512 * PROJ;                      // 1 MB
    float* h2p      = p; p += 4 * 512 * PROJ;                  // 4 MB split-K partials
    // contiguous zero-init region: cnt | cursor | stats4 (2-copy) | dhist | ecur
    int* cnt      = (int*)p; p += N;
    int* cursor   = (int*)p; p += N;
    float* stats4 = p; p += 4 * 512;                           // [layer][2 copies][256]
    int* dhist    = (int*)p; p += DBINS;
    int* ecur     = (int*)p; p += 8;
    int* rowstart = (int*)p; p += N + 1;
    int* gstart   = (int*)p; p += N_GRAPHS + 1;
    int* bsum     = (int*)p; p += 256;
    unsigned short* srcl16 = (unsigned short*)p; p += E / 2;   // 1.6 MB
    unsigned* ebuf = (unsigned*)p; p += 8 * ECAP;              // 4 MB binned edges
    int* doff     = (int*)p; p += DBINS;
    int4* meta    = (int4*)p; p += 4 * N;                      // 0.8 MB packed row meta

    float* outp = (float*)d_out;
    float* o_gproj = outp;
    float* o_tproj = outp + N_GRAPHS * PROJ;
    float* o_glogp = o_tproj + N_GRAPHS * PROJ;
    float* o_tlogp = o_glogp + N_GRAPHS * N_CLS;

    // ---- CSR build (binned) + degree-sort + prep ----
    hipMemsetAsync(cnt, 0, (size_t)(2 * N + 4 * 512 + DBINS + 8) * sizeof(int), stream);
    k_bin<<<(E + 1023) / 1024, 256, 0, stream>>>(ei, ebuf, ecur, E);
    k_degb<<<NBF * 8, 256, 0, stream>>>(ebuf, ecur, cnt);
    k_scan1<<<NB_SCAN, 256, 0, stream>>>(cnt, rowstart, dnorm, bsum);
    k_scan2<<<1, 256, 0, stream>>>(bsum);
    k_scan3<<<NB_SCAN, 256, 0, stream>>>(rowstart, bsum, cnt, dhist);
    k_fillb<<<NBF * 8, 256, 0, stream>>>(ebuf, ecur, rowstart, cursor, srcl16);
    k_dscan<<<1, 256, 0, stream>>>(dhist, doff);
    k_dperm<<<(N + 1023) / 1024, 1024, 0, stream>>>(cnt, doff, rowstart, dnorm, meta);
    k_prep<<<(4 * 16384 + N + 1 + 255) / 256, 256, 0, stream>>>(gcnW, Wt, batch, gstart);

    // ---- 4 GCN layers (BN of layer l-1 folded into mm of layer l) ----
    for (int l = 0; l < 4; l++) {
        const void* in = (l == 0) ? (const void*)x : (const void*)outbb;
        const float* st = (l == 0) ? nullptr : stats4 + (l - 1) * 512;
        const float* bg = (l == 0) ? nullptr : bng + (size_t)(l - 1) * HID;
        const float* bb = (l == 0) ? nullptr : bnb + (size_t)(l - 1) * HID;
        k_gcn_mm_mfma<<<(N + 63) / 64, 256, 0, stream>>>(in, Wt + (size_t)l * 16384,
                                                         st, bg, bb, dnorm, ph, N);
        k_gather_c<<<782 * 8, 128, 0, stream>>>((const uint4*)ph, srcl16, meta,
                                                gcnb + (size_t)l * HID, outbb,
                                                stats4 + l * 512, N);
    }

    // ---- segmented mean pool (layer-3 BN folded in-block) ----
    k_pool2<<<N_GRAPHS, 256, 0, stream>>>(outbb, gstart, stats4 + 3 * 512,
                                          bng + 3 * HID, bnb + 3 * HID, gemb);

    // ---- fused heads ----
    k_head1x<<<dim3(64, 4, 6), 256, 0, stream>>>(gemb, textf, gW1, tW1, projg, projt6);
    k_hprep<<<256, 256, 0, stream>>>(projg, projt6, gb1, tb1, prow_buf, grow_buf);
    k_head2a<<<dim3(64, 4, 4), 256, 0, stream>>>(grow_buf, gW2, tW2, h2p);
    k_head2b<<<512, 256, 0, stream>>>(h2p, prow_buf,
                                      gb2, gg, gbe, gclW, gclb,
                                      tb2, tg, tbe, tclW, tclb,
                                      o_gproj, o_tproj, o_glogp, o_tlogp);
}